// Round 2
// baseline (681.644 us; speedup 1.0000x reference)
//
#include <hip/hip_runtime.h>
#include <hip/hip_bf16.h>

typedef __hip_bfloat16 bf16;
typedef __attribute__((ext_vector_type(8))) short bf16x8;
typedef __attribute__((ext_vector_type(4))) float f32x4;

#define H 128
#define F3H 384
#define E_RBF 20
#define NLAYER 3

__device__ __forceinline__ float silu_f(float x) { return x / (1.0f + __expf(-x)); }
__device__ __forceinline__ float b2f(bf16 x) { return __bfloat162float(x); }

constexpr float PI_F = 3.14159265358979323846f;
constexpr float CUT = 5.0f;

// ---------------- CSR build ----------------
__global__ __launch_bounds__(256) void csr_hist(
    const int* __restrict__ edge, int* __restrict__ cnt, int nE) {
  int e = blockIdx.x * blockDim.x + threadIdx.x;
  if (e < nE) atomicAdd(&cnt[edge[2 * e]], 1);
}

__global__ __launch_bounds__(256) void csr_scan(
    const int* __restrict__ cnt, int* __restrict__ rowstart, int* __restrict__ cur, int N) {
  __shared__ int part[256];
  int t = threadIdx.x;
  int chunk = (N + 255) / 256;
  int lo = t * chunk; if (lo > N) lo = N;
  int hi = lo + chunk; if (hi > N) hi = N;
  int s = 0;
  for (int i = lo; i < hi; i++) s += cnt[i];
  part[t] = s;
  __syncthreads();
  if (t == 0) {
    int r = 0;
    for (int i = 0; i < 256; i++) { int v = part[i]; part[i] = r; r += v; }
  }
  __syncthreads();
  int r = part[t];
  for (int i = lo; i < hi; i++) { rowstart[i] = r; cur[i] = r; r += cnt[i]; }
}

__global__ __launch_bounds__(256) void csr_fill(
    const int* __restrict__ edge, int* __restrict__ cur, int* __restrict__ elist, int nE) {
  int e = blockIdx.x * blockDim.x + threadIdx.x;
  if (e < nE) {
    int d = edge[2 * e];
    int p = atomicAdd(&cur[d], 1);
    elist[p] = e;
  }
}

// ---------------- edge geometry pack ----------------
__global__ __launch_bounds__(256) void edge_pack(
    const int* __restrict__ elist, const int* __restrict__ edge,
    const float* __restrict__ edist, const float* __restrict__ ediff,
    int* __restrict__ srcs, float* __restrict__ geo, int nE) {
  int j = blockIdx.x * blockDim.x + threadIdx.x;
  if (j >= nE) return;
  int e = elist[j];
  srcs[j] = edge[2 * e + 1];
  float d = edist[e];
  float inv = 1.0f / d;
  float th = d * (PI_F / CUT);
  float s1 = sinf(th), c1 = cosf(th);
  float fc = (d < CUT) ? 0.5f * (c1 + 1.0f) : 0.0f;
  float* g = geo + (size_t)j * 24;
  float twoc = 2.0f * c1;
  float skp = 0.0f, sk = s1;
  #pragma unroll
  for (int k = 0; k < E_RBF; k++) {
    g[k] = sk * inv * fc;
    float nx = twoc * sk - skp;
    skp = sk; sk = nx;
  }
  g[20] = ediff[3 * (size_t)e] * inv;
  g[21] = ediff[3 * (size_t)e + 1] * inv;
  g[22] = ediff[3 * (size_t)e + 2] * inv;
  g[23] = fc;
}

// ---------------- node init (fp32 + bf16 shadow) ----------------
__global__ __launch_bounds__(H) void node_init(
    const int* __restrict__ z, const float* __restrict__ embed,
    float* __restrict__ ns, bf16* __restrict__ ns16, int N) {
  int i = blockIdx.x;
  int h = threadIdx.x;
  float v = embed[(size_t)z[i] * H + h];
  ns[(size_t)i * H + h] = v;
  ns16[(size_t)i * H + h] = __float2bfloat16(v);
}

// ---------------- pack U/V weights into MFMA B-fragment layout ----------------
__global__ __launch_bounds__(256) void pack_w(
    const float* __restrict__ Wu, const float* __restrict__ Wv,
    bf16* __restrict__ wp) {
  int t = blockIdx.x * blockDim.x + threadIdx.x;   // 12288 total
  if (t >= 3 * 2 * 4 * 8 * 64) return;
  int lane = t & 63;
  int c    = (t >> 6) & 7;
  int kb   = (t >> 9) & 3;
  int mat  = (t >> 11) & 1;
  int l    = t >> 12;
  const float* src = (mat ? Wv : Wu) + (size_t)l * H * H;
  bf16* dst = wp + ((size_t)(l * 2 + mat) * 16384) + (((kb * 8 + c) * 64 + lane) * 8);
  int quad = lane >> 4;
  int n = c * 16 + (lane & 15);
  #pragma unroll
  for (int j = 0; j < 8; j++) {
    int k = kb * 32 + quad * 8 + j;
    dst[j] = __float2bfloat16(src[(size_t)k * H + n]);
  }
}

// ---------------- generic B-fragment packer ----------------
__global__ __launch_bounds__(256) void pack_b(
    const float* __restrict__ src, bf16* __restrict__ dst,
    int K, int ncols, int L) {
  int kblocks = K >> 5, ncols16 = ncols >> 4;
  int total = L * kblocks * ncols16 * 64;
  int t = blockIdx.x * blockDim.x + threadIdx.x;
  if (t >= total) return;
  int lane = t & 63;
  int idx = t >> 6;
  int c = idx % ncols16; idx /= ncols16;
  int kb = idx % kblocks; idx /= kblocks;
  int l = idx;
  const float* s = src + (size_t)l * K * ncols;
  bf16* d = dst + (size_t)l * K * ncols + (((kb * ncols16 + c) * 64 + lane) * 8);
  int quad = lane >> 4;
  int n = c * 16 + (lane & 15);
  #pragma unroll
  for (int j = 0; j < 8; j++) {
    int k = kb * 32 + quad * 8 + j;
    d[j] = __float2bfloat16(s[(size_t)k * ncols + n]);
  }
}

// ---------------- MFMA dual GEMM: Uv/Vv ----------------
__global__ __launch_bounds__(256) void gemm_uv_mfma(
    const bf16* __restrict__ A, const bf16* __restrict__ Wp,
    const float* __restrict__ bu, const float* __restrict__ bv,
    float* __restrict__ Cu, float* __restrict__ Cv, int M) {
  int wave = threadIdx.x >> 6;
  int lane = threadIdx.x & 63;
  int r0 = blockIdx.x * 64 + wave * 16;
  int quad = lane >> 4;
  int nn = lane & 15;
  int arow = r0 + nn;
  if (arow >= M) arow = M - 1;
  f32x4 accu[8] = {};
  f32x4 accv[8] = {};
  for (int kb = 0; kb < 4; kb++) {
    bf16x8 af = *(const bf16x8*)&A[(size_t)arow * H + kb * 32 + quad * 8];
    #pragma unroll
    for (int c = 0; c < 8; c++) {
      bf16x8 bfu = *(const bf16x8*)&Wp[(((kb * 8 + c) * 64) + lane) * 8];
      bf16x8 bfv = *(const bf16x8*)&Wp[16384 + (((kb * 8 + c) * 64) + lane) * 8];
      accu[c] = __builtin_amdgcn_mfma_f32_16x16x32_bf16(af, bfu, accu[c], 0, 0, 0);
      accv[c] = __builtin_amdgcn_mfma_f32_16x16x32_bf16(af, bfv, accv[c], 0, 0, 0);
    }
  }
  #pragma unroll
  for (int c = 0; c < 8; c++) {
    int n = c * 16 + nn;
    float bub = bu[n], bvb = bv[n];
    #pragma unroll
    for (int r = 0; r < 4; r++) {
      int row = r0 + quad * 4 + r;
      if (row < M) {
        Cu[(size_t)row * H + n] = accu[c][r] + bub;
        Cv[(size_t)row * H + n] = accv[c][r] + bvb;
      }
    }
  }
}

// ---------------- vnorm -> A2[:,0:128] bf16 ----------------
__global__ __launch_bounds__(256) void vnorm_a2(
    const float* __restrict__ Vv, bf16* __restrict__ A2, int N) {
  int t = blockIdx.x * blockDim.x + threadIdx.x;
  if (t >= N * H) return;
  int i = t >> 7, h = t & 127;
  float v0 = Vv[(size_t)(3 * i + 0) * H + h];
  float v1 = Vv[(size_t)(3 * i + 1) * H + h];
  float v2 = Vv[(size_t)(3 * i + 2) * H + h];
  A2[(size_t)i * 256 + h] = __float2bfloat16(sqrtf(v0 * v0 + v1 * v1 + v2 * v2));
}

// ---------------- generic MFMA stage-1: out = silu(A@W+b) -> bf16, 128 cols ----------------
template<int KB>
__global__ __launch_bounds__(256) void gemm_silu_mfma(
    const bf16* __restrict__ A, const bf16* __restrict__ Wp,
    const float* __restrict__ bias, bf16* __restrict__ out, int M) {
  int wave = threadIdx.x >> 6, lane = threadIdx.x & 63;
  int rowg = wave >> 1, ch = wave & 1;
  int r0 = blockIdx.x * 32 + rowg * 16;
  int quad = lane >> 4, nn = lane & 15;
  int arow = r0 + nn; if (arow >= M) arow = M - 1;
  f32x4 acc[4] = {};
  for (int kb = 0; kb < KB; kb++) {
    bf16x8 af = *(const bf16x8*)&A[(size_t)arow * (KB * 32) + kb * 32 + quad * 8];
    #pragma unroll
    for (int c = 0; c < 4; c++) {
      int cg = ch * 4 + c;
      bf16x8 bw = *(const bf16x8*)&Wp[(((kb * 8 + cg) * 64) + lane) * 8];
      acc[c] = __builtin_amdgcn_mfma_f32_16x16x32_bf16(af, bw, acc[c], 0, 0, 0);
    }
  }
  #pragma unroll
  for (int c = 0; c < 4; c++) {
    int n = (ch * 4 + c) * 16 + nn;
    float bb = bias[n];
    #pragma unroll
    for (int r = 0; r < 4; r++) {
      int row = r0 + quad * 4 + r;
      if (row < M) out[(size_t)row * H + n] = __float2bfloat16(silu_f(acc[c][r] + bb));
    }
  }
}

// ---------------- MFMA stage-2, 384 cols -> bf16 (scalar-MLP "so") ----------------
__global__ __launch_bounds__(256) void gemm_so_mfma(
    const bf16* __restrict__ m1, const bf16* __restrict__ Wp,
    const float* __restrict__ b2, bf16* __restrict__ so, int M) {
  int wave = threadIdx.x >> 6, lane = threadIdx.x & 63;
  int rowg = wave >> 1, ch = wave & 1;
  int r0 = blockIdx.x * 32 + rowg * 16;
  int quad = lane >> 4, nn = lane & 15;
  int arow = r0 + nn; if (arow >= M) arow = M - 1;
  f32x4 a0[4] = {}, a1[4] = {}, a2[4] = {};
  for (int kb = 0; kb < 4; kb++) {
    bf16x8 af = *(const bf16x8*)&m1[(size_t)arow * H + kb * 32 + quad * 8];
    #pragma unroll
    for (int c = 0; c < 4; c++) {
      int cg = ch * 4 + c;
      bf16x8 b0 = *(const bf16x8*)&Wp[(((kb * 24 + cg) * 64) + lane) * 8];
      bf16x8 b1v = *(const bf16x8*)&Wp[(((kb * 24 + cg + 8) * 64) + lane) * 8];
      bf16x8 b2v = *(const bf16x8*)&Wp[(((kb * 24 + cg + 16) * 64) + lane) * 8];
      a0[c] = __builtin_amdgcn_mfma_f32_16x16x32_bf16(af, b0, a0[c], 0, 0, 0);
      a1[c] = __builtin_amdgcn_mfma_f32_16x16x32_bf16(af, b1v, a1[c], 0, 0, 0);
      a2[c] = __builtin_amdgcn_mfma_f32_16x16x32_bf16(af, b2v, a2[c], 0, 0, 0);
    }
  }
  #pragma unroll
  for (int c = 0; c < 4; c++) {
    int n = (ch * 4 + c) * 16 + nn;
    float bb0 = b2[n], bb1 = b2[H + n], bb2 = b2[2 * H + n];
    #pragma unroll
    for (int r = 0; r < 4; r++) {
      int row = r0 + quad * 4 + r;
      if (row < M) {
        so[(size_t)row * F3H + n]           = __float2bfloat16(a0[c][r] + bb0);
        so[(size_t)row * F3H + H + n]       = __float2bfloat16(a1[c][r] + bb1);
        so[(size_t)row * F3H + 2 * H + n]   = __float2bfloat16(a2[c][r] + bb2);
      }
    }
  }
}

// ---------------- MFMA stage-2, 128 cols -> fp32 (readout) ----------------
__global__ __launch_bounds__(256) void gemm_ro2_mfma(
    const bf16* __restrict__ m1, const bf16* __restrict__ Wp,
    const float* __restrict__ b2, float* __restrict__ out, int M) {
  int wave = threadIdx.x >> 6, lane = threadIdx.x & 63;
  int rowg = wave >> 1, ch = wave & 1;
  int r0 = blockIdx.x * 32 + rowg * 16;
  int quad = lane >> 4, nn = lane & 15;
  int arow = r0 + nn; if (arow >= M) arow = M - 1;
  f32x4 acc[4] = {};
  for (int kb = 0; kb < 4; kb++) {
    bf16x8 af = *(const bf16x8*)&m1[(size_t)arow * H + kb * 32 + quad * 8];
    #pragma unroll
    for (int c = 0; c < 4; c++) {
      int cg = ch * 4 + c;
      bf16x8 bw = *(const bf16x8*)&Wp[(((kb * 8 + cg) * 64) + lane) * 8];
      acc[c] = __builtin_amdgcn_mfma_f32_16x16x32_bf16(af, bw, acc[c], 0, 0, 0);
    }
  }
  #pragma unroll
  for (int c = 0; c < 4; c++) {
    int n = (ch * 4 + c) * 16 + nn;
    float bb = b2[n];
    #pragma unroll
    for (int r = 0; r < 4; r++) {
      int row = r0 + quad * 4 + r;
      if (row < M) out[(size_t)row * H + n] = acc[c][r] + bb;
    }
  }
}

// ---------------- MFMA update-MLP stage 2 + gating epilogue (+ns16) ----------------
__global__ __launch_bounds__(256) void gemm_mo_ep(
    const bf16* __restrict__ m1, const bf16* __restrict__ Wp,
    const float* __restrict__ b2,
    float* __restrict__ ns, bf16* __restrict__ ns16,
    float* __restrict__ nv, bf16* __restrict__ nvb16,
    const float* __restrict__ Uv, const float* __restrict__ Vv, int M) {
  int wave = threadIdx.x >> 6, lane = threadIdx.x & 63;
  int rowg = wave >> 1, ch = wave & 1;
  int r0 = blockIdx.x * 32 + rowg * 16;
  int quad = lane >> 4, nn = lane & 15;
  int arow = r0 + nn; if (arow >= M) arow = M - 1;
  f32x4 aav[4] = {}, aas[4] = {}, asz[4] = {};
  for (int kb = 0; kb < 4; kb++) {
    bf16x8 af = *(const bf16x8*)&m1[(size_t)arow * H + kb * 32 + quad * 8];
    #pragma unroll
    for (int c = 0; c < 4; c++) {
      int cg = ch * 4 + c;
      bf16x8 b0 = *(const bf16x8*)&Wp[(((kb * 24 + cg) * 64) + lane) * 8];
      bf16x8 b1v = *(const bf16x8*)&Wp[(((kb * 24 + cg + 8) * 64) + lane) * 8];
      bf16x8 b2v = *(const bf16x8*)&Wp[(((kb * 24 + cg + 16) * 64) + lane) * 8];
      aav[c] = __builtin_amdgcn_mfma_f32_16x16x32_bf16(af, b0, aav[c], 0, 0, 0);
      aas[c] = __builtin_amdgcn_mfma_f32_16x16x32_bf16(af, b1v, aas[c], 0, 0, 0);
      asz[c] = __builtin_amdgcn_mfma_f32_16x16x32_bf16(af, b2v, asz[c], 0, 0, 0);
    }
  }
  #pragma unroll
  for (int c = 0; c < 4; c++) {
    int n = (ch * 4 + c) * 16 + nn;
    float bav = b2[n], bas = b2[H + n], bss = b2[2 * H + n];
    #pragma unroll
    for (int r = 0; r < 4; r++) {
      int row = r0 + quad * 4 + r;
      if (row < M) {
        float avv = aav[c][r] + bav;
        float asv = aas[c][r] + bas;
        float ass = asz[c][r] + bss;
        float u0 = Uv[(size_t)(3 * row + 0) * H + n];
        float u1 = Uv[(size_t)(3 * row + 1) * H + n];
        float u2 = Uv[(size_t)(3 * row + 2) * H + n];
        float v0 = Vv[(size_t)(3 * row + 0) * H + n];
        float v1 = Vv[(size_t)(3 * row + 1) * H + n];
        float v2 = Vv[(size_t)(3 * row + 2) * H + n];
        float dot = u0 * v0 + u1 * v1 + u2 * v2;
        float ns_new = ns[(size_t)row * H + n] + asv * dot + ass;
        ns[(size_t)row * H + n] = ns_new;
        ns16[(size_t)row * H + n] = __float2bfloat16(ns_new);
        float n0 = nv[(size_t)(3 * row + 0) * H + n] + avv * u0;
        float n1 = nv[(size_t)(3 * row + 1) * H + n] + avv * u1;
        float n2 = nv[(size_t)(3 * row + 2) * H + n] + avv * u2;
        nv[(size_t)(3 * row + 0) * H + n] = n0;
        nv[(size_t)(3 * row + 1) * H + n] = n1;
        nv[(size_t)(3 * row + 2) * H + n] = n2;
        nvb16[(size_t)(3 * row + 0) * H + n] = __float2bfloat16(n0);
        nvb16[(size_t)(3 * row + 1) * H + n] = __float2bfloat16(n1);
        nvb16[(size_t)(3 * row + 2) * H + n] = __float2bfloat16(n2);
      }
    }
  }
}

// ---------------- message: round-0 body, 256 threads = 2 edge-halves per node ----------------
// The two 128-thread halves process even/odd edges of the node, doubling
// in-flight gathers + resident waves (round-0 plateaued at 2.15 TB/s effective
// with occupancy 41%). LDS merge of the 4 partial accumulators at the end.
template<bool HASNV>
__global__ __launch_bounds__(256, 4) void message3(
    const int* __restrict__ srcs, const int* __restrict__ rowstart,
    const int* __restrict__ cnt, const float* __restrict__ geo,
    const float* __restrict__ Wf, const float* __restrict__ bfb,
    const bf16* __restrict__ so, const bf16* __restrict__ nvb16,
    const float* __restrict__ nvA,
    float* __restrict__ ns, float* __restrict__ nvB,
    bf16* __restrict__ nvmsg16, bf16* __restrict__ A2, int N) {
  int i = blockIdx.x;
  int h = threadIdx.x & 127;
  int half = threadIdx.x >> 7;

  float wf0[E_RBF], wf1[E_RBF], wf2[E_RBF];
  #pragma unroll
  for (int k = 0; k < E_RBF; k++) {
    wf0[k] = Wf[k * F3H + h];
    wf1[k] = Wf[k * F3H + H + h];
    wf2[k] = Wf[k * F3H + 2 * H + h];
  }
  float bb0 = bfb[h], bb1 = bfb[H + h], bb2 = bfb[2 * H + h];

  float accs = 0.0f, a0 = 0.0f, a1 = 0.0f, a2 = 0.0f;
  int jlo = rowstart[i], jcnt = cnt[i];
  for (int jj = half; jj < jcnt; jj += 2) {
    int j = jlo + jj;
    int src = srcs[j];
    const float* g = geo + (size_t)j * 24;
    float gg[24];
    #pragma unroll
    for (int q = 0; q < 6; q++) *(float4*)&gg[4 * q] = *(const float4*)&g[4 * q];

    float fc = gg[23];
    float f0 = bb0 * fc, f1 = bb1 * fc, f2 = bb2 * fc;
    #pragma unroll
    for (int k = 0; k < E_RBF; k++) {
      float rk = gg[k];
      f0 += rk * wf0[k];
      f1 += rk * wf1[k];
      f2 += rk * wf2[k];
    }
    float u0 = gg[20], u1 = gg[21], u2 = gg[22];

    const bf16* sop = so + (size_t)src * F3H;
    float gsv = f0 * b2f(sop[h]);
    float gev = f1 * b2f(sop[H + h]);
    accs += f2 * b2f(sop[2 * H + h]);

    if (HASNV) {
      const bf16* nvp = nvb16 + (size_t)src * F3H;
      a0 += b2f(nvp[h])         * gsv + gev * u0;
      a1 += b2f(nvp[H + h])     * gsv + gev * u1;
      a2 += b2f(nvp[2 * H + h]) * gsv + gev * u2;
    } else {
      a0 += gev * u0;
      a1 += gev * u1;
      a2 += gev * u2;
    }
  }

  __shared__ float red[4][H];
  if (half) {
    red[0][h] = accs; red[1][h] = a0; red[2][h] = a1; red[3][h] = a2;
  }
  __syncthreads();
  if (half) return;
  accs += red[0][h]; a0 += red[1][h]; a1 += red[2][h]; a2 += red[3][h];

  float ns_new = ns[(size_t)i * H + h] + accs;
  ns[(size_t)i * H + h] = ns_new;
  A2[(size_t)i * 256 + 128 + h] = __float2bfloat16(ns_new);
  float o0, o1, o2;
  if (HASNV) {
    const float* nvi = nvA + (size_t)i * F3H;
    o0 = nvi[h] + a0;
    o1 = nvi[H + h] + a1;
    o2 = nvi[2 * H + h] + a2;
  } else {
    o0 = a0; o1 = a1; o2 = a2;
  }
  nvB[(size_t)i * F3H + h]         = o0;
  nvB[(size_t)i * F3H + H + h]     = o1;
  nvB[(size_t)i * F3H + 2 * H + h] = o2;
  nvmsg16[(size_t)i * F3H + h]         = __float2bfloat16(o0);
  nvmsg16[(size_t)i * F3H + H + h]     = __float2bfloat16(o1);
  nvmsg16[(size_t)i * F3H + 2 * H + h] = __float2bfloat16(o2);
}

extern "C" void kernel_launch(void* const* d_in, const int* in_sizes, int n_in,
                              void* d_out, int out_size, void* d_ws, size_t ws_size,
                              hipStream_t stream) {
  const int*   z     = (const int*)d_in[0];
  const int*   edge  = (const int*)d_in[1];
  const float* ediff = (const float*)d_in[2];
  const float* edist = (const float*)d_in[3];
  const float* embed = (const float*)d_in[4];
  const float* mfw   = (const float*)d_in[5];
  const float* mfb   = (const float*)d_in[6];
  const float* mw1   = (const float*)d_in[7];
  const float* mb1   = (const float*)d_in[8];
  const float* mw2   = (const float*)d_in[9];
  const float* mb2   = (const float*)d_in[10];
  const float* uUw   = (const float*)d_in[11];
  const float* uUb   = (const float*)d_in[12];
  const float* uVw   = (const float*)d_in[13];
  const float* uVb   = (const float*)d_in[14];
  const float* uw1   = (const float*)d_in[15];
  const float* ub1   = (const float*)d_in[16];
  const float* uw2   = (const float*)d_in[17];
  const float* ub2   = (const float*)d_in[18];
  const float* rw1   = (const float*)d_in[19];
  const float* rb1   = (const float*)d_in[20];
  const float* rw2   = (const float*)d_in[21];
  const float* rb2   = (const float*)d_in[22];

  const int N  = in_sizes[0];   // 10000
  const int nE = in_sizes[3];   // 160000

  float* ws = (float*)d_ws;
  size_t off = 0;
  float* ns      = ws + off; off += (size_t)N * H;
  float* nvA     = ws + off; off += (size_t)N * F3H;
  float* nvB     = ws + off; off += (size_t)N * F3H;
  float* Vv      = ws + off; off += (size_t)N * F3H;
  float* geo     = ws + off; off += (size_t)nE * 24;
  bf16* so       = (bf16*)(ws + off); off += (size_t)N * F3H / 2;
  bf16* nvb16    = (bf16*)(ws + off); off += (size_t)N * F3H / 2;
  bf16* nvmsg16  = (bf16*)(ws + off); off += (size_t)N * F3H / 2;
  bf16* A2       = (bf16*)(ws + off); off += (size_t)N * 128;       // N*256 bf16
  bf16* m1buf    = (bf16*)(ws + off); off += (size_t)N * 64;        // N*128 bf16
  bf16* ns16     = (bf16*)(ws + off); off += (size_t)N * 64;        // N*128 bf16
  bf16* wpack    = (bf16*)(ws + off); off += 3 * 2 * 16384 / 2;     // UV
  bf16* wp_m1    = (bf16*)(ws + off); off += 3 * 256 * 128 / 2;
  bf16* wp_m2    = (bf16*)(ws + off); off += 3 * 128 * 384 / 2;
  bf16* wp_sm1   = (bf16*)(ws + off); off += 3 * 128 * 128 / 2;
  bf16* wp_sm2   = (bf16*)(ws + off); off += 3 * 128 * 384 / 2;
  bf16* wp_ro1   = (bf16*)(ws + off); off += 128 * 128 / 2;
  bf16* wp_ro2   = (bf16*)(ws + off); off += 128 * 128 / 2;
  int* srcs     = (int*)(ws + off); off += nE;
  int* cnt      = (int*)(ws + off); off += N;
  int* rowstart = (int*)(ws + off); off += N;
  int* cur      = (int*)(ws + off); off += N;
  int* elist    = (int*)(ws + off); off += nE;

  const int tilesN = (N + 31) / 32;            // 313
  const int uvBlks = (3 * N + 63) / 64;        // 469

  (void)hipMemsetAsync(cnt, 0, (size_t)N * sizeof(int), stream);
  csr_hist<<<(nE + 255) / 256, 256, 0, stream>>>(edge, cnt, nE);
  csr_scan<<<1, 256, 0, stream>>>(cnt, rowstart, cur, N);
  csr_fill<<<(nE + 255) / 256, 256, 0, stream>>>(edge, cur, elist, nE);
  edge_pack<<<(nE + 255) / 256, 256, 0, stream>>>(elist, edge, edist, ediff, srcs, geo, nE);
  pack_w<<<48, 256, 0, stream>>>(uUw, uVw, wpack);
  pack_b<<<48, 256, 0, stream>>>(uw1, wp_m1, 256, 128, 3);
  pack_b<<<72, 256, 0, stream>>>(uw2, wp_m2, 128, 384, 3);
  pack_b<<<24, 256, 0, stream>>>(mw1, wp_sm1, 128, 128, 3);
  pack_b<<<72, 256, 0, stream>>>(mw2, wp_sm2, 128, 384, 3);
  pack_b<<<8, 256, 0, stream>>>(rw1, wp_ro1, 128, 128, 1);
  pack_b<<<8, 256, 0, stream>>>(rw2, wp_ro2, 128, 128, 1);

  node_init<<<N, H, 0, stream>>>(z, embed, ns, ns16, N);

  float* nv_cur = nvA;
  float* nv_nxt = nvB;
  for (int l = 0; l < NLAYER; l++) {
    // scalar message MLP (MFMA): m1 = silu(ns16@mw1+mb1); so = m1@mw2+mb2
    gemm_silu_mfma<4><<<tilesN, 256, 0, stream>>>(
        ns16, wp_sm1 + (size_t)l * 128 * 128, mb1 + (size_t)l * H, m1buf, N);
    gemm_so_mfma<<<tilesN, 256, 0, stream>>>(
        m1buf, wp_sm2 + (size_t)l * 128 * 384, mb2 + (size_t)l * F3H, so, N);

    if (l == 0)
      message3<false><<<N, 256, 0, stream>>>(srcs, rowstart, cnt, geo,
                                           mfw + (size_t)l * E_RBF * F3H, mfb + (size_t)l * F3H,
                                           so, nvb16, nv_cur, ns, nv_nxt, nvmsg16, A2, N);
    else
      message3<true><<<N, 256, 0, stream>>>(srcs, rowstart, cnt, geo,
                                          mfw + (size_t)l * E_RBF * F3H, mfb + (size_t)l * F3H,
                                          so, nvb16, nv_cur, ns, nv_nxt, nvmsg16, A2, N);

    float* Uv = nv_cur;  // dead after message3 — reuse as Uv scratch
    gemm_uv_mfma<<<uvBlks, 256, 0, stream>>>(
        nvmsg16, wpack + (size_t)l * 2 * 16384,
        uUb + (size_t)l * H, uVb + (size_t)l * H,
        Uv, Vv, 3 * N);

    vnorm_a2<<<(N * H + 255) / 256, 256, 0, stream>>>(Vv, A2, N);
    gemm_silu_mfma<8><<<tilesN, 256, 0, stream>>>(
        A2, wp_m1 + (size_t)l * 256 * 128, ub1 + (size_t)l * H, m1buf, N);
    gemm_mo_ep<<<tilesN, 256, 0, stream>>>(
        m1buf, wp_m2 + (size_t)l * 128 * 384, ub2 + (size_t)l * F3H,
        ns, ns16, nv_nxt, nvb16, Uv, Vv, N);

    float* t = nv_cur; nv_cur = nv_nxt; nv_nxt = t;
  }

  gemm_silu_mfma<4><<<tilesN, 256, 0, stream>>>(ns16, wp_ro1, rb1, m1buf, N);
  gemm_ro2_mfma<<<tilesN, 256, 0, stream>>>(m1buf, wp_ro2, rb2, (float*)d_out, N);
}

// Round 3
// 580.655 us; speedup vs baseline: 1.1739x; 1.1739x over previous
//
#include <hip/hip_runtime.h>
#include <hip/hip_bf16.h>

typedef __hip_bfloat16 bf16;
typedef __attribute__((ext_vector_type(8))) short bf16x8;
typedef __attribute__((ext_vector_type(4))) float f32x4;

#define H 128
#define F3H 384
#define E_RBF 20
#define NLAYER 3

__device__ __forceinline__ float silu_f(float x) { return x / (1.0f + __expf(-x)); }
__device__ __forceinline__ float b2f(bf16 x) { return __bfloat162float(x); }
__device__ __forceinline__ float blo(unsigned u) { return __uint_as_float(u << 16); }
__device__ __forceinline__ float bhi(unsigned u) { return __uint_as_float(u & 0xffff0000u); }

constexpr float PI_F = 3.14159265358979323846f;
constexpr float CUT = 5.0f;

// ---------------- CSR build ----------------
__global__ __launch_bounds__(256) void csr_hist(
    const int* __restrict__ edge, int* __restrict__ cnt, int nE) {
  int e = blockIdx.x * blockDim.x + threadIdx.x;
  if (e < nE) atomicAdd(&cnt[edge[2 * e]], 1);
}

__global__ __launch_bounds__(256) void csr_scan(
    const int* __restrict__ cnt, int* __restrict__ rowstart, int* __restrict__ cur, int N) {
  __shared__ int part[256];
  int t = threadIdx.x;
  int chunk = (N + 255) / 256;
  int lo = t * chunk; if (lo > N) lo = N;
  int hi = lo + chunk; if (hi > N) hi = N;
  int s = 0;
  for (int i = lo; i < hi; i++) s += cnt[i];
  part[t] = s;
  __syncthreads();
  if (t == 0) {
    int r = 0;
    for (int i = 0; i < 256; i++) { int v = part[i]; part[i] = r; r += v; }
  }
  __syncthreads();
  int r = part[t];
  for (int i = lo; i < hi; i++) { rowstart[i] = r; cur[i] = r; r += cnt[i]; }
}

__global__ __launch_bounds__(256) void csr_fill(
    const int* __restrict__ edge, int* __restrict__ cur, int* __restrict__ elist, int nE) {
  int e = blockIdx.x * blockDim.x + threadIdx.x;
  if (e < nE) {
    int d = edge[2 * e];
    int p = atomicAdd(&cur[d], 1);
    elist[p] = e;
  }
}

// ---------------- edge geometry pack ----------------
__global__ __launch_bounds__(256) void edge_pack(
    const int* __restrict__ elist, const int* __restrict__ edge,
    const float* __restrict__ edist, const float* __restrict__ ediff,
    int* __restrict__ srcs, float* __restrict__ geo, int nE) {
  int j = blockIdx.x * blockDim.x + threadIdx.x;
  if (j >= nE) return;
  int e = elist[j];
  srcs[j] = edge[2 * e + 1];
  float d = edist[e];
  float inv = 1.0f / d;
  float th = d * (PI_F / CUT);
  float s1 = sinf(th), c1 = cosf(th);
  float fc = (d < CUT) ? 0.5f * (c1 + 1.0f) : 0.0f;
  float* g = geo + (size_t)j * 24;
  float twoc = 2.0f * c1;
  float skp = 0.0f, sk = s1;
  #pragma unroll
  for (int k = 0; k < E_RBF; k++) {
    g[k] = sk * inv * fc;
    float nx = twoc * sk - skp;
    skp = sk; sk = nx;
  }
  g[20] = ediff[3 * (size_t)e] * inv;
  g[21] = ediff[3 * (size_t)e + 1] * inv;
  g[22] = ediff[3 * (size_t)e + 2] * inv;
  g[23] = fc;
}

// ---------------- node init (fp32 + bf16 shadow) ----------------
__global__ __launch_bounds__(H) void node_init(
    const int* __restrict__ z, const float* __restrict__ embed,
    float* __restrict__ ns, bf16* __restrict__ ns16, int N) {
  int i = blockIdx.x;
  int h = threadIdx.x;
  float v = embed[(size_t)z[i] * H + h];
  ns[(size_t)i * H + h] = v;
  ns16[(size_t)i * H + h] = __float2bfloat16(v);
}

// ---------------- pack U/V weights into MFMA B-fragment layout ----------------
__global__ __launch_bounds__(256) void pack_w(
    const float* __restrict__ Wu, const float* __restrict__ Wv,
    bf16* __restrict__ wp) {
  int t = blockIdx.x * blockDim.x + threadIdx.x;   // 12288 total
  if (t >= 3 * 2 * 4 * 8 * 64) return;
  int lane = t & 63;
  int c    = (t >> 6) & 7;
  int kb   = (t >> 9) & 3;
  int mat  = (t >> 11) & 1;
  int l    = t >> 12;
  const float* src = (mat ? Wv : Wu) + (size_t)l * H * H;
  bf16* dst = wp + ((size_t)(l * 2 + mat) * 16384) + (((kb * 8 + c) * 64 + lane) * 8);
  int quad = lane >> 4;
  int n = c * 16 + (lane & 15);
  #pragma unroll
  for (int j = 0; j < 8; j++) {
    int k = kb * 32 + quad * 8 + j;
    dst[j] = __float2bfloat16(src[(size_t)k * H + n]);
  }
}

// ---------------- generic B-fragment packer ----------------
__global__ __launch_bounds__(256) void pack_b(
    const float* __restrict__ src, bf16* __restrict__ dst,
    int K, int ncols, int L) {
  int kblocks = K >> 5, ncols16 = ncols >> 4;
  int total = L * kblocks * ncols16 * 64;
  int t = blockIdx.x * blockDim.x + threadIdx.x;
  if (t >= total) return;
  int lane = t & 63;
  int idx = t >> 6;
  int c = idx % ncols16; idx /= ncols16;
  int kb = idx % kblocks; idx /= kblocks;
  int l = idx;
  const float* s = src + (size_t)l * K * ncols;
  bf16* d = dst + (size_t)l * K * ncols + (((kb * ncols16 + c) * 64 + lane) * 8);
  int quad = lane >> 4;
  int n = c * 16 + (lane & 15);
  #pragma unroll
  for (int j = 0; j < 8; j++) {
    int k = kb * 32 + quad * 8 + j;
    d[j] = __float2bfloat16(s[(size_t)k * ncols + n]);
  }
}

// ---------------- MFMA dual GEMM: Uv/Vv ----------------
__global__ __launch_bounds__(256) void gemm_uv_mfma(
    const bf16* __restrict__ A, const bf16* __restrict__ Wp,
    const float* __restrict__ bu, const float* __restrict__ bv,
    float* __restrict__ Cu, float* __restrict__ Cv, int M) {
  int wave = threadIdx.x >> 6;
  int lane = threadIdx.x & 63;
  int r0 = blockIdx.x * 64 + wave * 16;
  int quad = lane >> 4;
  int nn = lane & 15;
  int arow = r0 + nn;
  if (arow >= M) arow = M - 1;
  f32x4 accu[8] = {};
  f32x4 accv[8] = {};
  for (int kb = 0; kb < 4; kb++) {
    bf16x8 af = *(const bf16x8*)&A[(size_t)arow * H + kb * 32 + quad * 8];
    #pragma unroll
    for (int c = 0; c < 8; c++) {
      bf16x8 bfu = *(const bf16x8*)&Wp[(((kb * 8 + c) * 64) + lane) * 8];
      bf16x8 bfv = *(const bf16x8*)&Wp[16384 + (((kb * 8 + c) * 64) + lane) * 8];
      accu[c] = __builtin_amdgcn_mfma_f32_16x16x32_bf16(af, bfu, accu[c], 0, 0, 0);
      accv[c] = __builtin_amdgcn_mfma_f32_16x16x32_bf16(af, bfv, accv[c], 0, 0, 0);
    }
  }
  #pragma unroll
  for (int c = 0; c < 8; c++) {
    int n = c * 16 + nn;
    float bub = bu[n], bvb = bv[n];
    #pragma unroll
    for (int r = 0; r < 4; r++) {
      int row = r0 + quad * 4 + r;
      if (row < M) {
        Cu[(size_t)row * H + n] = accu[c][r] + bub;
        Cv[(size_t)row * H + n] = accv[c][r] + bvb;
      }
    }
  }
}

// ---------------- vnorm -> A2[:,0:128] bf16 ----------------
__global__ __launch_bounds__(256) void vnorm_a2(
    const float* __restrict__ Vv, bf16* __restrict__ A2, int N) {
  int t = blockIdx.x * blockDim.x + threadIdx.x;
  if (t >= N * H) return;
  int i = t >> 7, h = t & 127;
  float v0 = Vv[(size_t)(3 * i + 0) * H + h];
  float v1 = Vv[(size_t)(3 * i + 1) * H + h];
  float v2 = Vv[(size_t)(3 * i + 2) * H + h];
  A2[(size_t)i * 256 + h] = __float2bfloat16(sqrtf(v0 * v0 + v1 * v1 + v2 * v2));
}

// ---------------- generic MFMA stage-1: out = silu(A@W+b) -> bf16, 128 cols ----------------
template<int KB>
__global__ __launch_bounds__(256) void gemm_silu_mfma(
    const bf16* __restrict__ A, const bf16* __restrict__ Wp,
    const float* __restrict__ bias, bf16* __restrict__ out, int M) {
  int wave = threadIdx.x >> 6, lane = threadIdx.x & 63;
  int rowg = wave >> 1, ch = wave & 1;
  int r0 = blockIdx.x * 32 + rowg * 16;
  int quad = lane >> 4, nn = lane & 15;
  int arow = r0 + nn; if (arow >= M) arow = M - 1;
  f32x4 acc[4] = {};
  for (int kb = 0; kb < KB; kb++) {
    bf16x8 af = *(const bf16x8*)&A[(size_t)arow * (KB * 32) + kb * 32 + quad * 8];
    #pragma unroll
    for (int c = 0; c < 4; c++) {
      int cg = ch * 4 + c;
      bf16x8 bw = *(const bf16x8*)&Wp[(((kb * 8 + cg) * 64) + lane) * 8];
      acc[c] = __builtin_amdgcn_mfma_f32_16x16x32_bf16(af, bw, acc[c], 0, 0, 0);
    }
  }
  #pragma unroll
  for (int c = 0; c < 4; c++) {
    int n = (ch * 4 + c) * 16 + nn;
    float bb = bias[n];
    #pragma unroll
    for (int r = 0; r < 4; r++) {
      int row = r0 + quad * 4 + r;
      if (row < M) out[(size_t)row * H + n] = __float2bfloat16(silu_f(acc[c][r] + bb));
    }
  }
}

// ---------------- MFMA stage-2, 384 cols -> packed gather layout [node][h][3] ----------------
__global__ __launch_bounds__(256) void gemm_so_mfma(
    const bf16* __restrict__ m1, const bf16* __restrict__ Wp,
    const float* __restrict__ b2, bf16* __restrict__ so, int M) {
  int wave = threadIdx.x >> 6, lane = threadIdx.x & 63;
  int rowg = wave >> 1, ch = wave & 1;
  int r0 = blockIdx.x * 32 + rowg * 16;
  int quad = lane >> 4, nn = lane & 15;
  int arow = r0 + nn; if (arow >= M) arow = M - 1;
  f32x4 a0[4] = {}, a1[4] = {}, a2[4] = {};
  for (int kb = 0; kb < 4; kb++) {
    bf16x8 af = *(const bf16x8*)&m1[(size_t)arow * H + kb * 32 + quad * 8];
    #pragma unroll
    for (int c = 0; c < 4; c++) {
      int cg = ch * 4 + c;
      bf16x8 b0 = *(const bf16x8*)&Wp[(((kb * 24 + cg) * 64) + lane) * 8];
      bf16x8 b1v = *(const bf16x8*)&Wp[(((kb * 24 + cg + 8) * 64) + lane) * 8];
      bf16x8 b2v = *(const bf16x8*)&Wp[(((kb * 24 + cg + 16) * 64) + lane) * 8];
      a0[c] = __builtin_amdgcn_mfma_f32_16x16x32_bf16(af, b0, a0[c], 0, 0, 0);
      a1[c] = __builtin_amdgcn_mfma_f32_16x16x32_bf16(af, b1v, a1[c], 0, 0, 0);
      a2[c] = __builtin_amdgcn_mfma_f32_16x16x32_bf16(af, b2v, a2[c], 0, 0, 0);
    }
  }
  #pragma unroll
  for (int c = 0; c < 4; c++) {
    int n = (ch * 4 + c) * 16 + nn;
    float bb0 = b2[n], bb1 = b2[H + n], bb2 = b2[2 * H + n];
    #pragma unroll
    for (int r = 0; r < 4; r++) {
      int row = r0 + quad * 4 + r;
      if (row < M) {
        bf16* sp = so + ((size_t)row * H + n) * 3;
        sp[0] = __float2bfloat16(a0[c][r] + bb0);
        sp[1] = __float2bfloat16(a1[c][r] + bb1);
        sp[2] = __float2bfloat16(a2[c][r] + bb2);
      }
    }
  }
}

// ---------------- MFMA stage-2, 128 cols -> fp32 (readout) ----------------
__global__ __launch_bounds__(256) void gemm_ro2_mfma(
    const bf16* __restrict__ m1, const bf16* __restrict__ Wp,
    const float* __restrict__ b2, float* __restrict__ out, int M) {
  int wave = threadIdx.x >> 6, lane = threadIdx.x & 63;
  int rowg = wave >> 1, ch = wave & 1;
  int r0 = blockIdx.x * 32 + rowg * 16;
  int quad = lane >> 4, nn = lane & 15;
  int arow = r0 + nn; if (arow >= M) arow = M - 1;
  f32x4 acc[4] = {};
  for (int kb = 0; kb < 4; kb++) {
    bf16x8 af = *(const bf16x8*)&m1[(size_t)arow * H + kb * 32 + quad * 8];
    #pragma unroll
    for (int c = 0; c < 4; c++) {
      int cg = ch * 4 + c;
      bf16x8 bw = *(const bf16x8*)&Wp[(((kb * 8 + cg) * 64) + lane) * 8];
      acc[c] = __builtin_amdgcn_mfma_f32_16x16x32_bf16(af, bw, acc[c], 0, 0, 0);
    }
  }
  #pragma unroll
  for (int c = 0; c < 4; c++) {
    int n = (ch * 4 + c) * 16 + nn;
    float bb = b2[n];
    #pragma unroll
    for (int r = 0; r < 4; r++) {
      int row = r0 + quad * 4 + r;
      if (row < M) out[(size_t)row * H + n] = acc[c][r] + bb;
    }
  }
}

// ---------------- MFMA update-MLP stage 2 + gating epilogue (+ns16) ----------------
__global__ __launch_bounds__(256) void gemm_mo_ep(
    const bf16* __restrict__ m1, const bf16* __restrict__ Wp,
    const float* __restrict__ b2,
    float* __restrict__ ns, bf16* __restrict__ ns16,
    float* __restrict__ nv, bf16* __restrict__ nvb16,
    const float* __restrict__ Uv, const float* __restrict__ Vv, int M) {
  int wave = threadIdx.x >> 6, lane = threadIdx.x & 63;
  int rowg = wave >> 1, ch = wave & 1;
  int r0 = blockIdx.x * 32 + rowg * 16;
  int quad = lane >> 4, nn = lane & 15;
  int arow = r0 + nn; if (arow >= M) arow = M - 1;
  f32x4 aav[4] = {}, aas[4] = {}, asz[4] = {};
  for (int kb = 0; kb < 4; kb++) {
    bf16x8 af = *(const bf16x8*)&m1[(size_t)arow * H + kb * 32 + quad * 8];
    #pragma unroll
    for (int c = 0; c < 4; c++) {
      int cg = ch * 4 + c;
      bf16x8 b0 = *(const bf16x8*)&Wp[(((kb * 24 + cg) * 64) + lane) * 8];
      bf16x8 b1v = *(const bf16x8*)&Wp[(((kb * 24 + cg + 8) * 64) + lane) * 8];
      bf16x8 b2v = *(const bf16x8*)&Wp[(((kb * 24 + cg + 16) * 64) + lane) * 8];
      aav[c] = __builtin_amdgcn_mfma_f32_16x16x32_bf16(af, b0, aav[c], 0, 0, 0);
      aas[c] = __builtin_amdgcn_mfma_f32_16x16x32_bf16(af, b1v, aas[c], 0, 0, 0);
      asz[c] = __builtin_amdgcn_mfma_f32_16x16x32_bf16(af, b2v, asz[c], 0, 0, 0);
    }
  }
  #pragma unroll
  for (int c = 0; c < 4; c++) {
    int n = (ch * 4 + c) * 16 + nn;
    float bav = b2[n], bas = b2[H + n], bss = b2[2 * H + n];
    #pragma unroll
    for (int r = 0; r < 4; r++) {
      int row = r0 + quad * 4 + r;
      if (row < M) {
        float avv = aav[c][r] + bav;
        float asv = aas[c][r] + bas;
        float ass = asz[c][r] + bss;
        float u0 = Uv[(size_t)(3 * row + 0) * H + n];
        float u1 = Uv[(size_t)(3 * row + 1) * H + n];
        float u2 = Uv[(size_t)(3 * row + 2) * H + n];
        float v0 = Vv[(size_t)(3 * row + 0) * H + n];
        float v1 = Vv[(size_t)(3 * row + 1) * H + n];
        float v2 = Vv[(size_t)(3 * row + 2) * H + n];
        float dot = u0 * v0 + u1 * v1 + u2 * v2;
        float ns_new = ns[(size_t)row * H + n] + asv * dot + ass;
        ns[(size_t)row * H + n] = ns_new;
        ns16[(size_t)row * H + n] = __float2bfloat16(ns_new);
        float n0 = nv[(size_t)(3 * row + 0) * H + n] + avv * u0;
        float n1 = nv[(size_t)(3 * row + 1) * H + n] + avv * u1;
        float n2 = nv[(size_t)(3 * row + 2) * H + n] + avv * u2;
        nv[(size_t)(3 * row + 0) * H + n] = n0;
        nv[(size_t)(3 * row + 1) * H + n] = n1;
        nv[(size_t)(3 * row + 2) * H + n] = n2;
        bf16* nq = nvb16 + ((size_t)row * H + n) * 3;
        nq[0] = __float2bfloat16(n0);
        nq[1] = __float2bfloat16(n1);
        nq[2] = __float2bfloat16(n2);
      }
    }
  }
}

// ---------------- message: round-0 structure; packed 6B/h gathers ----------------
// so/nvb16 layout [node][h][3] bf16: a wave's gather = one aligned contiguous
// 384B region (3 lines) per array, vs 3 scattered 128B lines in the row-major
// layout. Same byte count (no padding), better DRAM burst locality.
template<bool HASNV>
__global__ __launch_bounds__(128, 4) void message3(
    const int* __restrict__ srcs, const int* __restrict__ rowstart,
    const int* __restrict__ cnt, const float* __restrict__ geo,
    const float* __restrict__ Wf, const float* __restrict__ bfb,
    const bf16* __restrict__ so, const bf16* __restrict__ nvb16,
    const float* __restrict__ nvA,
    float* __restrict__ ns, float* __restrict__ nvB,
    bf16* __restrict__ nvmsg16, bf16* __restrict__ A2, int N) {
  int i = blockIdx.x;
  int h = threadIdx.x;

  float wf0[E_RBF], wf1[E_RBF], wf2[E_RBF];
  #pragma unroll
  for (int k = 0; k < E_RBF; k++) {
    wf0[k] = Wf[k * F3H + h];
    wf1[k] = Wf[k * F3H + H + h];
    wf2[k] = Wf[k * F3H + 2 * H + h];
  }
  float bb0 = bfb[h], bb1 = bfb[H + h], bb2 = bfb[2 * H + h];

  float accs = 0.0f, a0 = 0.0f, a1 = 0.0f, a2 = 0.0f;
  int jlo = rowstart[i], jhi = jlo + cnt[i];
  for (int j = jlo; j < jhi; j++) {
    int src = srcs[j];
    const float* g = geo + (size_t)j * 24;
    float gg[24];
    #pragma unroll
    for (int q = 0; q < 6; q++) *(float4*)&gg[4 * q] = *(const float4*)&g[4 * q];

    float fc = gg[23];
    float f0 = bb0 * fc, f1 = bb1 * fc, f2 = bb2 * fc;
    #pragma unroll
    for (int k = 0; k < E_RBF; k++) {
      float rk = gg[k];
      f0 += rk * wf0[k];
      f1 += rk * wf1[k];
      f2 += rk * wf2[k];
    }
    float u0 = gg[20], u1 = gg[21], u2 = gg[22];

    // packed gather: 6B at so + (src*128 + h)*3 bf16
    const char* sp = (const char*)so + ((size_t)src * H + h) * 6;
    unsigned w0; unsigned short w1;
    __builtin_memcpy(&w0, sp, 4);
    __builtin_memcpy(&w1, sp + 4, 2);
    float gsv = f0 * blo(w0);
    float gev = f1 * bhi(w0);
    accs += f2 * blo((unsigned)w1);

    if (HASNV) {
      const char* np = (const char*)nvb16 + ((size_t)src * H + h) * 6;
      unsigned x0; unsigned short x1;
      __builtin_memcpy(&x0, np, 4);
      __builtin_memcpy(&x1, np + 4, 2);
      a0 += blo(x0) * gsv + gev * u0;
      a1 += bhi(x0) * gsv + gev * u1;
      a2 += blo((unsigned)x1) * gsv + gev * u2;
    } else {
      a0 += gev * u0;
      a1 += gev * u1;
      a2 += gev * u2;
    }
  }

  float ns_new = ns[(size_t)i * H + h] + accs;
  ns[(size_t)i * H + h] = ns_new;
  A2[(size_t)i * 256 + 128 + h] = __float2bfloat16(ns_new);
  float o0, o1, o2;
  if (HASNV) {
    const float* nvi = nvA + (size_t)i * F3H;
    o0 = nvi[h] + a0;
    o1 = nvi[H + h] + a1;
    o2 = nvi[2 * H + h] + a2;
  } else {
    o0 = a0; o1 = a1; o2 = a2;
  }
  nvB[(size_t)i * F3H + h]         = o0;
  nvB[(size_t)i * F3H + H + h]     = o1;
  nvB[(size_t)i * F3H + 2 * H + h] = o2;
  nvmsg16[(size_t)i * F3H + h]         = __float2bfloat16(o0);
  nvmsg16[(size_t)i * F3H + H + h]     = __float2bfloat16(o1);
  nvmsg16[(size_t)i * F3H + 2 * H + h] = __float2bfloat16(o2);
}

extern "C" void kernel_launch(void* const* d_in, const int* in_sizes, int n_in,
                              void* d_out, int out_size, void* d_ws, size_t ws_size,
                              hipStream_t stream) {
  const int*   z     = (const int*)d_in[0];
  const int*   edge  = (const int*)d_in[1];
  const float* ediff = (const float*)d_in[2];
  const float* edist = (const float*)d_in[3];
  const float* embed = (const float*)d_in[4];
  const float* mfw   = (const float*)d_in[5];
  const float* mfb   = (const float*)d_in[6];
  const float* mw1   = (const float*)d_in[7];
  const float* mb1   = (const float*)d_in[8];
  const float* mw2   = (const float*)d_in[9];
  const float* mb2   = (const float*)d_in[10];
  const float* uUw   = (const float*)d_in[11];
  const float* uUb   = (const float*)d_in[12];
  const float* uVw   = (const float*)d_in[13];
  const float* uVb   = (const float*)d_in[14];
  const float* uw1   = (const float*)d_in[15];
  const float* ub1   = (const float*)d_in[16];
  const float* uw2   = (const float*)d_in[17];
  const float* ub2   = (const float*)d_in[18];
  const float* rw1   = (const float*)d_in[19];
  const float* rb1   = (const float*)d_in[20];
  const float* rw2   = (const float*)d_in[21];
  const float* rb2   = (const float*)d_in[22];

  const int N  = in_sizes[0];   // 10000
  const int nE = in_sizes[3];   // 160000

  float* ws = (float*)d_ws;
  size_t off = 0;
  float* ns      = ws + off; off += (size_t)N * H;
  float* nvA     = ws + off; off += (size_t)N * F3H;
  float* nvB     = ws + off; off += (size_t)N * F3H;
  float* Vv      = ws + off; off += (size_t)N * F3H;
  float* geo     = ws + off; off += (size_t)nE * 24;
  bf16* so       = (bf16*)(ws + off); off += (size_t)N * F3H / 2;   // N*128*3 bf16
  bf16* nvb16    = (bf16*)(ws + off); off += (size_t)N * F3H / 2;   // N*128*3 bf16
  bf16* nvmsg16  = (bf16*)(ws + off); off += (size_t)N * F3H / 2;
  bf16* A2       = (bf16*)(ws + off); off += (size_t)N * 128;       // N*256 bf16
  bf16* m1buf    = (bf16*)(ws + off); off += (size_t)N * 64;        // N*128 bf16
  bf16* ns16     = (bf16*)(ws + off); off += (size_t)N * 64;        // N*128 bf16
  bf16* wpack    = (bf16*)(ws + off); off += 3 * 2 * 16384 / 2;     // UV
  bf16* wp_m1    = (bf16*)(ws + off); off += 3 * 256 * 128 / 2;
  bf16* wp_m2    = (bf16*)(ws + off); off += 3 * 128 * 384 / 2;
  bf16* wp_sm1   = (bf16*)(ws + off); off += 3 * 128 * 128 / 2;
  bf16* wp_sm2   = (bf16*)(ws + off); off += 3 * 128 * 384 / 2;
  bf16* wp_ro1   = (bf16*)(ws + off); off += 128 * 128 / 2;
  bf16* wp_ro2   = (bf16*)(ws + off); off += 128 * 128 / 2;
  int* srcs     = (int*)(ws + off); off += nE;
  int* cnt      = (int*)(ws + off); off += N;
  int* rowstart = (int*)(ws + off); off += N;
  int* cur      = (int*)(ws + off); off += N;
  int* elist    = (int*)(ws + off); off += nE;

  const int tilesN = (N + 31) / 32;            // 313
  const int uvBlks = (3 * N + 63) / 64;        // 469

  (void)hipMemsetAsync(cnt, 0, (size_t)N * sizeof(int), stream);
  csr_hist<<<(nE + 255) / 256, 256, 0, stream>>>(edge, cnt, nE);
  csr_scan<<<1, 256, 0, stream>>>(cnt, rowstart, cur, N);
  csr_fill<<<(nE + 255) / 256, 256, 0, stream>>>(edge, cur, elist, nE);
  edge_pack<<<(nE + 255) / 256, 256, 0, stream>>>(elist, edge, edist, ediff, srcs, geo, nE);
  pack_w<<<48, 256, 0, stream>>>(uUw, uVw, wpack);
  pack_b<<<48, 256, 0, stream>>>(uw1, wp_m1, 256, 128, 3);
  pack_b<<<72, 256, 0, stream>>>(uw2, wp_m2, 128, 384, 3);
  pack_b<<<24, 256, 0, stream>>>(mw1, wp_sm1, 128, 128, 3);
  pack_b<<<72, 256, 0, stream>>>(mw2, wp_sm2, 128, 384, 3);
  pack_b<<<8, 256, 0, stream>>>(rw1, wp_ro1, 128, 128, 1);
  pack_b<<<8, 256, 0, stream>>>(rw2, wp_ro2, 128, 128, 1);

  node_init<<<N, H, 0, stream>>>(z, embed, ns, ns16, N);

  float* nv_cur = nvA;
  float* nv_nxt = nvB;
  for (int l = 0; l < NLAYER; l++) {
    // scalar message MLP (MFMA): m1 = silu(ns16@mw1+mb1); so = m1@mw2+mb2
    gemm_silu_mfma<4><<<tilesN, 256, 0, stream>>>(
        ns16, wp_sm1 + (size_t)l * 128 * 128, mb1 + (size_t)l * H, m1buf, N);
    gemm_so_mfma<<<tilesN, 256, 0, stream>>>(
        m1buf, wp_sm2 + (size_t)l * 128 * 384, mb2 + (size_t)l * F3H, so, N);

    if (l == 0)
      message3<false><<<N, H, 0, stream>>>(srcs, rowstart, cnt, geo,
                                           mfw + (size_t)l * E_RBF * F3H, mfb + (size_t)l * F3H,
                                           so, nvb16, nv_cur, ns, nv_nxt, nvmsg16, A2, N);
    else
      message3<true><<<N, H, 0, stream>>>(srcs, rowstart, cnt, geo,
                                          mfw + (size_t)l * E_RBF * F3H, mfb + (size_t)l * F3H,
                                          so, nvb16, nv_cur, ns, nv_nxt, nvmsg16, A2, N);

    float* Uv = nv_cur;  // dead after message3 — reuse as Uv scratch
    gemm_uv_mfma<<<uvBlks, 256, 0, stream>>>(
        nvmsg16, wpack + (size_t)l * 2 * 16384,
        uUb + (size_t)l * H, uVb + (size_t)l * H,
        Uv, Vv, 3 * N);

    vnorm_a2<<<(N * H + 255) / 256, 256, 0, stream>>>(Vv, A2, N);
    gemm_silu_mfma<8><<<tilesN, 256, 0, stream>>>(
        A2, wp_m1 + (size_t)l * 256 * 128, ub1 + (size_t)l * H, m1buf, N);
    gemm_mo_ep<<<tilesN, 256, 0, stream>>>(
        m1buf, wp_m2 + (size_t)l * 128 * 384, ub2 + (size_t)l * F3H,
        ns, ns16, nv_nxt, nvb16, Uv, Vv, N);

    float* t = nv_cur; nv_cur = nv_nxt; nv_nxt = t;
  }

  gemm_silu_mfma<4><<<tilesN, 256, 0, stream>>>(ns16, wp_ro1, rb1, m1buf, N);
  gemm_ro2_mfma<<<tilesN, 256, 0, stream>>>(m1buf, wp_ro2, rb2, (float*)d_out, N);
}

// Round 4
// 565.851 us; speedup vs baseline: 1.2046x; 1.0262x over previous
//
#include <hip/hip_runtime.h>
#include <hip/hip_bf16.h>

typedef __hip_bfloat16 bf16;
typedef __attribute__((ext_vector_type(8))) short bf16x8;
typedef __attribute__((ext_vector_type(4))) float f32x4;

#define H 128
#define F3H 384
#define E_RBF 20
#define NLAYER 3

__device__ __forceinline__ float silu_f(float x) { return x / (1.0f + __expf(-x)); }
__device__ __forceinline__ float b2f(bf16 x) { return __bfloat162float(x); }

constexpr float PI_F = 3.14159265358979323846f;
constexpr float CUT = 5.0f;

// ---------------- CSR build ----------------
__global__ __launch_bounds__(256) void csr_hist(
    const int* __restrict__ edge, int* __restrict__ cnt, int nE) {
  int e = blockIdx.x * blockDim.x + threadIdx.x;
  if (e < nE) atomicAdd(&cnt[edge[2 * e]], 1);
}

__global__ __launch_bounds__(256) void csr_scan(
    const int* __restrict__ cnt, int* __restrict__ rowstart, int* __restrict__ cur, int N) {
  __shared__ int part[256];
  int t = threadIdx.x;
  int chunk = (N + 255) / 256;
  int lo = t * chunk; if (lo > N) lo = N;
  int hi = lo + chunk; if (hi > N) hi = N;
  int s = 0;
  for (int i = lo; i < hi; i++) s += cnt[i];
  part[t] = s;
  __syncthreads();
  if (t == 0) {
    int r = 0;
    for (int i = 0; i < 256; i++) { int v = part[i]; part[i] = r; r += v; }
  }
  __syncthreads();
  int r = part[t];
  for (int i = lo; i < hi; i++) { rowstart[i] = r; cur[i] = r; r += cnt[i]; }
}

__global__ __launch_bounds__(256) void csr_fill(
    const int* __restrict__ edge, int* __restrict__ cur, int* __restrict__ elist, int nE) {
  int e = blockIdx.x * blockDim.x + threadIdx.x;
  if (e < nE) {
    int d = edge[2 * e];
    int p = atomicAdd(&cur[d], 1);
    elist[p] = e;
  }
}

// ---------------- edge geometry pack ----------------
__global__ __launch_bounds__(256) void edge_pack(
    const int* __restrict__ elist, const int* __restrict__ edge,
    const float* __restrict__ edist, const float* __restrict__ ediff,
    int* __restrict__ srcs, float* __restrict__ geo, int nE) {
  int j = blockIdx.x * blockDim.x + threadIdx.x;
  if (j >= nE) return;
  int e = elist[j];
  srcs[j] = edge[2 * e + 1];
  float d = edist[e];
  float inv = 1.0f / d;
  float th = d * (PI_F / CUT);
  float s1 = sinf(th), c1 = cosf(th);
  float fc = (d < CUT) ? 0.5f * (c1 + 1.0f) : 0.0f;
  float* g = geo + (size_t)j * 24;
  float twoc = 2.0f * c1;
  float skp = 0.0f, sk = s1;
  #pragma unroll
  for (int k = 0; k < E_RBF; k++) {
    g[k] = sk * inv * fc;
    float nx = twoc * sk - skp;
    skp = sk; sk = nx;
  }
  g[20] = ediff[3 * (size_t)e] * inv;
  g[21] = ediff[3 * (size_t)e + 1] * inv;
  g[22] = ediff[3 * (size_t)e + 2] * inv;
  g[23] = fc;
}

// ---------------- node init (fp32 + bf16 shadow) ----------------
__global__ __launch_bounds__(H) void node_init(
    const int* __restrict__ z, const float* __restrict__ embed,
    float* __restrict__ ns, bf16* __restrict__ ns16, int N) {
  int i = blockIdx.x;
  int h = threadIdx.x;
  float v = embed[(size_t)z[i] * H + h];
  ns[(size_t)i * H + h] = v;
  ns16[(size_t)i * H + h] = __float2bfloat16(v);
}

// ---------------- pack U/V weights into MFMA B-fragment layout ----------------
__global__ __launch_bounds__(256) void pack_w(
    const float* __restrict__ Wu, const float* __restrict__ Wv,
    bf16* __restrict__ wp) {
  int t = blockIdx.x * blockDim.x + threadIdx.x;   // 12288 total
  if (t >= 3 * 2 * 4 * 8 * 64) return;
  int lane = t & 63;
  int c    = (t >> 6) & 7;
  int kb   = (t >> 9) & 3;
  int mat  = (t >> 11) & 1;
  int l    = t >> 12;
  const float* src = (mat ? Wv : Wu) + (size_t)l * H * H;
  bf16* dst = wp + ((size_t)(l * 2 + mat) * 16384) + (((kb * 8 + c) * 64 + lane) * 8);
  int quad = lane >> 4;
  int n = c * 16 + (lane & 15);
  #pragma unroll
  for (int j = 0; j < 8; j++) {
    int k = kb * 32 + quad * 8 + j;
    dst[j] = __float2bfloat16(src[(size_t)k * H + n]);
  }
}

// ---------------- generic B-fragment packer ----------------
__global__ __launch_bounds__(256) void pack_b(
    const float* __restrict__ src, bf16* __restrict__ dst,
    int K, int ncols, int L) {
  int kblocks = K >> 5, ncols16 = ncols >> 4;
  int total = L * kblocks * ncols16 * 64;
  int t = blockIdx.x * blockDim.x + threadIdx.x;
  if (t >= total) return;
  int lane = t & 63;
  int idx = t >> 6;
  int c = idx % ncols16; idx /= ncols16;
  int kb = idx % kblocks; idx /= kblocks;
  int l = idx;
  const float* s = src + (size_t)l * K * ncols;
  bf16* d = dst + (size_t)l * K * ncols + (((kb * ncols16 + c) * 64 + lane) * 8);
  int quad = lane >> 4;
  int n = c * 16 + (lane & 15);
  #pragma unroll
  for (int j = 0; j < 8; j++) {
    int k = kb * 32 + quad * 8 + j;
    d[j] = __float2bfloat16(s[(size_t)k * ncols + n]);
  }
}

// ---------------- MFMA dual GEMM: Uv/Vv ----------------
__global__ __launch_bounds__(256) void gemm_uv_mfma(
    const bf16* __restrict__ A, const bf16* __restrict__ Wp,
    const float* __restrict__ bu, const float* __restrict__ bv,
    float* __restrict__ Cu, float* __restrict__ Cv, int M) {
  int wave = threadIdx.x >> 6;
  int lane = threadIdx.x & 63;
  int r0 = blockIdx.x * 64 + wave * 16;
  int quad = lane >> 4;
  int nn = lane & 15;
  int arow = r0 + nn;
  if (arow >= M) arow = M - 1;
  f32x4 accu[8] = {};
  f32x4 accv[8] = {};
  for (int kb = 0; kb < 4; kb++) {
    bf16x8 af = *(const bf16x8*)&A[(size_t)arow * H + kb * 32 + quad * 8];
    #pragma unroll
    for (int c = 0; c < 8; c++) {
      bf16x8 bfu = *(const bf16x8*)&Wp[(((kb * 8 + c) * 64) + lane) * 8];
      bf16x8 bfv = *(const bf16x8*)&Wp[16384 + (((kb * 8 + c) * 64) + lane) * 8];
      accu[c] = __builtin_amdgcn_mfma_f32_16x16x32_bf16(af, bfu, accu[c], 0, 0, 0);
      accv[c] = __builtin_amdgcn_mfma_f32_16x16x32_bf16(af, bfv, accv[c], 0, 0, 0);
    }
  }
  #pragma unroll
  for (int c = 0; c < 8; c++) {
    int n = c * 16 + nn;
    float bub = bu[n], bvb = bv[n];
    #pragma unroll
    for (int r = 0; r < 4; r++) {
      int row = r0 + quad * 4 + r;
      if (row < M) {
        Cu[(size_t)row * H + n] = accu[c][r] + bub;
        Cv[(size_t)row * H + n] = accv[c][r] + bvb;
      }
    }
  }
}

// ---------------- vnorm -> A2[:,0:128] bf16 ----------------
__global__ __launch_bounds__(256) void vnorm_a2(
    const float* __restrict__ Vv, bf16* __restrict__ A2, int N) {
  int t = blockIdx.x * blockDim.x + threadIdx.x;
  if (t >= N * H) return;
  int i = t >> 7, h = t & 127;
  float v0 = Vv[(size_t)(3 * i + 0) * H + h];
  float v1 = Vv[(size_t)(3 * i + 1) * H + h];
  float v2 = Vv[(size_t)(3 * i + 2) * H + h];
  A2[(size_t)i * 256 + h] = __float2bfloat16(sqrtf(v0 * v0 + v1 * v1 + v2 * v2));
}

// ---------------- generic MFMA stage-1: out = silu(A@W+b) -> bf16, 128 cols ----------------
template<int KB>
__global__ __launch_bounds__(256) void gemm_silu_mfma(
    const bf16* __restrict__ A, const bf16* __restrict__ Wp,
    const float* __restrict__ bias, bf16* __restrict__ out, int M) {
  int wave = threadIdx.x >> 6, lane = threadIdx.x & 63;
  int rowg = wave >> 1, ch = wave & 1;
  int r0 = blockIdx.x * 32 + rowg * 16;
  int quad = lane >> 4, nn = lane & 15;
  int arow = r0 + nn; if (arow >= M) arow = M - 1;
  f32x4 acc[4] = {};
  for (int kb = 0; kb < KB; kb++) {
    bf16x8 af = *(const bf16x8*)&A[(size_t)arow * (KB * 32) + kb * 32 + quad * 8];
    #pragma unroll
    for (int c = 0; c < 4; c++) {
      int cg = ch * 4 + c;
      bf16x8 bw = *(const bf16x8*)&Wp[(((kb * 8 + cg) * 64) + lane) * 8];
      acc[c] = __builtin_amdgcn_mfma_f32_16x16x32_bf16(af, bw, acc[c], 0, 0, 0);
    }
  }
  #pragma unroll
  for (int c = 0; c < 4; c++) {
    int n = (ch * 4 + c) * 16 + nn;
    float bb = bias[n];
    #pragma unroll
    for (int r = 0; r < 4; r++) {
      int row = r0 + quad * 4 + r;
      if (row < M) out[(size_t)row * H + n] = __float2bfloat16(silu_f(acc[c][r] + bb));
    }
  }
}

// ---------------- MFMA stage-2, 384 cols -> bf16 (scalar-MLP "so") ----------------
__global__ __launch_bounds__(256) void gemm_so_mfma(
    const bf16* __restrict__ m1, const bf16* __restrict__ Wp,
    const float* __restrict__ b2, bf16* __restrict__ so, int M) {
  int wave = threadIdx.x >> 6, lane = threadIdx.x & 63;
  int rowg = wave >> 1, ch = wave & 1;
  int r0 = blockIdx.x * 32 + rowg * 16;
  int quad = lane >> 4, nn = lane & 15;
  int arow = r0 + nn; if (arow >= M) arow = M - 1;
  f32x4 a0[4] = {}, a1[4] = {}, a2[4] = {};
  for (int kb = 0; kb < 4; kb++) {
    bf16x8 af = *(const bf16x8*)&m1[(size_t)arow * H + kb * 32 + quad * 8];
    #pragma unroll
    for (int c = 0; c < 4; c++) {
      int cg = ch * 4 + c;
      bf16x8 b0 = *(const bf16x8*)&Wp[(((kb * 24 + cg) * 64) + lane) * 8];
      bf16x8 b1v = *(const bf16x8*)&Wp[(((kb * 24 + cg + 8) * 64) + lane) * 8];
      bf16x8 b2v = *(const bf16x8*)&Wp[(((kb * 24 + cg + 16) * 64) + lane) * 8];
      a0[c] = __builtin_amdgcn_mfma_f32_16x16x32_bf16(af, b0, a0[c], 0, 0, 0);
      a1[c] = __builtin_amdgcn_mfma_f32_16x16x32_bf16(af, b1v, a1[c], 0, 0, 0);
      a2[c] = __builtin_amdgcn_mfma_f32_16x16x32_bf16(af, b2v, a2[c], 0, 0, 0);
    }
  }
  #pragma unroll
  for (int c = 0; c < 4; c++) {
    int n = (ch * 4 + c) * 16 + nn;
    float bb0 = b2[n], bb1 = b2[H + n], bb2 = b2[2 * H + n];
    #pragma unroll
    for (int r = 0; r < 4; r++) {
      int row = r0 + quad * 4 + r;
      if (row < M) {
        so[(size_t)row * F3H + n]           = __float2bfloat16(a0[c][r] + bb0);
        so[(size_t)row * F3H + H + n]       = __float2bfloat16(a1[c][r] + bb1);
        so[(size_t)row * F3H + 2 * H + n]   = __float2bfloat16(a2[c][r] + bb2);
      }
    }
  }
}

// ---------------- MFMA stage-2, 128 cols -> fp32 (readout) ----------------
__global__ __launch_bounds__(256) void gemm_ro2_mfma(
    const bf16* __restrict__ m1, const bf16* __restrict__ Wp,
    const float* __restrict__ b2, float* __restrict__ out, int M) {
  int wave = threadIdx.x >> 6, lane = threadIdx.x & 63;
  int rowg = wave >> 1, ch = wave & 1;
  int r0 = blockIdx.x * 32 + rowg * 16;
  int quad = lane >> 4, nn = lane & 15;
  int arow = r0 + nn; if (arow >= M) arow = M - 1;
  f32x4 acc[4] = {};
  for (int kb = 0; kb < 4; kb++) {
    bf16x8 af = *(const bf16x8*)&m1[(size_t)arow * H + kb * 32 + quad * 8];
    #pragma unroll
    for (int c = 0; c < 4; c++) {
      int cg = ch * 4 + c;
      bf16x8 bw = *(const bf16x8*)&Wp[(((kb * 8 + cg) * 64) + lane) * 8];
      acc[c] = __builtin_amdgcn_mfma_f32_16x16x32_bf16(af, bw, acc[c], 0, 0, 0);
    }
  }
  #pragma unroll
  for (int c = 0; c < 4; c++) {
    int n = (ch * 4 + c) * 16 + nn;
    float bb = b2[n];
    #pragma unroll
    for (int r = 0; r < 4; r++) {
      int row = r0 + quad * 4 + r;
      if (row < M) out[(size_t)row * H + n] = acc[c][r] + bb;
    }
  }
}

// ---------------- MFMA update-MLP stage 2 + gating epilogue (+ns16) ----------------
__global__ __launch_bounds__(256) void gemm_mo_ep(
    const bf16* __restrict__ m1, const bf16* __restrict__ Wp,
    const float* __restrict__ b2,
    float* __restrict__ ns, bf16* __restrict__ ns16,
    float* __restrict__ nv, bf16* __restrict__ nvb16,
    const float* __restrict__ Uv, const float* __restrict__ Vv, int M) {
  int wave = threadIdx.x >> 6, lane = threadIdx.x & 63;
  int rowg = wave >> 1, ch = wave & 1;
  int r0 = blockIdx.x * 32 + rowg * 16;
  int quad = lane >> 4, nn = lane & 15;
  int arow = r0 + nn; if (arow >= M) arow = M - 1;
  f32x4 aav[4] = {}, aas[4] = {}, asz[4] = {};
  for (int kb = 0; kb < 4; kb++) {
    bf16x8 af = *(const bf16x8*)&m1[(size_t)arow * H + kb * 32 + quad * 8];
    #pragma unroll
    for (int c = 0; c < 4; c++) {
      int cg = ch * 4 + c;
      bf16x8 b0 = *(const bf16x8*)&Wp[(((kb * 24 + cg) * 64) + lane) * 8];
      bf16x8 b1v = *(const bf16x8*)&Wp[(((kb * 24 + cg + 8) * 64) + lane) * 8];
      bf16x8 b2v = *(const bf16x8*)&Wp[(((kb * 24 + cg + 16) * 64) + lane) * 8];
      aav[c] = __builtin_amdgcn_mfma_f32_16x16x32_bf16(af, b0, aav[c], 0, 0, 0);
      aas[c] = __builtin_amdgcn_mfma_f32_16x16x32_bf16(af, b1v, aas[c], 0, 0, 0);
      asz[c] = __builtin_amdgcn_mfma_f32_16x16x32_bf16(af, b2v, asz[c], 0, 0, 0);
    }
  }
  #pragma unroll
  for (int c = 0; c < 4; c++) {
    int n = (ch * 4 + c) * 16 + nn;
    float bav = b2[n], bas = b2[H + n], bss = b2[2 * H + n];
    #pragma unroll
    for (int r = 0; r < 4; r++) {
      int row = r0 + quad * 4 + r;
      if (row < M) {
        float avv = aav[c][r] + bav;
        float asv = aas[c][r] + bas;
        float ass = asz[c][r] + bss;
        float u0 = Uv[(size_t)(3 * row + 0) * H + n];
        float u1 = Uv[(size_t)(3 * row + 1) * H + n];
        float u2 = Uv[(size_t)(3 * row + 2) * H + n];
        float v0 = Vv[(size_t)(3 * row + 0) * H + n];
        float v1 = Vv[(size_t)(3 * row + 1) * H + n];
        float v2 = Vv[(size_t)(3 * row + 2) * H + n];
        float dot = u0 * v0 + u1 * v1 + u2 * v2;
        float ns_new = ns[(size_t)row * H + n] + asv * dot + ass;
        ns[(size_t)row * H + n] = ns_new;
        ns16[(size_t)row * H + n] = __float2bfloat16(ns_new);
        float n0 = nv[(size_t)(3 * row + 0) * H + n] + avv * u0;
        float n1 = nv[(size_t)(3 * row + 1) * H + n] + avv * u1;
        float n2 = nv[(size_t)(3 * row + 2) * H + n] + avv * u2;
        nv[(size_t)(3 * row + 0) * H + n] = n0;
        nv[(size_t)(3 * row + 1) * H + n] = n1;
        nv[(size_t)(3 * row + 2) * H + n] = n2;
        nvb16[(size_t)(3 * row + 0) * H + n] = __float2bfloat16(n0);
        nvb16[(size_t)(3 * row + 1) * H + n] = __float2bfloat16(n1);
        nvb16[(size_t)(3 * row + 2) * H + n] = __float2bfloat16(n2);
      }
    }
  }
}

// ---------------- message: round-0 structure, edge loop unrolled x2 ----------------
// All 12 payload gathers (so + nv for edges j and j+1) issue before either
// edge's compute: doubles gather MLP per wave (latency-bound theory, r0-r3
// evidence: effective BW tracks issue health, not layout). Accumulation
// order preserved (edge j fully summed before j+1) -> bitwise identical.
template<bool HASNV>
__global__ __launch_bounds__(128, 4) void message3(
    const int* __restrict__ srcs, const int* __restrict__ rowstart,
    const int* __restrict__ cnt, const float* __restrict__ geo,
    const float* __restrict__ Wf, const float* __restrict__ bfb,
    const bf16* __restrict__ so, const bf16* __restrict__ nvb16,
    const float* __restrict__ nvA,
    float* __restrict__ ns, float* __restrict__ nvB,
    bf16* __restrict__ nvmsg16, bf16* __restrict__ A2, int N) {
  int i = blockIdx.x;
  int h = threadIdx.x;

  float wf0[E_RBF], wf1[E_RBF], wf2[E_RBF];
  #pragma unroll
  for (int k = 0; k < E_RBF; k++) {
    wf0[k] = Wf[k * F3H + h];
    wf1[k] = Wf[k * F3H + H + h];
    wf2[k] = Wf[k * F3H + 2 * H + h];
  }
  float bb0 = bfb[h], bb1 = bfb[H + h], bb2 = bfb[2 * H + h];

  float accs = 0.0f, a0 = 0.0f, a1 = 0.0f, a2 = 0.0f;
  int jlo = rowstart[i], jhi = jlo + cnt[i];
  int j = jlo;
  for (; j + 1 < jhi; j += 2) {
    int s0 = srcs[j];
    int s1 = srcs[j + 1];
    // issue ALL payload gathers for both edges first (12 loads in flight)
    const bf16* sop0 = so + (size_t)s0 * F3H;
    const bf16* sop1 = so + (size_t)s1 * F3H;
    float sA0 = b2f(sop0[h]), sB0 = b2f(sop0[H + h]), sC0 = b2f(sop0[2 * H + h]);
    float sA1 = b2f(sop1[h]), sB1 = b2f(sop1[H + h]), sC1 = b2f(sop1[2 * H + h]);
    float nA0, nB0, nC0, nA1, nB1, nC1;
    if (HASNV) {
      const bf16* nvp0 = nvb16 + (size_t)s0 * F3H;
      const bf16* nvp1 = nvb16 + (size_t)s1 * F3H;
      nA0 = b2f(nvp0[h]); nB0 = b2f(nvp0[H + h]); nC0 = b2f(nvp0[2 * H + h]);
      nA1 = b2f(nvp1[h]); nB1 = b2f(nvp1[H + h]); nC1 = b2f(nvp1[2 * H + h]);
    }

    // ---- edge j ----
    {
      const float* g = geo + (size_t)j * 24;
      float gg[24];
      #pragma unroll
      for (int q = 0; q < 6; q++) *(float4*)&gg[4 * q] = *(const float4*)&g[4 * q];
      float fc = gg[23];
      float f0 = bb0 * fc, f1 = bb1 * fc, f2 = bb2 * fc;
      #pragma unroll
      for (int k = 0; k < E_RBF; k++) {
        float rk = gg[k];
        f0 += rk * wf0[k];
        f1 += rk * wf1[k];
        f2 += rk * wf2[k];
      }
      float u0 = gg[20], u1 = gg[21], u2 = gg[22];
      float gsv = f0 * sA0;
      float gev = f1 * sB0;
      accs += f2 * sC0;
      if (HASNV) {
        a0 += nA0 * gsv + gev * u0;
        a1 += nB0 * gsv + gev * u1;
        a2 += nC0 * gsv + gev * u2;
      } else {
        a0 += gev * u0;
        a1 += gev * u1;
        a2 += gev * u2;
      }
    }
    // ---- edge j+1 ----
    {
      const float* g = geo + (size_t)(j + 1) * 24;
      float gg[24];
      #pragma unroll
      for (int q = 0; q < 6; q++) *(float4*)&gg[4 * q] = *(const float4*)&g[4 * q];
      float fc = gg[23];
      float f0 = bb0 * fc, f1 = bb1 * fc, f2 = bb2 * fc;
      #pragma unroll
      for (int k = 0; k < E_RBF; k++) {
        float rk = gg[k];
        f0 += rk * wf0[k];
        f1 += rk * wf1[k];
        f2 += rk * wf2[k];
      }
      float u0 = gg[20], u1 = gg[21], u2 = gg[22];
      float gsv = f0 * sA1;
      float gev = f1 * sB1;
      accs += f2 * sC1;
      if (HASNV) {
        a0 += nA1 * gsv + gev * u0;
        a1 += nB1 * gsv + gev * u1;
        a2 += nC1 * gsv + gev * u2;
      } else {
        a0 += gev * u0;
        a1 += gev * u1;
        a2 += gev * u2;
      }
    }
  }
  // ---- tail edge ----
  if (j < jhi) {
    int src = srcs[j];
    const float* g = geo + (size_t)j * 24;
    float gg[24];
    #pragma unroll
    for (int q = 0; q < 6; q++) *(float4*)&gg[4 * q] = *(const float4*)&g[4 * q];
    float fc = gg[23];
    float f0 = bb0 * fc, f1 = bb1 * fc, f2 = bb2 * fc;
    #pragma unroll
    for (int k = 0; k < E_RBF; k++) {
      float rk = gg[k];
      f0 += rk * wf0[k];
      f1 += rk * wf1[k];
      f2 += rk * wf2[k];
    }
    float u0 = gg[20], u1 = gg[21], u2 = gg[22];
    const bf16* sop = so + (size_t)src * F3H;
    float gsv = f0 * b2f(sop[h]);
    float gev = f1 * b2f(sop[H + h]);
    accs += f2 * b2f(sop[2 * H + h]);
    if (HASNV) {
      const bf16* nvp = nvb16 + (size_t)src * F3H;
      a0 += b2f(nvp[h])         * gsv + gev * u0;
      a1 += b2f(nvp[H + h])     * gsv + gev * u1;
      a2 += b2f(nvp[2 * H + h]) * gsv + gev * u2;
    } else {
      a0 += gev * u0;
      a1 += gev * u1;
      a2 += gev * u2;
    }
  }

  float ns_new = ns[(size_t)i * H + h] + accs;
  ns[(size_t)i * H + h] = ns_new;
  A2[(size_t)i * 256 + 128 + h] = __float2bfloat16(ns_new);
  float o0, o1, o2;
  if (HASNV) {
    const float* nvi = nvA + (size_t)i * F3H;
    o0 = nvi[h] + a0;
    o1 = nvi[H + h] + a1;
    o2 = nvi[2 * H + h] + a2;
  } else {
    o0 = a0; o1 = a1; o2 = a2;
  }
  nvB[(size_t)i * F3H + h]         = o0;
  nvB[(size_t)i * F3H + H + h]     = o1;
  nvB[(size_t)i * F3H + 2 * H + h] = o2;
  nvmsg16[(size_t)i * F3H + h]         = __float2bfloat16(o0);
  nvmsg16[(size_t)i * F3H + H + h]     = __float2bfloat16(o1);
  nvmsg16[(size_t)i * F3H + 2 * H + h] = __float2bfloat16(o2);
}

extern "C" void kernel_launch(void* const* d_in, const int* in_sizes, int n_in,
                              void* d_out, int out_size, void* d_ws, size_t ws_size,
                              hipStream_t stream) {
  const int*   z     = (const int*)d_in[0];
  const int*   edge  = (const int*)d_in[1];
  const float* ediff = (const float*)d_in[2];
  const float* edist = (const float*)d_in[3];
  const float* embed = (const float*)d_in[4];
  const float* mfw   = (const float*)d_in[5];
  const float* mfb   = (const float*)d_in[6];
  const float* mw1   = (const float*)d_in[7];
  const float* mb1   = (const float*)d_in[8];
  const float* mw2   = (const float*)d_in[9];
  const float* mb2   = (const float*)d_in[10];
  const float* uUw   = (const float*)d_in[11];
  const float* uUb   = (const float*)d_in[12];
  const float* uVw   = (const float*)d_in[13];
  const float* uVb   = (const float*)d_in[14];
  const float* uw1   = (const float*)d_in[15];
  const float* ub1   = (const float*)d_in[16];
  const float* uw2   = (const float*)d_in[17];
  const float* ub2   = (const float*)d_in[18];
  const float* rw1   = (const float*)d_in[19];
  const float* rb1   = (const float*)d_in[20];
  const float* rw2   = (const float*)d_in[21];
  const float* rb2   = (const float*)d_in[22];

  const int N  = in_sizes[0];   // 10000
  const int nE = in_sizes[3];   // 160000

  float* ws = (float*)d_ws;
  size_t off = 0;
  float* ns      = ws + off; off += (size_t)N * H;
  float* nvA     = ws + off; off += (size_t)N * F3H;
  float* nvB     = ws + off; off += (size_t)N * F3H;
  float* Vv      = ws + off; off += (size_t)N * F3H;
  float* geo     = ws + off; off += (size_t)nE * 24;
  bf16* so       = (bf16*)(ws + off); off += (size_t)N * F3H / 2;
  bf16* nvb16    = (bf16*)(ws + off); off += (size_t)N * F3H / 2;
  bf16* nvmsg16  = (bf16*)(ws + off); off += (size_t)N * F3H / 2;
  bf16* A2       = (bf16*)(ws + off); off += (size_t)N * 128;       // N*256 bf16
  bf16* m1buf    = (bf16*)(ws + off); off += (size_t)N * 64;        // N*128 bf16
  bf16* ns16     = (bf16*)(ws + off); off += (size_t)N * 64;        // N*128 bf16
  bf16* wpack    = (bf16*)(ws + off); off += 3 * 2 * 16384 / 2;     // UV
  bf16* wp_m1    = (bf16*)(ws + off); off += 3 * 256 * 128 / 2;
  bf16* wp_m2    = (bf16*)(ws + off); off += 3 * 128 * 384 / 2;
  bf16* wp_sm1   = (bf16*)(ws + off); off += 3 * 128 * 128 / 2;
  bf16* wp_sm2   = (bf16*)(ws + off); off += 3 * 128 * 384 / 2;
  bf16* wp_ro1   = (bf16*)(ws + off); off += 128 * 128 / 2;
  bf16* wp_ro2   = (bf16*)(ws + off); off += 128 * 128 / 2;
  int* srcs     = (int*)(ws + off); off += nE;
  int* cnt      = (int*)(ws + off); off += N;
  int* rowstart = (int*)(ws + off); off += N;
  int* cur      = (int*)(ws + off); off += N;
  int* elist    = (int*)(ws + off); off += nE;

  const int tilesN = (N + 31) / 32;            // 313
  const int uvBlks = (3 * N + 63) / 64;        // 469

  (void)hipMemsetAsync(cnt, 0, (size_t)N * sizeof(int), stream);
  csr_hist<<<(nE + 255) / 256, 256, 0, stream>>>(edge, cnt, nE);
  csr_scan<<<1, 256, 0, stream>>>(cnt, rowstart, cur, N);
  csr_fill<<<(nE + 255) / 256, 256, 0, stream>>>(edge, cur, elist, nE);
  edge_pack<<<(nE + 255) / 256, 256, 0, stream>>>(elist, edge, edist, ediff, srcs, geo, nE);
  pack_w<<<48, 256, 0, stream>>>(uUw, uVw, wpack);
  pack_b<<<48, 256, 0, stream>>>(uw1, wp_m1, 256, 128, 3);
  pack_b<<<72, 256, 0, stream>>>(uw2, wp_m2, 128, 384, 3);
  pack_b<<<24, 256, 0, stream>>>(mw1, wp_sm1, 128, 128, 3);
  pack_b<<<72, 256, 0, stream>>>(mw2, wp_sm2, 128, 384, 3);
  pack_b<<<8, 256, 0, stream>>>(rw1, wp_ro1, 128, 128, 1);
  pack_b<<<8, 256, 0, stream>>>(rw2, wp_ro2, 128, 128, 1);

  node_init<<<N, H, 0, stream>>>(z, embed, ns, ns16, N);

  float* nv_cur = nvA;
  float* nv_nxt = nvB;
  for (int l = 0; l < NLAYER; l++) {
    // scalar message MLP (MFMA): m1 = silu(ns16@mw1+mb1); so = m1@mw2+mb2
    gemm_silu_mfma<4><<<tilesN, 256, 0, stream>>>(
        ns16, wp_sm1 + (size_t)l * 128 * 128, mb1 + (size_t)l * H, m1buf, N);
    gemm_so_mfma<<<tilesN, 256, 0, stream>>>(
        m1buf, wp_sm2 + (size_t)l * 128 * 384, mb2 + (size_t)l * F3H, so, N);

    if (l == 0)
      message3<false><<<N, H, 0, stream>>>(srcs, rowstart, cnt, geo,
                                           mfw + (size_t)l * E_RBF * F3H, mfb + (size_t)l * F3H,
                                           so, nvb16, nv_cur, ns, nv_nxt, nvmsg16, A2, N);
    else
      message3<true><<<N, H, 0, stream>>>(srcs, rowstart, cnt, geo,
                                          mfw + (size_t)l * E_RBF * F3H, mfb + (size_t)l * F3H,
                                          so, nvb16, nv_cur, ns, nv_nxt, nvmsg16, A2, N);

    float* Uv = nv_cur;  // dead after message3 — reuse as Uv scratch
    gemm_uv_mfma<<<uvBlks, 256, 0, stream>>>(
        nvmsg16, wpack + (size_t)l * 2 * 16384,
        uUb + (size_t)l * H, uVb + (size_t)l * H,
        Uv, Vv, 3 * N);

    vnorm_a2<<<(N * H + 255) / 256, 256, 0, stream>>>(Vv, A2, N);
    gemm_silu_mfma<8><<<tilesN, 256, 0, stream>>>(
        A2, wp_m1 + (size_t)l * 256 * 128, ub1 + (size_t)l * H, m1buf, N);
    gemm_mo_ep<<<tilesN, 256, 0, stream>>>(
        m1buf, wp_m2 + (size_t)l * 128 * 384, ub2 + (size_t)l * F3H,
        ns, ns16, nv_nxt, nvb16, Uv, Vv, N);

    float* t = nv_cur; nv_cur = nv_nxt; nv_nxt = t;
  }

  gemm_silu_mfma<4><<<tilesN, 256, 0, stream>>>(ns16, wp_ro1, rb1, m1buf, N);
  gemm_ro2_mfma<<<tilesN, 256, 0, stream>>>(m1buf, wp_ro2, rb2, (float*)d_out, N);
}

// Round 5
// 547.587 us; speedup vs baseline: 1.2448x; 1.0334x over previous
//
#include <hip/hip_runtime.h>
#include <hip/hip_bf16.h>

typedef __hip_bfloat16 bf16;
typedef __attribute__((ext_vector_type(8))) short bf16x8;
typedef __attribute__((ext_vector_type(4))) float f32x4;

#define H 128
#define F3H 384
#define E_RBF 20
#define NLAYER 3

__device__ __forceinline__ float silu_f(float x) { return x / (1.0f + __expf(-x)); }
__device__ __forceinline__ float b2f(bf16 x) { return __bfloat162float(x); }

constexpr float PI_F = 3.14159265358979323846f;
constexpr float CUT = 5.0f;

// ---------------- CSR build ----------------
__global__ __launch_bounds__(256) void csr_hist(
    const int* __restrict__ edge, int* __restrict__ cnt, int nE) {
  int e = blockIdx.x * blockDim.x + threadIdx.x;
  if (e < nE) atomicAdd(&cnt[edge[2 * e]], 1);
}

__global__ __launch_bounds__(256) void csr_scan(
    const int* __restrict__ cnt, int* __restrict__ rowstart, int* __restrict__ cur, int N) {
  __shared__ int part[256];
  int t = threadIdx.x;
  int chunk = (N + 255) / 256;
  int lo = t * chunk; if (lo > N) lo = N;
  int hi = lo + chunk; if (hi > N) hi = N;
  int s = 0;
  for (int i = lo; i < hi; i++) s += cnt[i];
  part[t] = s;
  __syncthreads();
  if (t == 0) {
    int r = 0;
    for (int i = 0; i < 256; i++) { int v = part[i]; part[i] = r; r += v; }
  }
  __syncthreads();
  int r = part[t];
  for (int i = lo; i < hi; i++) { rowstart[i] = r; cur[i] = r; r += cnt[i]; }
}

__global__ __launch_bounds__(256) void csr_fill(
    const int* __restrict__ edge, int* __restrict__ cur, int* __restrict__ elist, int nE) {
  int e = blockIdx.x * blockDim.x + threadIdx.x;
  if (e < nE) {
    int d = edge[2 * e];
    int p = atomicAdd(&cur[d], 1);
    elist[p] = e;
  }
}

// ---------------- edge geometry pack ----------------
__global__ __launch_bounds__(256) void edge_pack(
    const int* __restrict__ elist, const int* __restrict__ edge,
    const float* __restrict__ edist, const float* __restrict__ ediff,
    int* __restrict__ srcs, float* __restrict__ geo, int nE) {
  int j = blockIdx.x * blockDim.x + threadIdx.x;
  if (j >= nE) return;
  int e = elist[j];
  srcs[j] = edge[2 * e + 1];
  float d = edist[e];
  float inv = 1.0f / d;
  float th = d * (PI_F / CUT);
  float s1 = sinf(th), c1 = cosf(th);
  float fc = (d < CUT) ? 0.5f * (c1 + 1.0f) : 0.0f;
  float* g = geo + (size_t)j * 24;
  float twoc = 2.0f * c1;
  float skp = 0.0f, sk = s1;
  #pragma unroll
  for (int k = 0; k < E_RBF; k++) {
    g[k] = sk * inv * fc;
    float nx = twoc * sk - skp;
    skp = sk; sk = nx;
  }
  g[20] = ediff[3 * (size_t)e] * inv;
  g[21] = ediff[3 * (size_t)e + 1] * inv;
  g[22] = ediff[3 * (size_t)e + 2] * inv;
  g[23] = fc;
}

// ---------------- node init (fp32 + bf16 shadow) ----------------
__global__ __launch_bounds__(H) void node_init(
    const int* __restrict__ z, const float* __restrict__ embed,
    float* __restrict__ ns, bf16* __restrict__ ns16, int N) {
  int i = blockIdx.x;
  int h = threadIdx.x;
  float v = embed[(size_t)z[i] * H + h];
  ns[(size_t)i * H + h] = v;
  ns16[(size_t)i * H + h] = __float2bfloat16(v);
}

// ---------------- pack U/V weights into MFMA B-fragment layout ----------------
__global__ __launch_bounds__(256) void pack_w(
    const float* __restrict__ Wu, const float* __restrict__ Wv,
    bf16* __restrict__ wp) {
  int t = blockIdx.x * blockDim.x + threadIdx.x;   // 12288 total
  if (t >= 3 * 2 * 4 * 8 * 64) return;
  int lane = t & 63;
  int c    = (t >> 6) & 7;
  int kb   = (t >> 9) & 3;
  int mat  = (t >> 11) & 1;
  int l    = t >> 12;
  const float* src = (mat ? Wv : Wu) + (size_t)l * H * H;
  bf16* dst = wp + ((size_t)(l * 2 + mat) * 16384) + (((kb * 8 + c) * 64 + lane) * 8);
  int quad = lane >> 4;
  int n = c * 16 + (lane & 15);
  #pragma unroll
  for (int j = 0; j < 8; j++) {
    int k = kb * 32 + quad * 8 + j;
    dst[j] = __float2bfloat16(src[(size_t)k * H + n]);
  }
}

// ---------------- generic B-fragment packer ----------------
__global__ __launch_bounds__(256) void pack_b(
    const float* __restrict__ src, bf16* __restrict__ dst,
    int K, int ncols, int L) {
  int kblocks = K >> 5, ncols16 = ncols >> 4;
  int total = L * kblocks * ncols16 * 64;
  int t = blockIdx.x * blockDim.x + threadIdx.x;
  if (t >= total) return;
  int lane = t & 63;
  int idx = t >> 6;
  int c = idx % ncols16; idx /= ncols16;
  int kb = idx % kblocks; idx /= kblocks;
  int l = idx;
  const float* s = src + (size_t)l * K * ncols;
  bf16* d = dst + (size_t)l * K * ncols + (((kb * ncols16 + c) * 64 + lane) * 8);
  int quad = lane >> 4;
  int n = c * 16 + (lane & 15);
  #pragma unroll
  for (int j = 0; j < 8; j++) {
    int k = kb * 32 + quad * 8 + j;
    d[j] = __float2bfloat16(s[(size_t)k * ncols + n]);
  }
}

// ---------------- fused MFMA dual GEMM Uv/Vv + vnorm -> A2[:,0:128] ----------------
// 384 threads = 6 waves = 96 rows = exactly 32 nodes per block. Vv^2 staged in
// LDS, reduced across the 3 rows of each node after a barrier. vnorm input is
// the identical accv+bvb value previously written to and re-read from Vv.
__global__ __launch_bounds__(384) void gemm_uv_vn(
    const bf16* __restrict__ A, const bf16* __restrict__ Wp,
    const float* __restrict__ bu, const float* __restrict__ bv,
    float* __restrict__ Cu, float* __restrict__ Cv, bf16* __restrict__ A2,
    int M, int N) {
  __shared__ float vsq[96][H];   // 48 KiB
  int wave = threadIdx.x >> 6;   // 0..5
  int lane = threadIdx.x & 63;
  int r0 = blockIdx.x * 96 + wave * 16;
  int quad = lane >> 4;
  int nn = lane & 15;
  int arow = r0 + nn;
  if (arow >= M) arow = M - 1;
  f32x4 accu[8] = {};
  f32x4 accv[8] = {};
  for (int kb = 0; kb < 4; kb++) {
    bf16x8 af = *(const bf16x8*)&A[(size_t)arow * H + kb * 32 + quad * 8];
    #pragma unroll
    for (int c = 0; c < 8; c++) {
      bf16x8 bfu = *(const bf16x8*)&Wp[(((kb * 8 + c) * 64) + lane) * 8];
      bf16x8 bfv = *(const bf16x8*)&Wp[16384 + (((kb * 8 + c) * 64) + lane) * 8];
      accu[c] = __builtin_amdgcn_mfma_f32_16x16x32_bf16(af, bfu, accu[c], 0, 0, 0);
      accv[c] = __builtin_amdgcn_mfma_f32_16x16x32_bf16(af, bfv, accv[c], 0, 0, 0);
    }
  }
  #pragma unroll
  for (int c = 0; c < 8; c++) {
    int n = c * 16 + nn;
    float bub = bu[n], bvb = bv[n];
    #pragma unroll
    for (int r = 0; r < 4; r++) {
      int row = r0 + quad * 4 + r;
      int lr = wave * 16 + quad * 4 + r;
      float cu = accu[c][r] + bub;
      float cv = accv[c][r] + bvb;
      if (row < M) {
        Cu[(size_t)row * H + n] = cu;
        Cv[(size_t)row * H + n] = cv;
      }
      vsq[lr][n] = cv * cv;
    }
  }
  __syncthreads();
  for (int t = threadIdx.x; t < 32 * H; t += 384) {
    int node = t >> 7, hh = t & 127;
    int gnode = blockIdx.x * 32 + node;
    if (gnode < N) {
      float s = vsq[node * 3][hh] + vsq[node * 3 + 1][hh] + vsq[node * 3 + 2][hh];
      A2[(size_t)gnode * 256 + hh] = __float2bfloat16(sqrtf(s));
    }
  }
}

// ---------------- fused 2-stage MLP: so = (silu(A@W1+b1))@W2+b2, 384 cols ----------------
// stage-1 result staged in LDS [32][136] bf16 (row pad 136 -> 4-bank skew,
// 2-way conflicts = free). Replaces gemm_silu<4> + gemm_so.
__global__ __launch_bounds__(256) void mlp_msg(
    const bf16* __restrict__ A, const bf16* __restrict__ Wp1,
    const float* __restrict__ b1, const bf16* __restrict__ Wp2,
    const float* __restrict__ b2, bf16* __restrict__ so, int M) {
  __shared__ bf16 m1l[32][136];
  int wave = threadIdx.x >> 6, lane = threadIdx.x & 63;
  int rowg = wave >> 1, ch = wave & 1;
  int r0 = blockIdx.x * 32 + rowg * 16;
  int quad = lane >> 4, nn = lane & 15;
  int arow = r0 + nn; if (arow >= M) arow = M - 1;
  f32x4 acc[4] = {};
  for (int kb = 0; kb < 4; kb++) {
    bf16x8 af = *(const bf16x8*)&A[(size_t)arow * H + kb * 32 + quad * 8];
    #pragma unroll
    for (int c = 0; c < 4; c++) {
      int cg = ch * 4 + c;
      bf16x8 bw = *(const bf16x8*)&Wp1[(((kb * 8 + cg) * 64) + lane) * 8];
      acc[c] = __builtin_amdgcn_mfma_f32_16x16x32_bf16(af, bw, acc[c], 0, 0, 0);
    }
  }
  #pragma unroll
  for (int c = 0; c < 4; c++) {
    int n = (ch * 4 + c) * 16 + nn;
    float bb = b1[n];
    #pragma unroll
    for (int r = 0; r < 4; r++) {
      int lr = rowg * 16 + quad * 4 + r;
      m1l[lr][n] = __float2bfloat16(silu_f(acc[c][r] + bb));
    }
  }
  __syncthreads();
  f32x4 a0[4] = {}, a1[4] = {}, a2[4] = {};
  for (int kb = 0; kb < 4; kb++) {
    bf16x8 af = *(const bf16x8*)&m1l[rowg * 16 + nn][kb * 32 + quad * 8];
    #pragma unroll
    for (int c = 0; c < 4; c++) {
      int cg = ch * 4 + c;
      bf16x8 b0 = *(const bf16x8*)&Wp2[(((kb * 24 + cg) * 64) + lane) * 8];
      bf16x8 b1v = *(const bf16x8*)&Wp2[(((kb * 24 + cg + 8) * 64) + lane) * 8];
      bf16x8 b2v = *(const bf16x8*)&Wp2[(((kb * 24 + cg + 16) * 64) + lane) * 8];
      a0[c] = __builtin_amdgcn_mfma_f32_16x16x32_bf16(af, b0, a0[c], 0, 0, 0);
      a1[c] = __builtin_amdgcn_mfma_f32_16x16x32_bf16(af, b1v, a1[c], 0, 0, 0);
      a2[c] = __builtin_amdgcn_mfma_f32_16x16x32_bf16(af, b2v, a2[c], 0, 0, 0);
    }
  }
  #pragma unroll
  for (int c = 0; c < 4; c++) {
    int n = (ch * 4 + c) * 16 + nn;
    float bb0 = b2[n], bb1 = b2[H + n], bb2 = b2[2 * H + n];
    #pragma unroll
    for (int r = 0; r < 4; r++) {
      int row = r0 + quad * 4 + r;
      if (row < M) {
        so[(size_t)row * F3H + n]           = __float2bfloat16(a0[c][r] + bb0);
        so[(size_t)row * F3H + H + n]       = __float2bfloat16(a1[c][r] + bb1);
        so[(size_t)row * F3H + 2 * H + n]   = __float2bfloat16(a2[c][r] + bb2);
      }
    }
  }
}

// ---------------- fused 2-stage update MLP + gating epilogue ----------------
// Replaces gemm_silu<8> (A2, K=256) + gemm_mo_ep.
__global__ __launch_bounds__(256) void mlp_upd(
    const bf16* __restrict__ A, const bf16* __restrict__ Wp1,
    const float* __restrict__ b1, const bf16* __restrict__ Wp2,
    const float* __restrict__ b2,
    float* __restrict__ ns, bf16* __restrict__ ns16,
    float* __restrict__ nv, bf16* __restrict__ nvb16,
    const float* __restrict__ Uv, const float* __restrict__ Vv, int M) {
  __shared__ bf16 m1l[32][136];
  int wave = threadIdx.x >> 6, lane = threadIdx.x & 63;
  int rowg = wave >> 1, ch = wave & 1;
  int r0 = blockIdx.x * 32 + rowg * 16;
  int quad = lane >> 4, nn = lane & 15;
  int arow = r0 + nn; if (arow >= M) arow = M - 1;
  f32x4 acc[4] = {};
  for (int kb = 0; kb < 8; kb++) {
    bf16x8 af = *(const bf16x8*)&A[(size_t)arow * 256 + kb * 32 + quad * 8];
    #pragma unroll
    for (int c = 0; c < 4; c++) {
      int cg = ch * 4 + c;
      bf16x8 bw = *(const bf16x8*)&Wp1[(((kb * 8 + cg) * 64) + lane) * 8];
      acc[c] = __builtin_amdgcn_mfma_f32_16x16x32_bf16(af, bw, acc[c], 0, 0, 0);
    }
  }
  #pragma unroll
  for (int c = 0; c < 4; c++) {
    int n = (ch * 4 + c) * 16 + nn;
    float bb = b1[n];
    #pragma unroll
    for (int r = 0; r < 4; r++) {
      int lr = rowg * 16 + quad * 4 + r;
      m1l[lr][n] = __float2bfloat16(silu_f(acc[c][r] + bb));
    }
  }
  __syncthreads();
  f32x4 aav[4] = {}, aas[4] = {}, asz[4] = {};
  for (int kb = 0; kb < 4; kb++) {
    bf16x8 af = *(const bf16x8*)&m1l[rowg * 16 + nn][kb * 32 + quad * 8];
    #pragma unroll
    for (int c = 0; c < 4; c++) {
      int cg = ch * 4 + c;
      bf16x8 b0 = *(const bf16x8*)&Wp2[(((kb * 24 + cg) * 64) + lane) * 8];
      bf16x8 b1v = *(const bf16x8*)&Wp2[(((kb * 24 + cg + 8) * 64) + lane) * 8];
      bf16x8 b2v = *(const bf16x8*)&Wp2[(((kb * 24 + cg + 16) * 64) + lane) * 8];
      aav[c] = __builtin_amdgcn_mfma_f32_16x16x32_bf16(af, b0, aav[c], 0, 0, 0);
      aas[c] = __builtin_amdgcn_mfma_f32_16x16x32_bf16(af, b1v, aas[c], 0, 0, 0);
      asz[c] = __builtin_amdgcn_mfma_f32_16x16x32_bf16(af, b2v, asz[c], 0, 0, 0);
    }
  }
  #pragma unroll
  for (int c = 0; c < 4; c++) {
    int n = (ch * 4 + c) * 16 + nn;
    float bav = b2[n], bas = b2[H + n], bss = b2[2 * H + n];
    #pragma unroll
    for (int r = 0; r < 4; r++) {
      int row = r0 + quad * 4 + r;
      if (row < M) {
        float avv = aav[c][r] + bav;
        float asv = aas[c][r] + bas;
        float ass = asz[c][r] + bss;
        float u0 = Uv[(size_t)(3 * row + 0) * H + n];
        float u1 = Uv[(size_t)(3 * row + 1) * H + n];
        float u2 = Uv[(size_t)(3 * row + 2) * H + n];
        float v0 = Vv[(size_t)(3 * row + 0) * H + n];
        float v1 = Vv[(size_t)(3 * row + 1) * H + n];
        float v2 = Vv[(size_t)(3 * row + 2) * H + n];
        float dot = u0 * v0 + u1 * v1 + u2 * v2;
        float ns_new = ns[(size_t)row * H + n] + asv * dot + ass;
        ns[(size_t)row * H + n] = ns_new;
        ns16[(size_t)row * H + n] = __float2bfloat16(ns_new);
        float n0 = nv[(size_t)(3 * row + 0) * H + n] + avv * u0;
        float n1 = nv[(size_t)(3 * row + 1) * H + n] + avv * u1;
        float n2 = nv[(size_t)(3 * row + 2) * H + n] + avv * u2;
        nv[(size_t)(3 * row + 0) * H + n] = n0;
        nv[(size_t)(3 * row + 1) * H + n] = n1;
        nv[(size_t)(3 * row + 2) * H + n] = n2;
        nvb16[(size_t)(3 * row + 0) * H + n] = __float2bfloat16(n0);
        nvb16[(size_t)(3 * row + 1) * H + n] = __float2bfloat16(n1);
        nvb16[(size_t)(3 * row + 2) * H + n] = __float2bfloat16(n2);
      }
    }
  }
}

// ---------------- fused readout: out = (silu(ns16@rw1+rb1))@rw2+rb2 ----------------
__global__ __launch_bounds__(256) void mlp_ro(
    const bf16* __restrict__ A, const bf16* __restrict__ Wp1,
    const float* __restrict__ b1, const bf16* __restrict__ Wp2,
    const float* __restrict__ b2, float* __restrict__ out, int M) {
  __shared__ bf16 m1l[32][136];
  int wave = threadIdx.x >> 6, lane = threadIdx.x & 63;
  int rowg = wave >> 1, ch = wave & 1;
  int r0 = blockIdx.x * 32 + rowg * 16;
  int quad = lane >> 4, nn = lane & 15;
  int arow = r0 + nn; if (arow >= M) arow = M - 1;
  f32x4 acc[4] = {};
  for (int kb = 0; kb < 4; kb++) {
    bf16x8 af = *(const bf16x8*)&A[(size_t)arow * H + kb * 32 + quad * 8];
    #pragma unroll
    for (int c = 0; c < 4; c++) {
      int cg = ch * 4 + c;
      bf16x8 bw = *(const bf16x8*)&Wp1[(((kb * 8 + cg) * 64) + lane) * 8];
      acc[c] = __builtin_amdgcn_mfma_f32_16x16x32_bf16(af, bw, acc[c], 0, 0, 0);
    }
  }
  #pragma unroll
  for (int c = 0; c < 4; c++) {
    int n = (ch * 4 + c) * 16 + nn;
    float bb = b1[n];
    #pragma unroll
    for (int r = 0; r < 4; r++) {
      int lr = rowg * 16 + quad * 4 + r;
      m1l[lr][n] = __float2bfloat16(silu_f(acc[c][r] + bb));
    }
  }
  __syncthreads();
  f32x4 a2[4] = {};
  for (int kb = 0; kb < 4; kb++) {
    bf16x8 af = *(const bf16x8*)&m1l[rowg * 16 + nn][kb * 32 + quad * 8];
    #pragma unroll
    for (int c = 0; c < 4; c++) {
      int cg = ch * 4 + c;
      bf16x8 bw = *(const bf16x8*)&Wp2[(((kb * 8 + cg) * 64) + lane) * 8];
      a2[c] = __builtin_amdgcn_mfma_f32_16x16x32_bf16(af, bw, a2[c], 0, 0, 0);
    }
  }
  #pragma unroll
  for (int c = 0; c < 4; c++) {
    int n = (ch * 4 + c) * 16 + nn;
    float bb = b2[n];
    #pragma unroll
    for (int r = 0; r < 4; r++) {
      int row = r0 + quad * 4 + r;
      if (row < M) out[(size_t)row * H + n] = a2[c][r] + bb;
    }
  }
}

// ---------------- message: round-0 structure, edge loop unrolled x2 ----------------
// At the measured random-gather ceiling (~2.15 TB/s effective, invariant under
// r1-r4 restructures). Do not restructure further.
template<bool HASNV>
__global__ __launch_bounds__(128, 4) void message3(
    const int* __restrict__ srcs, const int* __restrict__ rowstart,
    const int* __restrict__ cnt, const float* __restrict__ geo,
    const float* __restrict__ Wf, const float* __restrict__ bfb,
    const bf16* __restrict__ so, const bf16* __restrict__ nvb16,
    const float* __restrict__ nvA,
    float* __restrict__ ns, float* __restrict__ nvB,
    bf16* __restrict__ nvmsg16, bf16* __restrict__ A2, int N) {
  int i = blockIdx.x;
  int h = threadIdx.x;

  float wf0[E_RBF], wf1[E_RBF], wf2[E_RBF];
  #pragma unroll
  for (int k = 0; k < E_RBF; k++) {
    wf0[k] = Wf[k * F3H + h];
    wf1[k] = Wf[k * F3H + H + h];
    wf2[k] = Wf[k * F3H + 2 * H + h];
  }
  float bb0 = bfb[h], bb1 = bfb[H + h], bb2 = bfb[2 * H + h];

  float accs = 0.0f, a0 = 0.0f, a1 = 0.0f, a2 = 0.0f;
  int jlo = rowstart[i], jhi = jlo + cnt[i];
  int j = jlo;
  for (; j + 1 < jhi; j += 2) {
    int s0 = srcs[j];
    int s1 = srcs[j + 1];
    const bf16* sop0 = so + (size_t)s0 * F3H;
    const bf16* sop1 = so + (size_t)s1 * F3H;
    float sA0 = b2f(sop0[h]), sB0 = b2f(sop0[H + h]), sC0 = b2f(sop0[2 * H + h]);
    float sA1 = b2f(sop1[h]), sB1 = b2f(sop1[H + h]), sC1 = b2f(sop1[2 * H + h]);
    float nA0, nB0, nC0, nA1, nB1, nC1;
    if (HASNV) {
      const bf16* nvp0 = nvb16 + (size_t)s0 * F3H;
      const bf16* nvp1 = nvb16 + (size_t)s1 * F3H;
      nA0 = b2f(nvp0[h]); nB0 = b2f(nvp0[H + h]); nC0 = b2f(nvp0[2 * H + h]);
      nA1 = b2f(nvp1[h]); nB1 = b2f(nvp1[H + h]); nC1 = b2f(nvp1[2 * H + h]);
    }

    {
      const float* g = geo + (size_t)j * 24;
      float gg[24];
      #pragma unroll
      for (int q = 0; q < 6; q++) *(float4*)&gg[4 * q] = *(const float4*)&g[4 * q];
      float fc = gg[23];
      float f0 = bb0 * fc, f1 = bb1 * fc, f2 = bb2 * fc;
      #pragma unroll
      for (int k = 0; k < E_RBF; k++) {
        float rk = gg[k];
        f0 += rk * wf0[k];
        f1 += rk * wf1[k];
        f2 += rk * wf2[k];
      }
      float u0 = gg[20], u1 = gg[21], u2 = gg[22];
      float gsv = f0 * sA0;
      float gev = f1 * sB0;
      accs += f2 * sC0;
      if (HASNV) {
        a0 += nA0 * gsv + gev * u0;
        a1 += nB0 * gsv + gev * u1;
        a2 += nC0 * gsv + gev * u2;
      } else {
        a0 += gev * u0;
        a1 += gev * u1;
        a2 += gev * u2;
      }
    }
    {
      const float* g = geo + (size_t)(j + 1) * 24;
      float gg[24];
      #pragma unroll
      for (int q = 0; q < 6; q++) *(float4*)&gg[4 * q] = *(const float4*)&g[4 * q];
      float fc = gg[23];
      float f0 = bb0 * fc, f1 = bb1 * fc, f2 = bb2 * fc;
      #pragma unroll
      for (int k = 0; k < E_RBF; k++) {
        float rk = gg[k];
        f0 += rk * wf0[k];
        f1 += rk * wf1[k];
        f2 += rk * wf2[k];
      }
      float u0 = gg[20], u1 = gg[21], u2 = gg[22];
      float gsv = f0 * sA1;
      float gev = f1 * sB1;
      accs += f2 * sC1;
      if (HASNV) {
        a0 += nA1 * gsv + gev * u0;
        a1 += nB1 * gsv + gev * u1;
        a2 += nC1 * gsv + gev * u2;
      } else {
        a0 += gev * u0;
        a1 += gev * u1;
        a2 += gev * u2;
      }
    }
  }
  if (j < jhi) {
    int src = srcs[j];
    const float* g = geo + (size_t)j * 24;
    float gg[24];
    #pragma unroll
    for (int q = 0; q < 6; q++) *(float4*)&gg[4 * q] = *(const float4*)&g[4 * q];
    float fc = gg[23];
    float f0 = bb0 * fc, f1 = bb1 * fc, f2 = bb2 * fc;
    #pragma unroll
    for (int k = 0; k < E_RBF; k++) {
      float rk = gg[k];
      f0 += rk * wf0[k];
      f1 += rk * wf1[k];
      f2 += rk * wf2[k];
    }
    float u0 = gg[20], u1 = gg[21], u2 = gg[22];
    const bf16* sop = so + (size_t)src * F3H;
    float gsv = f0 * b2f(sop[h]);
    float gev = f1 * b2f(sop[H + h]);
    accs += f2 * b2f(sop[2 * H + h]);
    if (HASNV) {
      const bf16* nvp = nvb16 + (size_t)src * F3H;
      a0 += b2f(nvp[h])         * gsv + gev * u0;
      a1 += b2f(nvp[H + h])     * gsv + gev * u1;
      a2 += b2f(nvp[2 * H + h]) * gsv + gev * u2;
    } else {
      a0 += gev * u0;
      a1 += gev * u1;
      a2 += gev * u2;
    }
  }

  float ns_new = ns[(size_t)i * H + h] + accs;
  ns[(size_t)i * H + h] = ns_new;
  A2[(size_t)i * 256 + 128 + h] = __float2bfloat16(ns_new);
  float o0, o1, o2;
  if (HASNV) {
    const float* nvi = nvA + (size_t)i * F3H;
    o0 = nvi[h] + a0;
    o1 = nvi[H + h] + a1;
    o2 = nvi[2 * H + h] + a2;
  } else {
    o0 = a0; o1 = a1; o2 = a2;
  }
  nvB[(size_t)i * F3H + h]         = o0;
  nvB[(size_t)i * F3H + H + h]     = o1;
  nvB[(size_t)i * F3H + 2 * H + h] = o2;
  nvmsg16[(size_t)i * F3H + h]         = __float2bfloat16(o0);
  nvmsg16[(size_t)i * F3H + H + h]     = __float2bfloat16(o1);
  nvmsg16[(size_t)i * F3H + 2 * H + h] = __float2bfloat16(o2);
}

extern "C" void kernel_launch(void* const* d_in, const int* in_sizes, int n_in,
                              void* d_out, int out_size, void* d_ws, size_t ws_size,
                              hipStream_t stream) {
  const int*   z     = (const int*)d_in[0];
  const int*   edge  = (const int*)d_in[1];
  const float* ediff = (const float*)d_in[2];
  const float* edist = (const float*)d_in[3];
  const float* embed = (const float*)d_in[4];
  const float* mfw   = (const float*)d_in[5];
  const float* mfb   = (const float*)d_in[6];
  const float* mw1   = (const float*)d_in[7];
  const float* mb1   = (const float*)d_in[8];
  const float* mw2   = (const float*)d_in[9];
  const float* mb2   = (const float*)d_in[10];
  const float* uUw   = (const float*)d_in[11];
  const float* uUb   = (const float*)d_in[12];
  const float* uVw   = (const float*)d_in[13];
  const float* uVb   = (const float*)d_in[14];
  const float* uw1   = (const float*)d_in[15];
  const float* ub1   = (const float*)d_in[16];
  const float* uw2   = (const float*)d_in[17];
  const float* ub2   = (const float*)d_in[18];
  const float* rw1   = (const float*)d_in[19];
  const float* rb1   = (const float*)d_in[20];
  const float* rw2   = (const float*)d_in[21];
  const float* rb2   = (const float*)d_in[22];

  const int N  = in_sizes[0];   // 10000
  const int nE = in_sizes[3];   // 160000

  float* ws = (float*)d_ws;
  size_t off = 0;
  float* ns      = ws + off; off += (size_t)N * H;
  float* nvA     = ws + off; off += (size_t)N * F3H;
  float* nvB     = ws + off; off += (size_t)N * F3H;
  float* Vv      = ws + off; off += (size_t)N * F3H;
  float* geo     = ws + off; off += (size_t)nE * 24;
  bf16* so       = (bf16*)(ws + off); off += (size_t)N * F3H / 2;
  bf16* nvb16    = (bf16*)(ws + off); off += (size_t)N * F3H / 2;
  bf16* nvmsg16  = (bf16*)(ws + off); off += (size_t)N * F3H / 2;
  bf16* A2       = (bf16*)(ws + off); off += (size_t)N * 128;       // N*256 bf16
  bf16* ns16     = (bf16*)(ws + off); off += (size_t)N * 64;        // N*128 bf16
  bf16* wpack    = (bf16*)(ws + off); off += 3 * 2 * 16384 / 2;     // UV
  bf16* wp_m1    = (bf16*)(ws + off); off += 3 * 256 * 128 / 2;
  bf16* wp_m2    = (bf16*)(ws + off); off += 3 * 128 * 384 / 2;
  bf16* wp_sm1   = (bf16*)(ws + off); off += 3 * 128 * 128 / 2;
  bf16* wp_sm2   = (bf16*)(ws + off); off += 3 * 128 * 384 / 2;
  bf16* wp_ro1   = (bf16*)(ws + off); off += 128 * 128 / 2;
  bf16* wp_ro2   = (bf16*)(ws + off); off += 128 * 128 / 2;
  int* srcs     = (int*)(ws + off); off += nE;
  int* cnt      = (int*)(ws + off); off += N;
  int* rowstart = (int*)(ws + off); off += N;
  int* cur      = (int*)(ws + off); off += N;
  int* elist    = (int*)(ws + off); off += nE;

  const int tilesN = (N + 31) / 32;            // 313

  (void)hipMemsetAsync(cnt, 0, (size_t)N * sizeof(int), stream);
  csr_hist<<<(nE + 255) / 256, 256, 0, stream>>>(edge, cnt, nE);
  csr_scan<<<1, 256, 0, stream>>>(cnt, rowstart, cur, N);
  csr_fill<<<(nE + 255) / 256, 256, 0, stream>>>(edge, cur, elist, nE);
  edge_pack<<<(nE + 255) / 256, 256, 0, stream>>>(elist, edge, edist, ediff, srcs, geo, nE);
  pack_w<<<48, 256, 0, stream>>>(uUw, uVw, wpack);
  pack_b<<<48, 256, 0, stream>>>(uw1, wp_m1, 256, 128, 3);
  pack_b<<<72, 256, 0, stream>>>(uw2, wp_m2, 128, 384, 3);
  pack_b<<<24, 256, 0, stream>>>(mw1, wp_sm1, 128, 128, 3);
  pack_b<<<72, 256, 0, stream>>>(mw2, wp_sm2, 128, 384, 3);
  pack_b<<<8, 256, 0, stream>>>(rw1, wp_ro1, 128, 128, 1);
  pack_b<<<8, 256, 0, stream>>>(rw2, wp_ro2, 128, 128, 1);

  node_init<<<N, H, 0, stream>>>(z, embed, ns, ns16, N);

  float* nv_cur = nvA;
  float* nv_nxt = nvB;
  for (int l = 0; l < NLAYER; l++) {
    mlp_msg<<<tilesN, 256, 0, stream>>>(
        ns16, wp_sm1 + (size_t)l * 128 * 128, mb1 + (size_t)l * H,
        wp_sm2 + (size_t)l * 128 * 384, mb2 + (size_t)l * F3H, so, N);

    if (l == 0)
      message3<false><<<N, H, 0, stream>>>(srcs, rowstart, cnt, geo,
                                           mfw + (size_t)l * E_RBF * F3H, mfb + (size_t)l * F3H,
                                           so, nvb16, nv_cur, ns, nv_nxt, nvmsg16, A2, N);
    else
      message3<true><<<N, H, 0, stream>>>(srcs, rowstart, cnt, geo,
                                          mfw + (size_t)l * E_RBF * F3H, mfb + (size_t)l * F3H,
                                          so, nvb16, nv_cur, ns, nv_nxt, nvmsg16, A2, N);

    float* Uv = nv_cur;  // dead after message3 — reuse as Uv scratch
    gemm_uv_vn<<<tilesN, 384, 0, stream>>>(
        nvmsg16, wpack + (size_t)l * 2 * 16384,
        uUb + (size_t)l * H, uVb + (size_t)l * H,
        Uv, Vv, A2, 3 * N, N);

    mlp_upd<<<tilesN, 256, 0, stream>>>(
        A2, wp_m1 + (size_t)l * 256 * 128, ub1 + (size_t)l * H,
        wp_m2 + (size_t)l * 128 * 384, ub2 + (size_t)l * F3H,
        ns, ns16, nv_nxt, nvb16, Uv, Vv, N);

    float* t = nv_cur; nv_cur = nv_nxt; nv_nxt = t;
  }

  mlp_ro<<<tilesN, 256, 0, stream>>>(
      ns16, wp_ro1, rb1, wp_ro2, rb2, (float*)d_out, N);
}

// Round 6
// 516.565 us; speedup vs baseline: 1.3196x; 1.0601x over previous
//
#include <hip/hip_runtime.h>
#include <hip/hip_bf16.h>

typedef __hip_bfloat16 bf16;
typedef __attribute__((ext_vector_type(8))) short bf16x8;
typedef __attribute__((ext_vector_type(4))) float f32x4;

#define H 128
#define F3H 384
#define E_RBF 20
#define NLAYER 3

__device__ __forceinline__ float silu_f(float x) { return x / (1.0f + __expf(-x)); }
__device__ __forceinline__ float b2f(bf16 x) { return __bfloat162float(x); }

constexpr float PI_F = 3.14159265358979323846f;
constexpr float CUT = 5.0f;

// ---------------- CSR build ----------------
__global__ __launch_bounds__(256) void csr_hist(
    const int* __restrict__ edge, int* __restrict__ cnt, int nE) {
  int e = blockIdx.x * blockDim.x + threadIdx.x;
  if (e < nE) atomicAdd(&cnt[edge[2 * e]], 1);
}

__global__ __launch_bounds__(256) void csr_scan(
    const int* __restrict__ cnt, int* __restrict__ rowstart, int* __restrict__ cur, int N) {
  __shared__ int part[256];
  int t = threadIdx.x;
  int chunk = (N + 255) / 256;
  int lo = t * chunk; if (lo > N) lo = N;
  int hi = lo + chunk; if (hi > N) hi = N;
  int s = 0;
  for (int i = lo; i < hi; i++) s += cnt[i];
  part[t] = s;
  __syncthreads();
  if (t == 0) {
    int r = 0;
    for (int i = 0; i < 256; i++) { int v = part[i]; part[i] = r; r += v; }
  }
  __syncthreads();
  int r = part[t];
  for (int i = lo; i < hi; i++) { rowstart[i] = r; cur[i] = r; r += cnt[i]; }
}

__global__ __launch_bounds__(256) void csr_fill(
    const int* __restrict__ edge, int* __restrict__ cur, int* __restrict__ elist, int nE) {
  int e = blockIdx.x * blockDim.x + threadIdx.x;
  if (e < nE) {
    int d = edge[2 * e];
    int p = atomicAdd(&cur[d], 1);
    elist[p] = e;
  }
}

// ---------------- edge geometry pack ----------------
__global__ __launch_bounds__(256) void edge_pack(
    const int* __restrict__ elist, const int* __restrict__ edge,
    const float* __restrict__ edist, const float* __restrict__ ediff,
    int* __restrict__ srcs, float* __restrict__ geo, int nE) {
  int j = blockIdx.x * blockDim.x + threadIdx.x;
  if (j >= nE) return;
  int e = elist[j];
  srcs[j] = edge[2 * e + 1];
  float d = edist[e];
  float inv = 1.0f / d;
  float th = d * (PI_F / CUT);
  float s1 = sinf(th), c1 = cosf(th);
  float fc = (d < CUT) ? 0.5f * (c1 + 1.0f) : 0.0f;
  float* g = geo + (size_t)j * 24;
  float twoc = 2.0f * c1;
  float skp = 0.0f, sk = s1;
  #pragma unroll
  for (int k = 0; k < E_RBF; k++) {
    g[k] = sk * inv * fc;
    float nx = twoc * sk - skp;
    skp = sk; sk = nx;
  }
  g[20] = ediff[3 * (size_t)e] * inv;
  g[21] = ediff[3 * (size_t)e + 1] * inv;
  g[22] = ediff[3 * (size_t)e + 2] * inv;
  g[23] = fc;
}

// ---------------- node init (fp32 + bf16 shadow) ----------------
__global__ __launch_bounds__(H) void node_init(
    const int* __restrict__ z, const float* __restrict__ embed,
    float* __restrict__ ns, bf16* __restrict__ ns16, int N) {
  int i = blockIdx.x;
  int h = threadIdx.x;
  float v = embed[(size_t)z[i] * H + h];
  ns[(size_t)i * H + h] = v;
  ns16[(size_t)i * H + h] = __float2bfloat16(v);
}

// ---------------- pack U/V weights into MFMA B-fragment layout ----------------
__global__ __launch_bounds__(256) void pack_w(
    const float* __restrict__ Wu, const float* __restrict__ Wv,
    bf16* __restrict__ wp) {
  int t = blockIdx.x * blockDim.x + threadIdx.x;   // 12288 total
  if (t >= 3 * 2 * 4 * 8 * 64) return;
  int lane = t & 63;
  int c    = (t >> 6) & 7;
  int kb   = (t >> 9) & 3;
  int mat  = (t >> 11) & 1;
  int l    = t >> 12;
  const float* src = (mat ? Wv : Wu) + (size_t)l * H * H;
  bf16* dst = wp + ((size_t)(l * 2 + mat) * 16384) + (((kb * 8 + c) * 64 + lane) * 8);
  int quad = lane >> 4;
  int n = c * 16 + (lane & 15);
  #pragma unroll
  for (int j = 0; j < 8; j++) {
    int k = kb * 32 + quad * 8 + j;
    dst[j] = __float2bfloat16(src[(size_t)k * H + n]);
  }
}

// ---------------- generic B-fragment packer ----------------
__global__ __launch_bounds__(256) void pack_b(
    const float* __restrict__ src, bf16* __restrict__ dst,
    int K, int ncols, int L) {
  int kblocks = K >> 5, ncols16 = ncols >> 4;
  int total = L * kblocks * ncols16 * 64;
  int t = blockIdx.x * blockDim.x + threadIdx.x;
  if (t >= total) return;
  int lane = t & 63;
  int idx = t >> 6;
  int c = idx % ncols16; idx /= ncols16;
  int kb = idx % kblocks; idx /= kblocks;
  int l = idx;
  const float* s = src + (size_t)l * K * ncols;
  bf16* d = dst + (size_t)l * K * ncols + (((kb * ncols16 + c) * 64 + lane) * 8);
  int quad = lane >> 4;
  int n = c * 16 + (lane & 15);
  #pragma unroll
  for (int j = 0; j < 8; j++) {
    int k = kb * 32 + quad * 8 + j;
    d[j] = __float2bfloat16(s[(size_t)k * ncols + n]);
  }
}

// ---------------- fused 2-stage MLP: so = (silu(A@W1+b1))@W2+b2, 384 cols ----------------
__global__ __launch_bounds__(256) void mlp_msg(
    const bf16* __restrict__ A, const bf16* __restrict__ Wp1,
    const float* __restrict__ b1, const bf16* __restrict__ Wp2,
    const float* __restrict__ b2, bf16* __restrict__ so, int M) {
  __shared__ bf16 m1l[32][136];
  int wave = threadIdx.x >> 6, lane = threadIdx.x & 63;
  int rowg = wave >> 1, ch = wave & 1;
  int r0 = blockIdx.x * 32 + rowg * 16;
  int quad = lane >> 4, nn = lane & 15;
  int arow = r0 + nn; if (arow >= M) arow = M - 1;
  f32x4 acc[4] = {};
  for (int kb = 0; kb < 4; kb++) {
    bf16x8 af = *(const bf16x8*)&A[(size_t)arow * H + kb * 32 + quad * 8];
    #pragma unroll
    for (int c = 0; c < 4; c++) {
      int cg = ch * 4 + c;
      bf16x8 bw = *(const bf16x8*)&Wp1[(((kb * 8 + cg) * 64) + lane) * 8];
      acc[c] = __builtin_amdgcn_mfma_f32_16x16x32_bf16(af, bw, acc[c], 0, 0, 0);
    }
  }
  #pragma unroll
  for (int c = 0; c < 4; c++) {
    int n = (ch * 4 + c) * 16 + nn;
    float bb = b1[n];
    #pragma unroll
    for (int r = 0; r < 4; r++) {
      int lr = rowg * 16 + quad * 4 + r;
      m1l[lr][n] = __float2bfloat16(silu_f(acc[c][r] + bb));
    }
  }
  __syncthreads();
  f32x4 a0[4] = {}, a1[4] = {}, a2[4] = {};
  for (int kb = 0; kb < 4; kb++) {
    bf16x8 af = *(const bf16x8*)&m1l[rowg * 16 + nn][kb * 32 + quad * 8];
    #pragma unroll
    for (int c = 0; c < 4; c++) {
      int cg = ch * 4 + c;
      bf16x8 b0 = *(const bf16x8*)&Wp2[(((kb * 24 + cg) * 64) + lane) * 8];
      bf16x8 b1v = *(const bf16x8*)&Wp2[(((kb * 24 + cg + 8) * 64) + lane) * 8];
      bf16x8 b2v = *(const bf16x8*)&Wp2[(((kb * 24 + cg + 16) * 64) + lane) * 8];
      a0[c] = __builtin_amdgcn_mfma_f32_16x16x32_bf16(af, b0, a0[c], 0, 0, 0);
      a1[c] = __builtin_amdgcn_mfma_f32_16x16x32_bf16(af, b1v, a1[c], 0, 0, 0);
      a2[c] = __builtin_amdgcn_mfma_f32_16x16x32_bf16(af, b2v, a2[c], 0, 0, 0);
    }
  }
  #pragma unroll
  for (int c = 0; c < 4; c++) {
    int n = (ch * 4 + c) * 16 + nn;
    float bb0 = b2[n], bb1 = b2[H + n], bb2 = b2[2 * H + n];
    #pragma unroll
    for (int r = 0; r < 4; r++) {
      int row = r0 + quad * 4 + r;
      if (row < M) {
        so[(size_t)row * F3H + n]           = __float2bfloat16(a0[c][r] + bb0);
        so[(size_t)row * F3H + H + n]       = __float2bfloat16(a1[c][r] + bb1);
        so[(size_t)row * F3H + 2 * H + n]   = __float2bfloat16(a2[c][r] + bb2);
      }
    }
  }
}

// ---------------- fused UV dual-GEMM + vnorm + update-MLP + gating epilogue ----------------
// 384 threads, 32 nodes (96 UV rows) per block. Uv/Vv live ONLY in LDS
// (removes 66 MB/layer of HBM round-trip). vnorm -> bf16 LDS tile (identical
// values to the old A2[:,0:128]); stage1 K=256 reads kb0-3 from LDS vnorm,
// kb4-7 from global nsmsg (the old A2 ns-half). Waves 4-5 idle in MLP phases.
// All fp32 op orders preserved -> bitwise-identical outputs.
__global__ __launch_bounds__(384) void uv_upd(
    const bf16* __restrict__ A, const bf16* __restrict__ Wpuv,
    const float* __restrict__ bu, const float* __restrict__ bv,
    const bf16* __restrict__ nsmsg,
    const bf16* __restrict__ Wp1, const float* __restrict__ b1,
    const bf16* __restrict__ Wp2, const float* __restrict__ b2,
    float* __restrict__ ns, bf16* __restrict__ ns16,
    float* __restrict__ nv, bf16* __restrict__ nvb16, int N) {
  __shared__ float Uv_l[96][132];   // +4 pad: quad rows -> bank shift 16 (2-way, free)
  __shared__ float Vv_l[96][132];
  __shared__ bf16 vn_l[32][136];
  __shared__ bf16 m1l[32][136];
  int wave = threadIdx.x >> 6;
  int lane = threadIdx.x & 63;
  int quad = lane >> 4, nn = lane & 15;
  int M3 = 3 * N;

  // ---- phase 1: dual GEMM Uv/Vv into LDS (all 6 waves, 16 rows each) ----
  {
    int r0 = blockIdx.x * 96 + wave * 16;
    int arow = r0 + nn; if (arow >= M3) arow = M3 - 1;
    f32x4 accu[8] = {};
    f32x4 accv[8] = {};
    for (int kb = 0; kb < 4; kb++) {
      bf16x8 af = *(const bf16x8*)&A[(size_t)arow * H + kb * 32 + quad * 8];
      #pragma unroll
      for (int c = 0; c < 8; c++) {
        bf16x8 bfu = *(const bf16x8*)&Wpuv[(((kb * 8 + c) * 64) + lane) * 8];
        bf16x8 bfv = *(const bf16x8*)&Wpuv[16384 + (((kb * 8 + c) * 64) + lane) * 8];
        accu[c] = __builtin_amdgcn_mfma_f32_16x16x32_bf16(af, bfu, accu[c], 0, 0, 0);
        accv[c] = __builtin_amdgcn_mfma_f32_16x16x32_bf16(af, bfv, accv[c], 0, 0, 0);
      }
    }
    #pragma unroll
    for (int c = 0; c < 8; c++) {
      int n = c * 16 + nn;
      float bub = bu[n], bvb = bv[n];
      #pragma unroll
      for (int r = 0; r < 4; r++) {
        int lr = wave * 16 + quad * 4 + r;
        Uv_l[lr][n] = accu[c][r] + bub;
        Vv_l[lr][n] = accv[c][r] + bvb;
      }
    }
  }
  __syncthreads();

  // ---- phase 2: vnorm -> vn_l (same fp32 order as before) ----
  for (int t = threadIdx.x; t < 32 * H; t += 384) {
    int node = t >> 7, hh = t & 127;
    float v0 = Vv_l[node * 3][hh];
    float v1 = Vv_l[node * 3 + 1][hh];
    float v2 = Vv_l[node * 3 + 2][hh];
    vn_l[node][hh] = __float2bfloat16(sqrtf(v0 * v0 + v1 * v1 + v2 * v2));
  }
  __syncthreads();

  // ---- phase 3: MLP stage 1, K=256 (waves 0..3) ----
  int rowg = wave >> 1, ch = wave & 1;
  int r0n = blockIdx.x * 32 + rowg * 16;
  int arown = r0n + nn; if (arown >= N) arown = N - 1;
  if (wave < 4) {
    f32x4 acc[4] = {};
    for (int kb = 0; kb < 8; kb++) {
      bf16x8 af;
      if (kb < 4) af = *(const bf16x8*)&vn_l[rowg * 16 + nn][kb * 32 + quad * 8];
      else        af = *(const bf16x8*)&nsmsg[(size_t)arown * H + (kb - 4) * 32 + quad * 8];
      #pragma unroll
      for (int c = 0; c < 4; c++) {
        int cg = ch * 4 + c;
        bf16x8 bw = *(const bf16x8*)&Wp1[(((kb * 8 + cg) * 64) + lane) * 8];
        acc[c] = __builtin_amdgcn_mfma_f32_16x16x32_bf16(af, bw, acc[c], 0, 0, 0);
      }
    }
    #pragma unroll
    for (int c = 0; c < 4; c++) {
      int n = (ch * 4 + c) * 16 + nn;
      float bb = b1[n];
      #pragma unroll
      for (int r = 0; r < 4; r++) {
        int lr = rowg * 16 + quad * 4 + r;
        m1l[lr][n] = __float2bfloat16(silu_f(acc[c][r] + bb));
      }
    }
  }
  __syncthreads();

  // ---- phase 4: MLP stage 2 + gating epilogue (waves 0..3) ----
  if (wave < 4) {
    f32x4 aav[4] = {}, aas[4] = {}, asz[4] = {};
    for (int kb = 0; kb < 4; kb++) {
      bf16x8 af = *(const bf16x8*)&m1l[rowg * 16 + nn][kb * 32 + quad * 8];
      #pragma unroll
      for (int c = 0; c < 4; c++) {
        int cg = ch * 4 + c;
        bf16x8 b0 = *(const bf16x8*)&Wp2[(((kb * 24 + cg) * 64) + lane) * 8];
        bf16x8 b1v = *(const bf16x8*)&Wp2[(((kb * 24 + cg + 8) * 64) + lane) * 8];
        bf16x8 b2v = *(const bf16x8*)&Wp2[(((kb * 24 + cg + 16) * 64) + lane) * 8];
        aav[c] = __builtin_amdgcn_mfma_f32_16x16x32_bf16(af, b0, aav[c], 0, 0, 0);
        aas[c] = __builtin_amdgcn_mfma_f32_16x16x32_bf16(af, b1v, aas[c], 0, 0, 0);
        asz[c] = __builtin_amdgcn_mfma_f32_16x16x32_bf16(af, b2v, asz[c], 0, 0, 0);
      }
    }
    #pragma unroll
    for (int c = 0; c < 4; c++) {
      int n = (ch * 4 + c) * 16 + nn;
      float bav = b2[n], bas = b2[H + n], bss = b2[2 * H + n];
      #pragma unroll
      for (int r = 0; r < 4; r++) {
        int row = r0n + quad * 4 + r;
        if (row < N) {
          int lrn = rowg * 16 + quad * 4 + r;
          float avv = aav[c][r] + bav;
          float asv = aas[c][r] + bas;
          float ass = asz[c][r] + bss;
          float u0 = Uv_l[lrn * 3 + 0][n];
          float u1 = Uv_l[lrn * 3 + 1][n];
          float u2 = Uv_l[lrn * 3 + 2][n];
          float v0 = Vv_l[lrn * 3 + 0][n];
          float v1 = Vv_l[lrn * 3 + 1][n];
          float v2 = Vv_l[lrn * 3 + 2][n];
          float dot = u0 * v0 + u1 * v1 + u2 * v2;
          float ns_new = ns[(size_t)row * H + n] + asv * dot + ass;
          ns[(size_t)row * H + n] = ns_new;
          ns16[(size_t)row * H + n] = __float2bfloat16(ns_new);
          float n0 = nv[(size_t)(3 * row + 0) * H + n] + avv * u0;
          float n1 = nv[(size_t)(3 * row + 1) * H + n] + avv * u1;
          float n2 = nv[(size_t)(3 * row + 2) * H + n] + avv * u2;
          nv[(size_t)(3 * row + 0) * H + n] = n0;
          nv[(size_t)(3 * row + 1) * H + n] = n1;
          nv[(size_t)(3 * row + 2) * H + n] = n2;
          nvb16[(size_t)(3 * row + 0) * H + n] = __float2bfloat16(n0);
          nvb16[(size_t)(3 * row + 1) * H + n] = __float2bfloat16(n1);
          nvb16[(size_t)(3 * row + 2) * H + n] = __float2bfloat16(n2);
        }
      }
    }
  }
}

// ---------------- fused readout: out = (silu(ns16@rw1+rb1))@rw2+rb2 ----------------
__global__ __launch_bounds__(256) void mlp_ro(
    const bf16* __restrict__ A, const bf16* __restrict__ Wp1,
    const float* __restrict__ b1, const bf16* __restrict__ Wp2,
    const float* __restrict__ b2, float* __restrict__ out, int M) {
  __shared__ bf16 m1l[32][136];
  int wave = threadIdx.x >> 6, lane = threadIdx.x & 63;
  int rowg = wave >> 1, ch = wave & 1;
  int r0 = blockIdx.x * 32 + rowg * 16;
  int quad = lane >> 4, nn = lane & 15;
  int arow = r0 + nn; if (arow >= M) arow = M - 1;
  f32x4 acc[4] = {};
  for (int kb = 0; kb < 4; kb++) {
    bf16x8 af = *(const bf16x8*)&A[(size_t)arow * H + kb * 32 + quad * 8];
    #pragma unroll
    for (int c = 0; c < 4; c++) {
      int cg = ch * 4 + c;
      bf16x8 bw = *(const bf16x8*)&Wp1[(((kb * 8 + cg) * 64) + lane) * 8];
      acc[c] = __builtin_amdgcn_mfma_f32_16x16x32_bf16(af, bw, acc[c], 0, 0, 0);
    }
  }
  #pragma unroll
  for (int c = 0; c < 4; c++) {
    int n = (ch * 4 + c) * 16 + nn;
    float bb = b1[n];
    #pragma unroll
    for (int r = 0; r < 4; r++) {
      int lr = rowg * 16 + quad * 4 + r;
      m1l[lr][n] = __float2bfloat16(silu_f(acc[c][r] + bb));
    }
  }
  __syncthreads();
  f32x4 a2[4] = {};
  for (int kb = 0; kb < 4; kb++) {
    bf16x8 af = *(const bf16x8*)&m1l[rowg * 16 + nn][kb * 32 + quad * 8];
    #pragma unroll
    for (int c = 0; c < 4; c++) {
      int cg = ch * 4 + c;
      bf16x8 bw = *(const bf16x8*)&Wp2[(((kb * 8 + cg) * 64) + lane) * 8];
      a2[c] = __builtin_amdgcn_mfma_f32_16x16x32_bf16(af, bw, a2[c], 0, 0, 0);
    }
  }
  #pragma unroll
  for (int c = 0; c < 4; c++) {
    int n = (ch * 4 + c) * 16 + nn;
    float bb = b2[n];
    #pragma unroll
    for (int r = 0; r < 4; r++) {
      int row = r0 + quad * 4 + r;
      if (row < M) out[(size_t)row * H + n] = a2[c][r] + bb;
    }
  }
}

// ---------------- message: round-0 structure, edge loop unrolled x2 ----------------
// At the measured random-gather ceiling (~2.15 TB/s effective, invariant under
// r1-r4 restructures). Do not restructure further.
template<bool HASNV>
__global__ __launch_bounds__(128, 4) void message3(
    const int* __restrict__ srcs, const int* __restrict__ rowstart,
    const int* __restrict__ cnt, const float* __restrict__ geo,
    const float* __restrict__ Wf, const float* __restrict__ bfb,
    const bf16* __restrict__ so, const bf16* __restrict__ nvb16,
    const float* __restrict__ nvA,
    float* __restrict__ ns, float* __restrict__ nvB,
    bf16* __restrict__ nvmsg16, bf16* __restrict__ nsmsg, int N) {
  int i = blockIdx.x;
  int h = threadIdx.x;

  float wf0[E_RBF], wf1[E_RBF], wf2[E_RBF];
  #pragma unroll
  for (int k = 0; k < E_RBF; k++) {
    wf0[k] = Wf[k * F3H + h];
    wf1[k] = Wf[k * F3H + H + h];
    wf2[k] = Wf[k * F3H + 2 * H + h];
  }
  float bb0 = bfb[h], bb1 = bfb[H + h], bb2 = bfb[2 * H + h];

  float accs = 0.0f, a0 = 0.0f, a1 = 0.0f, a2 = 0.0f;
  int jlo = rowstart[i], jhi = jlo + cnt[i];
  int j = jlo;
  for (; j + 1 < jhi; j += 2) {
    int s0 = srcs[j];
    int s1 = srcs[j + 1];
    const bf16* sop0 = so + (size_t)s0 * F3H;
    const bf16* sop1 = so + (size_t)s1 * F3H;
    float sA0 = b2f(sop0[h]), sB0 = b2f(sop0[H + h]), sC0 = b2f(sop0[2 * H + h]);
    float sA1 = b2f(sop1[h]), sB1 = b2f(sop1[H + h]), sC1 = b2f(sop1[2 * H + h]);
    float nA0, nB0, nC0, nA1, nB1, nC1;
    if (HASNV) {
      const bf16* nvp0 = nvb16 + (size_t)s0 * F3H;
      const bf16* nvp1 = nvb16 + (size_t)s1 * F3H;
      nA0 = b2f(nvp0[h]); nB0 = b2f(nvp0[H + h]); nC0 = b2f(nvp0[2 * H + h]);
      nA1 = b2f(nvp1[h]); nB1 = b2f(nvp1[H + h]); nC1 = b2f(nvp1[2 * H + h]);
    }

    {
      const float* g = geo + (size_t)j * 24;
      float gg[24];
      #pragma unroll
      for (int q = 0; q < 6; q++) *(float4*)&gg[4 * q] = *(const float4*)&g[4 * q];
      float fc = gg[23];
      float f0 = bb0 * fc, f1 = bb1 * fc, f2 = bb2 * fc;
      #pragma unroll
      for (int k = 0; k < E_RBF; k++) {
        float rk = gg[k];
        f0 += rk * wf0[k];
        f1 += rk * wf1[k];
        f2 += rk * wf2[k];
      }
      float u0 = gg[20], u1 = gg[21], u2 = gg[22];
      float gsv = f0 * sA0;
      float gev = f1 * sB0;
      accs += f2 * sC0;
      if (HASNV) {
        a0 += nA0 * gsv + gev * u0;
        a1 += nB0 * gsv + gev * u1;
        a2 += nC0 * gsv + gev * u2;
      } else {
        a0 += gev * u0;
        a1 += gev * u1;
        a2 += gev * u2;
      }
    }
    {
      const float* g = geo + (size_t)(j + 1) * 24;
      float gg[24];
      #pragma unroll
      for (int q = 0; q < 6; q++) *(float4*)&gg[4 * q] = *(const float4*)&g[4 * q];
      float fc = gg[23];
      float f0 = bb0 * fc, f1 = bb1 * fc, f2 = bb2 * fc;
      #pragma unroll
      for (int k = 0; k < E_RBF; k++) {
        float rk = gg[k];
        f0 += rk * wf0[k];
        f1 += rk * wf1[k];
        f2 += rk * wf2[k];
      }
      float u0 = gg[20], u1 = gg[21], u2 = gg[22];
      float gsv = f0 * sA1;
      float gev = f1 * sB1;
      accs += f2 * sC1;
      if (HASNV) {
        a0 += nA1 * gsv + gev * u0;
        a1 += nB1 * gsv + gev * u1;
        a2 += nC1 * gsv + gev * u2;
      } else {
        a0 += gev * u0;
        a1 += gev * u1;
        a2 += gev * u2;
      }
    }
  }
  if (j < jhi) {
    int src = srcs[j];
    const float* g = geo + (size_t)j * 24;
    float gg[24];
    #pragma unroll
    for (int q = 0; q < 6; q++) *(float4*)&gg[4 * q] = *(const float4*)&g[4 * q];
    float fc = gg[23];
    float f0 = bb0 * fc, f1 = bb1 * fc, f2 = bb2 * fc;
    #pragma unroll
    for (int k = 0; k < E_RBF; k++) {
      float rk = gg[k];
      f0 += rk * wf0[k];
      f1 += rk * wf1[k];
      f2 += rk * wf2[k];
    }
    float u0 = gg[20], u1 = gg[21], u2 = gg[22];
    const bf16* sop = so + (size_t)src * F3H;
    float gsv = f0 * b2f(sop[h]);
    float gev = f1 * b2f(sop[H + h]);
    accs += f2 * b2f(sop[2 * H + h]);
    if (HASNV) {
      const bf16* nvp = nvb16 + (size_t)src * F3H;
      a0 += b2f(nvp[h])         * gsv + gev * u0;
      a1 += b2f(nvp[H + h])     * gsv + gev * u1;
      a2 += b2f(nvp[2 * H + h]) * gsv + gev * u2;
    } else {
      a0 += gev * u0;
      a1 += gev * u1;
      a2 += gev * u2;
    }
  }

  float ns_new = ns[(size_t)i * H + h] + accs;
  ns[(size_t)i * H + h] = ns_new;
  nsmsg[(size_t)i * H + h] = __float2bfloat16(ns_new);
  float o0, o1, o2;
  if (HASNV) {
    const float* nvi = nvA + (size_t)i * F3H;
    o0 = nvi[h] + a0;
    o1 = nvi[H + h] + a1;
    o2 = nvi[2 * H + h] + a2;
  } else {
    o0 = a0; o1 = a1; o2 = a2;
  }
  nvB[(size_t)i * F3H + h]         = o0;
  nvB[(size_t)i * F3H + H + h]     = o1;
  nvB[(size_t)i * F3H + 2 * H + h] = o2;
  nvmsg16[(size_t)i * F3H + h]         = __float2bfloat16(o0);
  nvmsg16[(size_t)i * F3H + H + h]     = __float2bfloat16(o1);
  nvmsg16[(size_t)i * F3H + 2 * H + h] = __float2bfloat16(o2);
}

extern "C" void kernel_launch(void* const* d_in, const int* in_sizes, int n_in,
                              void* d_out, int out_size, void* d_ws, size_t ws_size,
                              hipStream_t stream) {
  const int*   z     = (const int*)d_in[0];
  const int*   edge  = (const int*)d_in[1];
  const float* ediff = (const float*)d_in[2];
  const float* edist = (const float*)d_in[3];
  const float* embed = (const float*)d_in[4];
  const float* mfw   = (const float*)d_in[5];
  const float* mfb   = (const float*)d_in[6];
  const float* mw1   = (const float*)d_in[7];
  const float* mb1   = (const float*)d_in[8];
  const float* mw2   = (const float*)d_in[9];
  const float* mb2   = (const float*)d_in[10];
  const float* uUw   = (const float*)d_in[11];
  const float* uUb   = (const float*)d_in[12];
  const float* uVw   = (const float*)d_in[13];
  const float* uVb   = (const float*)d_in[14];
  const float* uw1   = (const float*)d_in[15];
  const float* ub1   = (const float*)d_in[16];
  const float* uw2   = (const float*)d_in[17];
  const float* ub2   = (const float*)d_in[18];
  const float* rw1   = (const float*)d_in[19];
  const float* rb1   = (const float*)d_in[20];
  const float* rw2   = (const float*)d_in[21];
  const float* rb2   = (const float*)d_in[22];

  const int N  = in_sizes[0];   // 10000
  const int nE = in_sizes[3];   // 160000

  float* ws = (float*)d_ws;
  size_t off = 0;
  float* ns      = ws + off; off += (size_t)N * H;
  float* nvA     = ws + off; off += (size_t)N * F3H;
  float* nvB     = ws + off; off += (size_t)N * F3H;
  float* geo     = ws + off; off += (size_t)nE * 24;
  bf16* so       = (bf16*)(ws + off); off += (size_t)N * F3H / 2;
  bf16* nvb16    = (bf16*)(ws + off); off += (size_t)N * F3H / 2;
  bf16* nvmsg16  = (bf16*)(ws + off); off += (size_t)N * F3H / 2;
  bf16* nsmsg    = (bf16*)(ws + off); off += (size_t)N * 64;        // N*128 bf16
  bf16* ns16     = (bf16*)(ws + off); off += (size_t)N * 64;        // N*128 bf16
  bf16* wpack    = (bf16*)(ws + off); off += 3 * 2 * 16384 / 2;     // UV
  bf16* wp_m1    = (bf16*)(ws + off); off += 3 * 256 * 128 / 2;
  bf16* wp_m2    = (bf16*)(ws + off); off += 3 * 128 * 384 / 2;
  bf16* wp_sm1   = (bf16*)(ws + off); off += 3 * 128 * 128 / 2;
  bf16* wp_sm2   = (bf16*)(ws + off); off += 3 * 128 * 384 / 2;
  bf16* wp_ro1   = (bf16*)(ws + off); off += 128 * 128 / 2;
  bf16* wp_ro2   = (bf16*)(ws + off); off += 128 * 128 / 2;
  int* srcs     = (int*)(ws + off); off += nE;
  int* cnt      = (int*)(ws + off); off += N;
  int* rowstart = (int*)(ws + off); off += N;
  int* cur      = (int*)(ws + off); off += N;
  int* elist    = (int*)(ws + off); off += nE;

  const int tilesN = (N + 31) / 32;            // 313

  (void)hipMemsetAsync(cnt, 0, (size_t)N * sizeof(int), stream);
  csr_hist<<<(nE + 255) / 256, 256, 0, stream>>>(edge, cnt, nE);
  csr_scan<<<1, 256, 0, stream>>>(cnt, rowstart, cur, N);
  csr_fill<<<(nE + 255) / 256, 256, 0, stream>>>(edge, cur, elist, nE);
  edge_pack<<<(nE + 255) / 256, 256, 0, stream>>>(elist, edge, edist, ediff, srcs, geo, nE);
  pack_w<<<48, 256, 0, stream>>>(uUw, uVw, wpack);
  pack_b<<<48, 256, 0, stream>>>(uw1, wp_m1, 256, 128, 3);
  pack_b<<<72, 256, 0, stream>>>(uw2, wp_m2, 128, 384, 3);
  pack_b<<<24, 256, 0, stream>>>(mw1, wp_sm1, 128, 128, 3);
  pack_b<<<72, 256, 0, stream>>>(mw2, wp_sm2, 128, 384, 3);
  pack_b<<<8, 256, 0, stream>>>(rw1, wp_ro1, 128, 128, 1);
  pack_b<<<8, 256, 0, stream>>>(rw2, wp_ro2, 128, 128, 1);

  node_init<<<N, H, 0, stream>>>(z, embed, ns, ns16, N);

  float* nv_cur = nvA;
  float* nv_nxt = nvB;
  for (int l = 0; l < NLAYER; l++) {
    mlp_msg<<<tilesN, 256, 0, stream>>>(
        ns16, wp_sm1 + (size_t)l * 128 * 128, mb1 + (size_t)l * H,
        wp_sm2 + (size_t)l * 128 * 384, mb2 + (size_t)l * F3H, so, N);

    if (l == 0)
      message3<false><<<N, H, 0, stream>>>(srcs, rowstart, cnt, geo,
                                           mfw + (size_t)l * E_RBF * F3H, mfb + (size_t)l * F3H,
                                           so, nvb16, nv_cur, ns, nv_nxt, nvmsg16, nsmsg, N);
    else
      message3<true><<<N, H, 0, stream>>>(srcs, rowstart, cnt, geo,
                                          mfw + (size_t)l * E_RBF * F3H, mfb + (size_t)l * F3H,
                                          so, nvb16, nv_cur, ns, nv_nxt, nvmsg16, nsmsg, N);

    uv_upd<<<tilesN, 384, 0, stream>>>(
        nvmsg16, wpack + (size_t)l * 2 * 16384,
        uUb + (size_t)l * H, uVb + (size_t)l * H,
        nsmsg,
        wp_m1 + (size_t)l * 256 * 128, ub1 + (size_t)l * H,
        wp_m2 + (size_t)l * 128 * 384, ub2 + (size_t)l * F3H,
        ns, ns16, nv_nxt, nvb16, N);

    float* t = nv_cur; nv_cur = nv_nxt; nv_nxt = t;
  }

  mlp_ro<<<tilesN, 256, 0, stream>>>(
      ns16, wp_ro1, rb1, wp_ro2, rb2, (float*)d_out, N);
}

// Round 7
// 483.175 us; speedup vs baseline: 1.4108x; 1.0691x over previous
//
#include <hip/hip_runtime.h>
#include <hip/hip_bf16.h>

typedef __hip_bfloat16 bf16;
typedef __attribute__((ext_vector_type(8))) short bf16x8;
typedef __attribute__((ext_vector_type(4))) float f32x4;

#define H 128
#define F3H 384
#define E_RBF 20
#define NLAYER 3

__device__ __forceinline__ float silu_f(float x) { return x / (1.0f + __expf(-x)); }
__device__ __forceinline__ float b2f(bf16 x) { return __bfloat162float(x); }

constexpr float PI_F = 3.14159265358979323846f;
constexpr float CUT = 5.0f;

// ---------------- CSR hist ----------------
__global__ __launch_bounds__(256) void csr_hist(
    const int* __restrict__ edge, int* __restrict__ cnt, int nE) {
  int e = blockIdx.x * blockDim.x + threadIdx.x;
  if (e < nE) atomicAdd(&cnt[edge[2 * e]], 1);
}

// ---------------- CSR scan: 1024-thread LDS tree scan ----------------
__global__ __launch_bounds__(1024) void csr_scan(
    const int* __restrict__ cnt, int* __restrict__ rowstart, int* __restrict__ cur, int N) {
  __shared__ int part[1024];
  int t = threadIdx.x;
  int chunk = (N + 1023) / 1024;
  int lo = t * chunk; if (lo > N) lo = N;
  int hi = lo + chunk; if (hi > N) hi = N;
  int s = 0;
  for (int i = lo; i < hi; i++) s += cnt[i];
  part[t] = s;
  __syncthreads();
  // Hillis-Steele inclusive scan
  for (int off = 1; off < 1024; off <<= 1) {
    int v = (t >= off) ? part[t - off] : 0;
    __syncthreads();
    part[t] += v;
    __syncthreads();
  }
  int r = (t == 0) ? 0 : part[t - 1];
  for (int i = lo; i < hi; i++) { rowstart[i] = r; cur[i] = r; r += cnt[i]; }
}

// ---------------- CSR fill + edge geometry pack (fused; no elist) ----------------
__global__ __launch_bounds__(256) void csr_fill_pack(
    const int* __restrict__ edge, int* __restrict__ cur,
    const float* __restrict__ edist, const float* __restrict__ ediff,
    int* __restrict__ srcs, float* __restrict__ geo, int nE) {
  int e = blockIdx.x * blockDim.x + threadIdx.x;
  if (e >= nE) return;
  int d = edge[2 * e];
  int p = atomicAdd(&cur[d], 1);
  srcs[p] = edge[2 * e + 1];
  float dd = edist[e];
  float inv = 1.0f / dd;
  float th = dd * (PI_F / CUT);
  float s1 = sinf(th), c1 = cosf(th);
  float fc = (dd < CUT) ? 0.5f * (c1 + 1.0f) : 0.0f;
  float* g = geo + (size_t)p * 24;
  float twoc = 2.0f * c1;
  float skp = 0.0f, sk = s1;
  #pragma unroll
  for (int k = 0; k < E_RBF; k++) {
    g[k] = sk * inv * fc;
    float nx = twoc * sk - skp;
    skp = sk; sk = nx;
  }
  g[20] = ediff[3 * (size_t)e] * inv;
  g[21] = ediff[3 * (size_t)e + 1] * inv;
  g[22] = ediff[3 * (size_t)e + 2] * inv;
  g[23] = fc;
}

// ---------------- device helpers for weight packing ----------------
__device__ __forceinline__ void pack_w_item(
    const float* __restrict__ Wu, const float* __restrict__ Wv,
    bf16* __restrict__ wp, int t) {
  int lane = t & 63;
  int c    = (t >> 6) & 7;
  int kb   = (t >> 9) & 3;
  int mat  = (t >> 11) & 1;
  int l    = t >> 12;
  const float* src = (mat ? Wv : Wu) + (size_t)l * H * H;
  bf16* dst = wp + ((size_t)(l * 2 + mat) * 16384) + (((kb * 8 + c) * 64 + lane) * 8);
  int quad = lane >> 4;
  int n = c * 16 + (lane & 15);
  #pragma unroll
  for (int j = 0; j < 8; j++) {
    int k = kb * 32 + quad * 8 + j;
    dst[j] = __float2bfloat16(src[(size_t)k * H + n]);
  }
}

__device__ __forceinline__ void pack_b_item(
    const float* __restrict__ src, bf16* __restrict__ dst,
    int K, int ncols, int t) {
  int kblocks = K >> 5, ncols16 = ncols >> 4;
  int lane = t & 63;
  int idx = t >> 6;
  int c = idx % ncols16; idx /= ncols16;
  int kb = idx % kblocks; idx /= kblocks;
  int l = idx;
  const float* s = src + (size_t)l * K * ncols;
  bf16* d = dst + (size_t)l * K * ncols + (((kb * ncols16 + c) * 64 + lane) * 8);
  int quad = lane >> 4;
  int n = c * 16 + (lane & 15);
  #pragma unroll
  for (int j = 0; j < 8; j++) {
    int k = kb * 32 + quad * 8 + j;
    d[j] = __float2bfloat16(s[(size_t)k * ncols + n]);
  }
}

// ---------------- one-shot setup: all weight packs + node_init + cnt zero ----------------
__global__ __launch_bounds__(256) void pack_all(
    const float* __restrict__ Wu, const float* __restrict__ Wv, bf16* __restrict__ wpack,
    const float* __restrict__ uw1, bf16* __restrict__ wp_m1,
    const float* __restrict__ uw2, bf16* __restrict__ wp_m2,
    const float* __restrict__ mw1, bf16* __restrict__ wp_sm1,
    const float* __restrict__ mw2, bf16* __restrict__ wp_sm2,
    const float* __restrict__ rw1, bf16* __restrict__ wp_ro1,
    const float* __restrict__ rw2, bf16* __restrict__ wp_ro2,
    const int* __restrict__ z, const float* __restrict__ embed,
    float* __restrict__ ns, bf16* __restrict__ ns16,
    int* __restrict__ cnt, int N) {
  const int T0 = 12288;            // pack_w (UV)
  const int T1 = T0 + 12288;       // uw1 K=256 n=128 L=3
  const int T2 = T1 + 18432;       // uw2 K=128 n=384 L=3
  const int T3 = T2 + 6144;        // mw1 K=128 n=128 L=3
  const int T4 = T3 + 18432;       // mw2 K=128 n=384 L=3
  const int T5 = T4 + 2048;        // rw1
  const int T6 = T5 + 2048;        // rw2
  const int TN = T6 + N * H;       // node_init
  const int TT = TN + N;           // cnt zero
  for (int t = blockIdx.x * blockDim.x + threadIdx.x; t < TT; t += gridDim.x * blockDim.x) {
    if (t < T0)      pack_w_item(Wu, Wv, wpack, t);
    else if (t < T1) pack_b_item(uw1, wp_m1, 256, 128, t - T0);
    else if (t < T2) pack_b_item(uw2, wp_m2, 128, 384, t - T1);
    else if (t < T3) pack_b_item(mw1, wp_sm1, 128, 128, t - T2);
    else if (t < T4) pack_b_item(mw2, wp_sm2, 128, 384, t - T3);
    else if (t < T5) pack_b_item(rw1, wp_ro1, 128, 128, t - T4);
    else if (t < T6) pack_b_item(rw2, wp_ro2, 128, 128, t - T5);
    else if (t < TN) {
      int u = t - T6;
      int i = u >> 7, h = u & 127;
      float v = embed[(size_t)z[i] * H + h];
      ns[(size_t)i * H + h] = v;
      ns16[(size_t)i * H + h] = __float2bfloat16(v);
    } else {
      cnt[t - TN] = 0;
    }
  }
}

// ---------------- fused 2-stage MLP: so = (silu(A@W1+b1))@W2+b2, 384 cols ----------------
__global__ __launch_bounds__(256) void mlp_msg(
    const bf16* __restrict__ A, const bf16* __restrict__ Wp1,
    const float* __restrict__ b1, const bf16* __restrict__ Wp2,
    const float* __restrict__ b2, bf16* __restrict__ so, int M) {
  __shared__ bf16 m1l[32][136];
  int wave = threadIdx.x >> 6, lane = threadIdx.x & 63;
  int rowg = wave >> 1, ch = wave & 1;
  int r0 = blockIdx.x * 32 + rowg * 16;
  int quad = lane >> 4, nn = lane & 15;
  int arow = r0 + nn; if (arow >= M) arow = M - 1;
  f32x4 acc[4] = {};
  for (int kb = 0; kb < 4; kb++) {
    bf16x8 af = *(const bf16x8*)&A[(size_t)arow * H + kb * 32 + quad * 8];
    #pragma unroll
    for (int c = 0; c < 4; c++) {
      int cg = ch * 4 + c;
      bf16x8 bw = *(const bf16x8*)&Wp1[(((kb * 8 + cg) * 64) + lane) * 8];
      acc[c] = __builtin_amdgcn_mfma_f32_16x16x32_bf16(af, bw, acc[c], 0, 0, 0);
    }
  }
  #pragma unroll
  for (int c = 0; c < 4; c++) {
    int n = (ch * 4 + c) * 16 + nn;
    float bb = b1[n];
    #pragma unroll
    for (int r = 0; r < 4; r++) {
      int lr = rowg * 16 + quad * 4 + r;
      m1l[lr][n] = __float2bfloat16(silu_f(acc[c][r] + bb));
    }
  }
  __syncthreads();
  f32x4 a0[4] = {}, a1[4] = {}, a2[4] = {};
  for (int kb = 0; kb < 4; kb++) {
    bf16x8 af = *(const bf16x8*)&m1l[rowg * 16 + nn][kb * 32 + quad * 8];
    #pragma unroll
    for (int c = 0; c < 4; c++) {
      int cg = ch * 4 + c;
      bf16x8 b0 = *(const bf16x8*)&Wp2[(((kb * 24 + cg) * 64) + lane) * 8];
      bf16x8 b1v = *(const bf16x8*)&Wp2[(((kb * 24 + cg + 8) * 64) + lane) * 8];
      bf16x8 b2v = *(const bf16x8*)&Wp2[(((kb * 24 + cg + 16) * 64) + lane) * 8];
      a0[c] = __builtin_amdgcn_mfma_f32_16x16x32_bf16(af, b0, a0[c], 0, 0, 0);
      a1[c] = __builtin_amdgcn_mfma_f32_16x16x32_bf16(af, b1v, a1[c], 0, 0, 0);
      a2[c] = __builtin_amdgcn_mfma_f32_16x16x32_bf16(af, b2v, a2[c], 0, 0, 0);
    }
  }
  #pragma unroll
  for (int c = 0; c < 4; c++) {
    int n = (ch * 4 + c) * 16 + nn;
    float bb0 = b2[n], bb1 = b2[H + n], bb2 = b2[2 * H + n];
    #pragma unroll
    for (int r = 0; r < 4; r++) {
      int row = r0 + quad * 4 + r;
      if (row < M) {
        so[(size_t)row * F3H + n]           = __float2bfloat16(a0[c][r] + bb0);
        so[(size_t)row * F3H + H + n]       = __float2bfloat16(a1[c][r] + bb1);
        so[(size_t)row * F3H + 2 * H + n]   = __float2bfloat16(a2[c][r] + bb2);
      }
    }
  }
}

// ---------------- fused UV dual-GEMM + vnorm + update-MLP + gating epilogue ----------------
__global__ __launch_bounds__(384) void uv_upd(
    const bf16* __restrict__ A, const bf16* __restrict__ Wpuv,
    const float* __restrict__ bu, const float* __restrict__ bv,
    const bf16* __restrict__ nsmsg,
    const bf16* __restrict__ Wp1, const float* __restrict__ b1,
    const bf16* __restrict__ Wp2, const float* __restrict__ b2,
    float* __restrict__ ns, bf16* __restrict__ ns16,
    float* __restrict__ nv, bf16* __restrict__ nvb16, int N) {
  __shared__ float Uv_l[96][132];
  __shared__ float Vv_l[96][132];
  __shared__ bf16 vn_l[32][136];
  __shared__ bf16 m1l[32][136];
  int wave = threadIdx.x >> 6;
  int lane = threadIdx.x & 63;
  int quad = lane >> 4, nn = lane & 15;
  int M3 = 3 * N;

  {
    int r0 = blockIdx.x * 96 + wave * 16;
    int arow = r0 + nn; if (arow >= M3) arow = M3 - 1;
    f32x4 accu[8] = {};
    f32x4 accv[8] = {};
    for (int kb = 0; kb < 4; kb++) {
      bf16x8 af = *(const bf16x8*)&A[(size_t)arow * H + kb * 32 + quad * 8];
      #pragma unroll
      for (int c = 0; c < 8; c++) {
        bf16x8 bfu = *(const bf16x8*)&Wpuv[(((kb * 8 + c) * 64) + lane) * 8];
        bf16x8 bfv = *(const bf16x8*)&Wpuv[16384 + (((kb * 8 + c) * 64) + lane) * 8];
        accu[c] = __builtin_amdgcn_mfma_f32_16x16x32_bf16(af, bfu, accu[c], 0, 0, 0);
        accv[c] = __builtin_amdgcn_mfma_f32_16x16x32_bf16(af, bfv, accv[c], 0, 0, 0);
      }
    }
    #pragma unroll
    for (int c = 0; c < 8; c++) {
      int n = c * 16 + nn;
      float bub = bu[n], bvb = bv[n];
      #pragma unroll
      for (int r = 0; r < 4; r++) {
        int lr = wave * 16 + quad * 4 + r;
        Uv_l[lr][n] = accu[c][r] + bub;
        Vv_l[lr][n] = accv[c][r] + bvb;
      }
    }
  }
  __syncthreads();

  for (int t = threadIdx.x; t < 32 * H; t += 384) {
    int node = t >> 7, hh = t & 127;
    float v0 = Vv_l[node * 3][hh];
    float v1 = Vv_l[node * 3 + 1][hh];
    float v2 = Vv_l[node * 3 + 2][hh];
    vn_l[node][hh] = __float2bfloat16(sqrtf(v0 * v0 + v1 * v1 + v2 * v2));
  }
  __syncthreads();

  int rowg = wave >> 1, ch = wave & 1;
  int r0n = blockIdx.x * 32 + rowg * 16;
  int arown = r0n + nn; if (arown >= N) arown = N - 1;
  if (wave < 4) {
    f32x4 acc[4] = {};
    for (int kb = 0; kb < 8; kb++) {
      bf16x8 af;
      if (kb < 4) af = *(const bf16x8*)&vn_l[rowg * 16 + nn][kb * 32 + quad * 8];
      else        af = *(const bf16x8*)&nsmsg[(size_t)arown * H + (kb - 4) * 32 + quad * 8];
      #pragma unroll
      for (int c = 0; c < 4; c++) {
        int cg = ch * 4 + c;
        bf16x8 bw = *(const bf16x8*)&Wp1[(((kb * 8 + cg) * 64) + lane) * 8];
        acc[c] = __builtin_amdgcn_mfma_f32_16x16x32_bf16(af, bw, acc[c], 0, 0, 0);
      }
    }
    #pragma unroll
    for (int c = 0; c < 4; c++) {
      int n = (ch * 4 + c) * 16 + nn;
      float bb = b1[n];
      #pragma unroll
      for (int r = 0; r < 4; r++) {
        int lr = rowg * 16 + quad * 4 + r;
        m1l[lr][n] = __float2bfloat16(silu_f(acc[c][r] + bb));
      }
    }
  }
  __syncthreads();

  if (wave < 4) {
    f32x4 aav[4] = {}, aas[4] = {}, asz[4] = {};
    for (int kb = 0; kb < 4; kb++) {
      bf16x8 af = *(const bf16x8*)&m1l[rowg * 16 + nn][kb * 32 + quad * 8];
      #pragma unroll
      for (int c = 0; c < 4; c++) {
        int cg = ch * 4 + c;
        bf16x8 b0 = *(const bf16x8*)&Wp2[(((kb * 24 + cg) * 64) + lane) * 8];
        bf16x8 b1v = *(const bf16x8*)&Wp2[(((kb * 24 + cg + 8) * 64) + lane) * 8];
        bf16x8 b2v = *(const bf16x8*)&Wp2[(((kb * 24 + cg + 16) * 64) + lane) * 8];
        aav[c] = __builtin_amdgcn_mfma_f32_16x16x32_bf16(af, b0, aav[c], 0, 0, 0);
        aas[c] = __builtin_amdgcn_mfma_f32_16x16x32_bf16(af, b1v, aas[c], 0, 0, 0);
        asz[c] = __builtin_amdgcn_mfma_f32_16x16x32_bf16(af, b2v, asz[c], 0, 0, 0);
      }
    }
    #pragma unroll
    for (int c = 0; c < 4; c++) {
      int n = (ch * 4 + c) * 16 + nn;
      float bav = b2[n], bas = b2[H + n], bss = b2[2 * H + n];
      #pragma unroll
      for (int r = 0; r < 4; r++) {
        int row = r0n + quad * 4 + r;
        if (row < N) {
          int lrn = rowg * 16 + quad * 4 + r;
          float avv = aav[c][r] + bav;
          float asv = aas[c][r] + bas;
          float ass = asz[c][r] + bss;
          float u0 = Uv_l[lrn * 3 + 0][n];
          float u1 = Uv_l[lrn * 3 + 1][n];
          float u2 = Uv_l[lrn * 3 + 2][n];
          float v0 = Vv_l[lrn * 3 + 0][n];
          float v1 = Vv_l[lrn * 3 + 1][n];
          float v2 = Vv_l[lrn * 3 + 2][n];
          float dot = u0 * v0 + u1 * v1 + u2 * v2;
          float ns_new = ns[(size_t)row * H + n] + asv * dot + ass;
          ns[(size_t)row * H + n] = ns_new;
          ns16[(size_t)row * H + n] = __float2bfloat16(ns_new);
          float n0 = nv[(size_t)(3 * row + 0) * H + n] + avv * u0;
          float n1 = nv[(size_t)(3 * row + 1) * H + n] + avv * u1;
          float n2 = nv[(size_t)(3 * row + 2) * H + n] + avv * u2;
          nv[(size_t)(3 * row + 0) * H + n] = n0;
          nv[(size_t)(3 * row + 1) * H + n] = n1;
          nv[(size_t)(3 * row + 2) * H + n] = n2;
          nvb16[(size_t)(3 * row + 0) * H + n] = __float2bfloat16(n0);
          nvb16[(size_t)(3 * row + 1) * H + n] = __float2bfloat16(n1);
          nvb16[(size_t)(3 * row + 2) * H + n] = __float2bfloat16(n2);
        }
      }
    }
  }
}

// ---------------- fused readout: out = (silu(ns16@rw1+rb1))@rw2+rb2 ----------------
__global__ __launch_bounds__(256) void mlp_ro(
    const bf16* __restrict__ A, const bf16* __restrict__ Wp1,
    const float* __restrict__ b1, const bf16* __restrict__ Wp2,
    const float* __restrict__ b2, float* __restrict__ out, int M) {
  __shared__ bf16 m1l[32][136];
  int wave = threadIdx.x >> 6, lane = threadIdx.x & 63;
  int rowg = wave >> 1, ch = wave & 1;
  int r0 = blockIdx.x * 32 + rowg * 16;
  int quad = lane >> 4, nn = lane & 15;
  int arow = r0 + nn; if (arow >= M) arow = M - 1;
  f32x4 acc[4] = {};
  for (int kb = 0; kb < 4; kb++) {
    bf16x8 af = *(const bf16x8*)&A[(size_t)arow * H + kb * 32 + quad * 8];
    #pragma unroll
    for (int c = 0; c < 4; c++) {
      int cg = ch * 4 + c;
      bf16x8 bw = *(const bf16x8*)&Wp1[(((kb * 8 + cg) * 64) + lane) * 8];
      acc[c] = __builtin_amdgcn_mfma_f32_16x16x32_bf16(af, bw, acc[c], 0, 0, 0);
    }
  }
  #pragma unroll
  for (int c = 0; c < 4; c++) {
    int n = (ch * 4 + c) * 16 + nn;
    float bb = b1[n];
    #pragma unroll
    for (int r = 0; r < 4; r++) {
      int lr = rowg * 16 + quad * 4 + r;
      m1l[lr][n] = __float2bfloat16(silu_f(acc[c][r] + bb));
    }
  }
  __syncthreads();
  f32x4 a2[4] = {};
  for (int kb = 0; kb < 4; kb++) {
    bf16x8 af = *(const bf16x8*)&m1l[rowg * 16 + nn][kb * 32 + quad * 8];
    #pragma unroll
    for (int c = 0; c < 4; c++) {
      int cg = ch * 4 + c;
      bf16x8 bw = *(const bf16x8*)&Wp2[(((kb * 8 + cg) * 64) + lane) * 8];
      a2[c] = __builtin_amdgcn_mfma_f32_16x16x32_bf16(af, bw, a2[c], 0, 0, 0);
    }
  }
  #pragma unroll
  for (int c = 0; c < 4; c++) {
    int n = (ch * 4 + c) * 16 + nn;
    float bb = b2[n];
    #pragma unroll
    for (int r = 0; r < 4; r++) {
      int row = r0 + quad * 4 + r;
      if (row < M) out[(size_t)row * H + n] = a2[c][r] + bb;
    }
  }
}

// ---------------- message: round-0 structure, edge loop unrolled x2 ----------------
// At the measured random-gather ceiling (~2.15 TB/s effective, invariant under
// r1-r4 restructures). Do not restructure further.
template<bool HASNV>
__global__ __launch_bounds__(128, 4) void message3(
    const int* __restrict__ srcs, const int* __restrict__ rowstart,
    const int* __restrict__ cnt, const float* __restrict__ geo,
    const float* __restrict__ Wf, const float* __restrict__ bfb,
    const bf16* __restrict__ so, const bf16* __restrict__ nvb16,
    const float* __restrict__ nvA,
    float* __restrict__ ns, float* __restrict__ nvB,
    bf16* __restrict__ nvmsg16, bf16* __restrict__ nsmsg, int N) {
  int i = blockIdx.x;
  int h = threadIdx.x;

  float wf0[E_RBF], wf1[E_RBF], wf2[E_RBF];
  #pragma unroll
  for (int k = 0; k < E_RBF; k++) {
    wf0[k] = Wf[k * F3H + h];
    wf1[k] = Wf[k * F3H + H + h];
    wf2[k] = Wf[k * F3H + 2 * H + h];
  }
  float bb0 = bfb[h], bb1 = bfb[H + h], bb2 = bfb[2 * H + h];

  float accs = 0.0f, a0 = 0.0f, a1 = 0.0f, a2 = 0.0f;
  int jlo = rowstart[i], jhi = jlo + cnt[i];
  int j = jlo;
  for (; j + 1 < jhi; j += 2) {
    int s0 = srcs[j];
    int s1 = srcs[j + 1];
    const bf16* sop0 = so + (size_t)s0 * F3H;
    const bf16* sop1 = so + (size_t)s1 * F3H;
    float sA0 = b2f(sop0[h]), sB0 = b2f(sop0[H + h]), sC0 = b2f(sop0[2 * H + h]);
    float sA1 = b2f(sop1[h]), sB1 = b2f(sop1[H + h]), sC1 = b2f(sop1[2 * H + h]);
    float nA0, nB0, nC0, nA1, nB1, nC1;
    if (HASNV) {
      const bf16* nvp0 = nvb16 + (size_t)s0 * F3H;
      const bf16* nvp1 = nvb16 + (size_t)s1 * F3H;
      nA0 = b2f(nvp0[h]); nB0 = b2f(nvp0[H + h]); nC0 = b2f(nvp0[2 * H + h]);
      nA1 = b2f(nvp1[h]); nB1 = b2f(nvp1[H + h]); nC1 = b2f(nvp1[2 * H + h]);
    }

    {
      const float* g = geo + (size_t)j * 24;
      float gg[24];
      #pragma unroll
      for (int q = 0; q < 6; q++) *(float4*)&gg[4 * q] = *(const float4*)&g[4 * q];
      float fc = gg[23];
      float f0 = bb0 * fc, f1 = bb1 * fc, f2 = bb2 * fc;
      #pragma unroll
      for (int k = 0; k < E_RBF; k++) {
        float rk = gg[k];
        f0 += rk * wf0[k];
        f1 += rk * wf1[k];
        f2 += rk * wf2[k];
      }
      float u0 = gg[20], u1 = gg[21], u2 = gg[22];
      float gsv = f0 * sA0;
      float gev = f1 * sB0;
      accs += f2 * sC0;
      if (HASNV) {
        a0 += nA0 * gsv + gev * u0;
        a1 += nB0 * gsv + gev * u1;
        a2 += nC0 * gsv + gev * u2;
      } else {
        a0 += gev * u0;
        a1 += gev * u1;
        a2 += gev * u2;
      }
    }
    {
      const float* g = geo + (size_t)(j + 1) * 24;
      float gg[24];
      #pragma unroll
      for (int q = 0; q < 6; q++) *(float4*)&gg[4 * q] = *(const float4*)&g[4 * q];
      float fc = gg[23];
      float f0 = bb0 * fc, f1 = bb1 * fc, f2 = bb2 * fc;
      #pragma unroll
      for (int k = 0; k < E_RBF; k++) {
        float rk = gg[k];
        f0 += rk * wf0[k];
        f1 += rk * wf1[k];
        f2 += rk * wf2[k];
      }
      float u0 = gg[20], u1 = gg[21], u2 = gg[22];
      float gsv = f0 * sA1;
      float gev = f1 * sB1;
      accs += f2 * sC1;
      if (HASNV) {
        a0 += nA1 * gsv + gev * u0;
        a1 += nB1 * gsv + gev * u1;
        a2 += nC1 * gsv + gev * u2;
      } else {
        a0 += gev * u0;
        a1 += gev * u1;
        a2 += gev * u2;
      }
    }
  }
  if (j < jhi) {
    int src = srcs[j];
    const float* g = geo + (size_t)j * 24;
    float gg[24];
    #pragma unroll
    for (int q = 0; q < 6; q++) *(float4*)&gg[4 * q] = *(const float4*)&g[4 * q];
    float fc = gg[23];
    float f0 = bb0 * fc, f1 = bb1 * fc, f2 = bb2 * fc;
    #pragma unroll
    for (int k = 0; k < E_RBF; k++) {
      float rk = gg[k];
      f0 += rk * wf0[k];
      f1 += rk * wf1[k];
      f2 += rk * wf2[k];
    }
    float u0 = gg[20], u1 = gg[21], u2 = gg[22];
    const bf16* sop = so + (size_t)src * F3H;
    float gsv = f0 * b2f(sop[h]);
    float gev = f1 * b2f(sop[H + h]);
    accs += f2 * b2f(sop[2 * H + h]);
    if (HASNV) {
      const bf16* nvp = nvb16 + (size_t)src * F3H;
      a0 += b2f(nvp[h])         * gsv + gev * u0;
      a1 += b2f(nvp[H + h])     * gsv + gev * u1;
      a2 += b2f(nvp[2 * H + h]) * gsv + gev * u2;
    } else {
      a0 += gev * u0;
      a1 += gev * u1;
      a2 += gev * u2;
    }
  }

  float ns_new = ns[(size_t)i * H + h] + accs;
  ns[(size_t)i * H + h] = ns_new;
  nsmsg[(size_t)i * H + h] = __float2bfloat16(ns_new);
  float o0, o1, o2;
  if (HASNV) {
    const float* nvi = nvA + (size_t)i * F3H;
    o0 = nvi[h] + a0;
    o1 = nvi[H + h] + a1;
    o2 = nvi[2 * H + h] + a2;
  } else {
    o0 = a0; o1 = a1; o2 = a2;
  }
  nvB[(size_t)i * F3H + h]         = o0;
  nvB[(size_t)i * F3H + H + h]     = o1;
  nvB[(size_t)i * F3H + 2 * H + h] = o2;
  nvmsg16[(size_t)i * F3H + h]         = __float2bfloat16(o0);
  nvmsg16[(size_t)i * F3H + H + h]     = __float2bfloat16(o1);
  nvmsg16[(size_t)i * F3H + 2 * H + h] = __float2bfloat16(o2);
}

extern "C" void kernel_launch(void* const* d_in, const int* in_sizes, int n_in,
                              void* d_out, int out_size, void* d_ws, size_t ws_size,
                              hipStream_t stream) {
  const int*   z     = (const int*)d_in[0];
  const int*   edge  = (const int*)d_in[1];
  const float* ediff = (const float*)d_in[2];
  const float* edist = (const float*)d_in[3];
  const float* embed = (const float*)d_in[4];
  const float* mfw   = (const float*)d_in[5];
  const float* mfb   = (const float*)d_in[6];
  const float* mw1   = (const float*)d_in[7];
  const float* mb1   = (const float*)d_in[8];
  const float* mw2   = (const float*)d_in[9];
  const float* mb2   = (const float*)d_in[10];
  const float* uUw   = (const float*)d_in[11];
  const float* uUb   = (const float*)d_in[12];
  const float* uVw   = (const float*)d_in[13];
  const float* uVb   = (const float*)d_in[14];
  const float* uw1   = (const float*)d_in[15];
  const float* ub1   = (const float*)d_in[16];
  const float* uw2   = (const float*)d_in[17];
  const float* ub2   = (const float*)d_in[18];
  const float* rw1   = (const float*)d_in[19];
  const float* rb1   = (const float*)d_in[20];
  const float* rw2   = (const float*)d_in[21];
  const float* rb2   = (const float*)d_in[22];

  const int N  = in_sizes[0];   // 10000
  const int nE = in_sizes[3];   // 160000

  float* ws = (float*)d_ws;
  size_t off = 0;
  float* ns      = ws + off; off += (size_t)N * H;
  float* nvA     = ws + off; off += (size_t)N * F3H;
  float* nvB     = ws + off; off += (size_t)N * F3H;
  float* geo     = ws + off; off += (size_t)nE * 24;
  bf16* so       = (bf16*)(ws + off); off += (size_t)N * F3H / 2;
  bf16* nvb16    = (bf16*)(ws + off); off += (size_t)N * F3H / 2;
  bf16* nvmsg16  = (bf16*)(ws + off); off += (size_t)N * F3H / 2;
  bf16* nsmsg    = (bf16*)(ws + off); off += (size_t)N * 64;        // N*128 bf16
  bf16* ns16     = (bf16*)(ws + off); off += (size_t)N * 64;        // N*128 bf16
  bf16* wpack    = (bf16*)(ws + off); off += 3 * 2 * 16384 / 2;     // UV
  bf16* wp_m1    = (bf16*)(ws + off); off += 3 * 256 * 128 / 2;
  bf16* wp_m2    = (bf16*)(ws + off); off += 3 * 128 * 384 / 2;
  bf16* wp_sm1   = (bf16*)(ws + off); off += 3 * 128 * 128 / 2;
  bf16* wp_sm2   = (bf16*)(ws + off); off += 3 * 128 * 384 / 2;
  bf16* wp_ro1   = (bf16*)(ws + off); off += 128 * 128 / 2;
  bf16* wp_ro2   = (bf16*)(ws + off); off += 128 * 128 / 2;
  int* srcs     = (int*)(ws + off); off += nE;
  int* cnt      = (int*)(ws + off); off += N;
  int* rowstart = (int*)(ws + off); off += N;
  int* cur      = (int*)(ws + off); off += N;

  const int tilesN = (N + 31) / 32;            // 313

  // one-shot setup (weight packs + node_init + cnt zero), then CSR chain
  pack_all<<<1024, 256, 0, stream>>>(
      uUw, uVw, wpack, uw1, wp_m1, uw2, wp_m2, mw1, wp_sm1, mw2, wp_sm2,
      rw1, wp_ro1, rw2, wp_ro2, z, embed, ns, ns16, cnt, N);
  csr_hist<<<(nE + 255) / 256, 256, 0, stream>>>(edge, cnt, nE);
  csr_scan<<<1, 1024, 0, stream>>>(cnt, rowstart, cur, N);
  csr_fill_pack<<<(nE + 255) / 256, 256, 0, stream>>>(edge, cur, edist, ediff, srcs, geo, nE);

  float* nv_cur = nvA;
  float* nv_nxt = nvB;
  for (int l = 0; l < NLAYER; l++) {
    mlp_msg<<<tilesN, 256, 0, stream>>>(
        ns16, wp_sm1 + (size_t)l * 128 * 128, mb1 + (size_t)l * H,
        wp_sm2 + (size_t)l * 128 * 384, mb2 + (size_t)l * F3H, so, N);

    if (l == 0)
      message3<false><<<N, H, 0, stream>>>(srcs, rowstart, cnt, geo,
                                           mfw + (size_t)l * E_RBF * F3H, mfb + (size_t)l * F3H,
                                           so, nvb16, nv_cur, ns, nv_nxt, nvmsg16, nsmsg, N);
    else
      message3<true><<<N, H, 0, stream>>>(srcs, rowstart, cnt, geo,
                                          mfw + (size_t)l * E_RBF * F3H, mfb + (size_t)l * F3H,
                                          so, nvb16, nv_cur, ns, nv_nxt, nvmsg16, nsmsg, N);

    uv_upd<<<tilesN, 384, 0, stream>>>(
        nvmsg16, wpack + (size_t)l * 2 * 16384,
        uUb + (size_t)l * H, uVb + (size_t)l * H,
        nsmsg,
        wp_m1 + (size_t)l * 256 * 128, ub1 + (size_t)l * H,
        wp_m2 + (size_t)l * 128 * 384, ub2 + (size_t)l * F3H,
        ns, ns16, nv_nxt, nvb16, N);

    float* t = nv_cur; nv_cur = nv_nxt; nv_nxt = t;
  }

  mlp_ro<<<tilesN, 256, 0, stream>>>(
      ns16, wp_ro1, rb1, wp_ro2, rb2, (float*)d_out, N);
}

// Round 8
// 453.823 us; speedup vs baseline: 1.5020x; 1.0647x over previous
//
#include <hip/hip_runtime.h>
#include <hip/hip_bf16.h>

typedef __hip_bfloat16 bf16;
typedef __attribute__((ext_vector_type(8))) short bf16x8;
typedef __attribute__((ext_vector_type(4))) float f32x4;

#define H 128
#define F3H 384
#define E_RBF 20
#define NLAYER 3

__device__ __forceinline__ float silu_f(float x) { return x / (1.0f + __expf(-x)); }
__device__ __forceinline__ float b2f(bf16 x) { return __bfloat162float(x); }

constexpr float PI_F = 3.14159265358979323846f;
constexpr float CUT = 5.0f;

// ---------------- CSR hist ----------------
__global__ __launch_bounds__(256) void csr_hist(
    const int* __restrict__ edge, int* __restrict__ cnt, int nE) {
  int e = blockIdx.x * blockDim.x + threadIdx.x;
  if (e < nE) atomicAdd(&cnt[edge[2 * e]], 1);
}

// ---------------- CSR scan: 1024-thread LDS tree scan ----------------
__global__ __launch_bounds__(1024) void csr_scan(
    const int* __restrict__ cnt, int* __restrict__ rowstart, int* __restrict__ cur, int N) {
  __shared__ int part[1024];
  int t = threadIdx.x;
  int chunk = (N + 1023) / 1024;
  int lo = t * chunk; if (lo > N) lo = N;
  int hi = lo + chunk; if (hi > N) hi = N;
  int s = 0;
  for (int i = lo; i < hi; i++) s += cnt[i];
  part[t] = s;
  __syncthreads();
  for (int off = 1; off < 1024; off <<= 1) {
    int v = (t >= off) ? part[t - off] : 0;
    __syncthreads();
    part[t] += v;
    __syncthreads();
  }
  int r = (t == 0) ? 0 : part[t - 1];
  for (int i = lo; i < hi; i++) { rowstart[i] = r; cur[i] = r; r += cnt[i]; }
}

// ---------------- CSR fill + edge geometry pack (fused; no elist) ----------------
__global__ __launch_bounds__(256) void csr_fill_pack(
    const int* __restrict__ edge, int* __restrict__ cur,
    const float* __restrict__ edist, const float* __restrict__ ediff,
    int* __restrict__ srcs, float* __restrict__ geo, int nE) {
  int e = blockIdx.x * blockDim.x + threadIdx.x;
  if (e >= nE) return;
  int d = edge[2 * e];
  int p = atomicAdd(&cur[d], 1);
  srcs[p] = edge[2 * e + 1];
  float dd = edist[e];
  float inv = 1.0f / dd;
  float th = dd * (PI_F / CUT);
  float s1 = sinf(th), c1 = cosf(th);
  float fc = (dd < CUT) ? 0.5f * (c1 + 1.0f) : 0.0f;
  float* g = geo + (size_t)p * 24;
  float twoc = 2.0f * c1;
  float skp = 0.0f, sk = s1;
  #pragma unroll
  for (int k = 0; k < E_RBF; k++) {
    g[k] = sk * inv * fc;
    float nx = twoc * sk - skp;
    skp = sk; sk = nx;
  }
  g[20] = ediff[3 * (size_t)e] * inv;
  g[21] = ediff[3 * (size_t)e + 1] * inv;
  g[22] = ediff[3 * (size_t)e + 2] * inv;
  g[23] = fc;
}

// ---------------- device helpers for weight packing ----------------
__device__ __forceinline__ void pack_w_item(
    const float* __restrict__ Wu, const float* __restrict__ Wv,
    bf16* __restrict__ wp, int t) {
  int lane = t & 63;
  int c    = (t >> 6) & 7;
  int kb   = (t >> 9) & 3;
  int mat  = (t >> 11) & 1;
  int l    = t >> 12;
  const float* src = (mat ? Wv : Wu) + (size_t)l * H * H;
  bf16* dst = wp + ((size_t)(l * 2 + mat) * 16384) + (((kb * 8 + c) * 64 + lane) * 8);
  int quad = lane >> 4;
  int n = c * 16 + (lane & 15);
  #pragma unroll
  for (int j = 0; j < 8; j++) {
    int k = kb * 32 + quad * 8 + j;
    dst[j] = __float2bfloat16(src[(size_t)k * H + n]);
  }
}

__device__ __forceinline__ void pack_b_item(
    const float* __restrict__ src, bf16* __restrict__ dst,
    int K, int ncols, int t) {
  int kblocks = K >> 5, ncols16 = ncols >> 4;
  int lane = t & 63;
  int idx = t >> 6;
  int c = idx % ncols16; idx /= ncols16;
  int kb = idx % kblocks; idx /= kblocks;
  int l = idx;
  const float* s = src + (size_t)l * K * ncols;
  bf16* d = dst + (size_t)l * K * ncols + (((kb * ncols16 + c) * 64 + lane) * 8);
  int quad = lane >> 4;
  int n = c * 16 + (lane & 15);
  #pragma unroll
  for (int j = 0; j < 8; j++) {
    int k = kb * 32 + quad * 8 + j;
    d[j] = __float2bfloat16(s[(size_t)k * ncols + n]);
  }
}

// ---------------- one-shot setup: all weight packs + node_init + cnt zero ----------------
__global__ __launch_bounds__(256) void pack_all(
    const float* __restrict__ Wu, const float* __restrict__ Wv, bf16* __restrict__ wpack,
    const float* __restrict__ uw1, bf16* __restrict__ wp_m1,
    const float* __restrict__ uw2, bf16* __restrict__ wp_m2,
    const float* __restrict__ mw1, bf16* __restrict__ wp_sm1,
    const float* __restrict__ mw2, bf16* __restrict__ wp_sm2,
    const float* __restrict__ rw1, bf16* __restrict__ wp_ro1,
    const float* __restrict__ rw2, bf16* __restrict__ wp_ro2,
    const int* __restrict__ z, const float* __restrict__ embed,
    float* __restrict__ ns, bf16* __restrict__ ns16,
    int* __restrict__ cnt, int N) {
  const int T0 = 12288;            // pack_w (UV)
  const int T1 = T0 + 12288;       // uw1 K=256 n=128 L=3
  const int T2 = T1 + 18432;       // uw2 K=128 n=384 L=3
  const int T3 = T2 + 6144;        // mw1 K=128 n=128 L=3
  const int T4 = T3 + 18432;       // mw2 K=128 n=384 L=3
  const int T5 = T4 + 2048;        // rw1
  const int T6 = T5 + 2048;        // rw2
  const int TN = T6 + N * H;       // node_init
  const int TT = TN + N;           // cnt zero
  for (int t = blockIdx.x * blockDim.x + threadIdx.x; t < TT; t += gridDim.x * blockDim.x) {
    if (t < T0)      pack_w_item(Wu, Wv, wpack, t);
    else if (t < T1) pack_b_item(uw1, wp_m1, 256, 128, t - T0);
    else if (t < T2) pack_b_item(uw2, wp_m2, 128, 384, t - T1);
    else if (t < T3) pack_b_item(mw1, wp_sm1, 128, 128, t - T2);
    else if (t < T4) pack_b_item(mw2, wp_sm2, 128, 384, t - T3);
    else if (t < T5) pack_b_item(rw1, wp_ro1, 128, 128, t - T4);
    else if (t < T6) pack_b_item(rw2, wp_ro2, 128, 128, t - T5);
    else if (t < TN) {
      int u = t - T6;
      int i = u >> 7, h = u & 127;
      float v = embed[(size_t)z[i] * H + h];
      ns[(size_t)i * H + h] = v;
      ns16[(size_t)i * H + h] = __float2bfloat16(v);
    } else {
      cnt[t - TN] = 0;
    }
  }
}

// ---------------- fused 2-stage MLP: so = (silu(A@W1+b1))@W2+b2, 384 cols ----------------
__global__ __launch_bounds__(256) void mlp_msg(
    const bf16* __restrict__ A, const bf16* __restrict__ Wp1,
    const float* __restrict__ b1, const bf16* __restrict__ Wp2,
    const float* __restrict__ b2, bf16* __restrict__ so, int M) {
  __shared__ bf16 m1l[32][136];
  int wave = threadIdx.x >> 6, lane = threadIdx.x & 63;
  int rowg = wave >> 1, ch = wave & 1;
  int r0 = blockIdx.x * 32 + rowg * 16;
  int quad = lane >> 4, nn = lane & 15;
  int arow = r0 + nn; if (arow >= M) arow = M - 1;
  f32x4 acc[4] = {};
  for (int kb = 0; kb < 4; kb++) {
    bf16x8 af = *(const bf16x8*)&A[(size_t)arow * H + kb * 32 + quad * 8];
    #pragma unroll
    for (int c = 0; c < 4; c++) {
      int cg = ch * 4 + c;
      bf16x8 bw = *(const bf16x8*)&Wp1[(((kb * 8 + cg) * 64) + lane) * 8];
      acc[c] = __builtin_amdgcn_mfma_f32_16x16x32_bf16(af, bw, acc[c], 0, 0, 0);
    }
  }
  #pragma unroll
  for (int c = 0; c < 4; c++) {
    int n = (ch * 4 + c) * 16 + nn;
    float bb = b1[n];
    #pragma unroll
    for (int r = 0; r < 4; r++) {
      int lr = rowg * 16 + quad * 4 + r;
      m1l[lr][n] = __float2bfloat16(silu_f(acc[c][r] + bb));
    }
  }
  __syncthreads();
  f32x4 a0[4] = {}, a1[4] = {}, a2[4] = {};
  for (int kb = 0; kb < 4; kb++) {
    bf16x8 af = *(const bf16x8*)&m1l[rowg * 16 + nn][kb * 32 + quad * 8];
    #pragma unroll
    for (int c = 0; c < 4; c++) {
      int cg = ch * 4 + c;
      bf16x8 b0 = *(const bf16x8*)&Wp2[(((kb * 24 + cg) * 64) + lane) * 8];
      bf16x8 b1v = *(const bf16x8*)&Wp2[(((kb * 24 + cg + 8) * 64) + lane) * 8];
      bf16x8 b2v = *(const bf16x8*)&Wp2[(((kb * 24 + cg + 16) * 64) + lane) * 8];
      a0[c] = __builtin_amdgcn_mfma_f32_16x16x32_bf16(af, b0, a0[c], 0, 0, 0);
      a1[c] = __builtin_amdgcn_mfma_f32_16x16x32_bf16(af, b1v, a1[c], 0, 0, 0);
      a2[c] = __builtin_amdgcn_mfma_f32_16x16x32_bf16(af, b2v, a2[c], 0, 0, 0);
    }
  }
  #pragma unroll
  for (int c = 0; c < 4; c++) {
    int n = (ch * 4 + c) * 16 + nn;
    float bb0 = b2[n], bb1 = b2[H + n], bb2 = b2[2 * H + n];
    #pragma unroll
    for (int r = 0; r < 4; r++) {
      int row = r0 + quad * 4 + r;
      if (row < M) {
        so[(size_t)row * F3H + n]           = __float2bfloat16(a0[c][r] + bb0);
        so[(size_t)row * F3H + H + n]       = __float2bfloat16(a1[c][r] + bb1);
        so[(size_t)row * F3H + 2 * H + n]   = __float2bfloat16(a2[c][r] + bb2);
      }
    }
  }
}

// ---------------- fused UV dual-GEMM + vnorm + update-MLP + gating epilogue ----------------
// 16 nodes (48 UV rows) per block, 6 waves. LDS 58 KB -> 2 blocks/CU (was 116 KB
// -> 1 block/CU, ~19% occupancy + 1.22-generation tail). Phase 1 splits U/V
// across wave triples; MLP phases stripe the 8 n-groups over all 6 waves.
// Per-output MFMA chains identical to the 32-node version -> bitwise-same.
__global__ __launch_bounds__(384, 3) void uv_upd(
    const bf16* __restrict__ A, const bf16* __restrict__ Wpuv,
    const float* __restrict__ bu, const float* __restrict__ bv,
    const bf16* __restrict__ nsmsg,
    const bf16* __restrict__ Wp1, const float* __restrict__ b1,
    const bf16* __restrict__ Wp2, const float* __restrict__ b2,
    float* __restrict__ ns, bf16* __restrict__ ns16,
    float* __restrict__ nv, bf16* __restrict__ nvb16, int N) {
  __shared__ float Uv_l[48][132];
  __shared__ float Vv_l[48][132];
  __shared__ bf16 vn_l[16][136];
  __shared__ bf16 m1l[16][136];
  int wave = threadIdx.x >> 6;     // 0..5
  int lane = threadIdx.x & 63;
  int quad = lane >> 4, nn = lane & 15;
  int M3 = 3 * N;

  // ---- phase 1: dual GEMM; waves 0-2 -> U rows, waves 3-5 -> V rows ----
  {
    int wt = (wave >= 3) ? wave - 3 : wave;   // row tile 0..2
    bool isV = wave >= 3;
    int r0 = blockIdx.x * 48 + wt * 16;
    int arow = r0 + nn; if (arow >= M3) arow = M3 - 1;
    const bf16* Wb = Wpuv + (isV ? 16384 : 0);
    f32x4 acc[8] = {};
    for (int kb = 0; kb < 4; kb++) {
      bf16x8 af = *(const bf16x8*)&A[(size_t)arow * H + kb * 32 + quad * 8];
      #pragma unroll
      for (int c = 0; c < 8; c++) {
        bf16x8 bw = *(const bf16x8*)&Wb[(((kb * 8 + c) * 64) + lane) * 8];
        acc[c] = __builtin_amdgcn_mfma_f32_16x16x32_bf16(af, bw, acc[c], 0, 0, 0);
      }
    }
    const float* bias = isV ? bv : bu;
    #pragma unroll
    for (int c = 0; c < 8; c++) {
      int n = c * 16 + nn;
      float bb = bias[n];
      #pragma unroll
      for (int r = 0; r < 4; r++) {
        int lr = wt * 16 + quad * 4 + r;
        if (isV) Vv_l[lr][n] = acc[c][r] + bb;
        else     Uv_l[lr][n] = acc[c][r] + bb;
      }
    }
  }
  __syncthreads();

  // ---- phase 2: vnorm -> vn_l ----
  for (int t = threadIdx.x; t < 16 * H; t += 384) {
    int node = t >> 7, hh = t & 127;
    float v0 = Vv_l[node * 3][hh];
    float v1 = Vv_l[node * 3 + 1][hh];
    float v2 = Vv_l[node * 3 + 2][hh];
    vn_l[node][hh] = __float2bfloat16(sqrtf(v0 * v0 + v1 * v1 + v2 * v2));
  }
  __syncthreads();

  // ---- phase 3: MLP stage 1, K=256, 16 rows; n-groups striped over waves ----
  int r0n = blockIdx.x * 16;
  int arown = r0n + nn; if (arown >= N) arown = N - 1;
  for (int g = wave; g < 8; g += 6) {
    f32x4 acc = {};
    for (int kb = 0; kb < 8; kb++) {
      bf16x8 af;
      if (kb < 4) af = *(const bf16x8*)&vn_l[nn][kb * 32 + quad * 8];
      else        af = *(const bf16x8*)&nsmsg[(size_t)arown * H + (kb - 4) * 32 + quad * 8];
      bf16x8 bw = *(const bf16x8*)&Wp1[(((kb * 8 + g) * 64) + lane) * 8];
      acc = __builtin_amdgcn_mfma_f32_16x16x32_bf16(af, bw, acc, 0, 0, 0);
    }
    int n = g * 16 + nn;
    float bb = b1[n];
    #pragma unroll
    for (int r = 0; r < 4; r++) {
      m1l[quad * 4 + r][n] = __float2bfloat16(silu_f(acc[r] + bb));
    }
  }
  __syncthreads();

  // ---- phase 4: MLP stage 2 + gating epilogue; n-groups striped over waves ----
  for (int g = wave; g < 8; g += 6) {
    f32x4 aav = {}, aas = {}, asz = {};
    for (int kb = 0; kb < 4; kb++) {
      bf16x8 af = *(const bf16x8*)&m1l[nn][kb * 32 + quad * 8];
      bf16x8 b0 = *(const bf16x8*)&Wp2[(((kb * 24 + g) * 64) + lane) * 8];
      bf16x8 b1v = *(const bf16x8*)&Wp2[(((kb * 24 + g + 8) * 64) + lane) * 8];
      bf16x8 b2v = *(const bf16x8*)&Wp2[(((kb * 24 + g + 16) * 64) + lane) * 8];
      aav = __builtin_amdgcn_mfma_f32_16x16x32_bf16(af, b0, aav, 0, 0, 0);
      aas = __builtin_amdgcn_mfma_f32_16x16x32_bf16(af, b1v, aas, 0, 0, 0);
      asz = __builtin_amdgcn_mfma_f32_16x16x32_bf16(af, b2v, asz, 0, 0, 0);
    }
    int n = g * 16 + nn;
    float bav = b2[n], bas = b2[H + n], bss = b2[2 * H + n];
    #pragma unroll
    for (int r = 0; r < 4; r++) {
      int row = r0n + quad * 4 + r;
      if (row < N) {
        int lrn = quad * 4 + r;
        float avv = aav[r] + bav;
        float asv = aas[r] + bas;
        float ass = asz[r] + bss;
        float u0 = Uv_l[lrn * 3 + 0][n];
        float u1 = Uv_l[lrn * 3 + 1][n];
        float u2 = Uv_l[lrn * 3 + 2][n];
        float v0 = Vv_l[lrn * 3 + 0][n];
        float v1 = Vv_l[lrn * 3 + 1][n];
        float v2 = Vv_l[lrn * 3 + 2][n];
        float dot = u0 * v0 + u1 * v1 + u2 * v2;
        float ns_new = ns[(size_t)row * H + n] + asv * dot + ass;
        ns[(size_t)row * H + n] = ns_new;
        ns16[(size_t)row * H + n] = __float2bfloat16(ns_new);
        float n0 = nv[(size_t)(3 * row + 0) * H + n] + avv * u0;
        float n1 = nv[(size_t)(3 * row + 1) * H + n] + avv * u1;
        float n2 = nv[(size_t)(3 * row + 2) * H + n] + avv * u2;
        nv[(size_t)(3 * row + 0) * H + n] = n0;
        nv[(size_t)(3 * row + 1) * H + n] = n1;
        nv[(size_t)(3 * row + 2) * H + n] = n2;
        nvb16[(size_t)(3 * row + 0) * H + n] = __float2bfloat16(n0);
        nvb16[(size_t)(3 * row + 1) * H + n] = __float2bfloat16(n1);
        nvb16[(size_t)(3 * row + 2) * H + n] = __float2bfloat16(n2);
      }
    }
  }
}

// ---------------- fused readout: out = (silu(ns16@rw1+rb1))@rw2+rb2 ----------------
__global__ __launch_bounds__(256) void mlp_ro(
    const bf16* __restrict__ A, const bf16* __restrict__ Wp1,
    const float* __restrict__ b1, const bf16* __restrict__ Wp2,
    const float* __restrict__ b2, float* __restrict__ out, int M) {
  __shared__ bf16 m1l[32][136];
  int wave = threadIdx.x >> 6, lane = threadIdx.x & 63;
  int rowg = wave >> 1, ch = wave & 1;
  int r0 = blockIdx.x * 32 + rowg * 16;
  int quad = lane >> 4, nn = lane & 15;
  int arow = r0 + nn; if (arow >= M) arow = M - 1;
  f32x4 acc[4] = {};
  for (int kb = 0; kb < 4; kb++) {
    bf16x8 af = *(const bf16x8*)&A[(size_t)arow * H + kb * 32 + quad * 8];
    #pragma unroll
    for (int c = 0; c < 4; c++) {
      int cg = ch * 4 + c;
      bf16x8 bw = *(const bf16x8*)&Wp1[(((kb * 8 + cg) * 64) + lane) * 8];
      acc[c] = __builtin_amdgcn_mfma_f32_16x16x32_bf16(af, bw, acc[c], 0, 0, 0);
    }
  }
  #pragma unroll
  for (int c = 0; c < 4; c++) {
    int n = (ch * 4 + c) * 16 + nn;
    float bb = b1[n];
    #pragma unroll
    for (int r = 0; r < 4; r++) {
      int lr = rowg * 16 + quad * 4 + r;
      m1l[lr][n] = __float2bfloat16(silu_f(acc[c][r] + bb));
    }
  }
  __syncthreads();
  f32x4 a2[4] = {};
  for (int kb = 0; kb < 4; kb++) {
    bf16x8 af = *(const bf16x8*)&m1l[rowg * 16 + nn][kb * 32 + quad * 8];
    #pragma unroll
    for (int c = 0; c < 4; c++) {
      int cg = ch * 4 + c;
      bf16x8 bw = *(const bf16x8*)&Wp2[(((kb * 8 + cg) * 64) + lane) * 8];
      a2[c] = __builtin_amdgcn_mfma_f32_16x16x32_bf16(af, bw, a2[c], 0, 0, 0);
    }
  }
  #pragma unroll
  for (int c = 0; c < 4; c++) {
    int n = (ch * 4 + c) * 16 + nn;
    float bb = b2[n];
    #pragma unroll
    for (int r = 0; r < 4; r++) {
      int row = r0 + quad * 4 + r;
      if (row < M) out[(size_t)row * H + n] = a2[c][r] + bb;
    }
  }
}

// ---------------- message: round-0 structure, edge loop unrolled x2 ----------------
// At the measured random-gather ceiling (~2.15 TB/s effective, invariant under
// r1-r4 restructures). Do not restructure further.
template<bool HASNV>
__global__ __launch_bounds__(128, 4) void message3(
    const int* __restrict__ srcs, const int* __restrict__ rowstart,
    const int* __restrict__ cnt, const float* __restrict__ geo,
    const float* __restrict__ Wf, const float* __restrict__ bfb,
    const bf16* __restrict__ so, const bf16* __restrict__ nvb16,
    const float* __restrict__ nvA,
    float* __restrict__ ns, float* __restrict__ nvB,
    bf16* __restrict__ nvmsg16, bf16* __restrict__ nsmsg, int N) {
  int i = blockIdx.x;
  int h = threadIdx.x;

  float wf0[E_RBF], wf1[E_RBF], wf2[E_RBF];
  #pragma unroll
  for (int k = 0; k < E_RBF; k++) {
    wf0[k] = Wf[k * F3H + h];
    wf1[k] = Wf[k * F3H + H + h];
    wf2[k] = Wf[k * F3H + 2 * H + h];
  }
  float bb0 = bfb[h], bb1 = bfb[H + h], bb2 = bfb[2 * H + h];

  float accs = 0.0f, a0 = 0.0f, a1 = 0.0f, a2 = 0.0f;
  int jlo = rowstart[i], jhi = jlo + cnt[i];
  int j = jlo;
  for (; j + 1 < jhi; j += 2) {
    int s0 = srcs[j];
    int s1 = srcs[j + 1];
    const bf16* sop0 = so + (size_t)s0 * F3H;
    const bf16* sop1 = so + (size_t)s1 * F3H;
    float sA0 = b2f(sop0[h]), sB0 = b2f(sop0[H + h]), sC0 = b2f(sop0[2 * H + h]);
    float sA1 = b2f(sop1[h]), sB1 = b2f(sop1[H + h]), sC1 = b2f(sop1[2 * H + h]);
    float nA0, nB0, nC0, nA1, nB1, nC1;
    if (HASNV) {
      const bf16* nvp0 = nvb16 + (size_t)s0 * F3H;
      const bf16* nvp1 = nvb16 + (size_t)s1 * F3H;
      nA0 = b2f(nvp0[h]); nB0 = b2f(nvp0[H + h]); nC0 = b2f(nvp0[2 * H + h]);
      nA1 = b2f(nvp1[h]); nB1 = b2f(nvp1[H + h]); nC1 = b2f(nvp1[2 * H + h]);
    }

    {
      const float* g = geo + (size_t)j * 24;
      float gg[24];
      #pragma unroll
      for (int q = 0; q < 6; q++) *(float4*)&gg[4 * q] = *(const float4*)&g[4 * q];
      float fc = gg[23];
      float f0 = bb0 * fc, f1 = bb1 * fc, f2 = bb2 * fc;
      #pragma unroll
      for (int k = 0; k < E_RBF; k++) {
        float rk = gg[k];
        f0 += rk * wf0[k];
        f1 += rk * wf1[k];
        f2 += rk * wf2[k];
      }
      float u0 = gg[20], u1 = gg[21], u2 = gg[22];
      float gsv = f0 * sA0;
      float gev = f1 * sB0;
      accs += f2 * sC0;
      if (HASNV) {
        a0 += nA0 * gsv + gev * u0;
        a1 += nB0 * gsv + gev * u1;
        a2 += nC0 * gsv + gev * u2;
      } else {
        a0 += gev * u0;
        a1 += gev * u1;
        a2 += gev * u2;
      }
    }
    {
      const float* g = geo + (size_t)(j + 1) * 24;
      float gg[24];
      #pragma unroll
      for (int q = 0; q < 6; q++) *(float4*)&gg[4 * q] = *(const float4*)&g[4 * q];
      float fc = gg[23];
      float f0 = bb0 * fc, f1 = bb1 * fc, f2 = bb2 * fc;
      #pragma unroll
      for (int k = 0; k < E_RBF; k++) {
        float rk = gg[k];
        f0 += rk * wf0[k];
        f1 += rk * wf1[k];
        f2 += rk * wf2[k];
      }
      float u0 = gg[20], u1 = gg[21], u2 = gg[22];
      float gsv = f0 * sA1;
      float gev = f1 * sB1;
      accs += f2 * sC1;
      if (HASNV) {
        a0 += nA1 * gsv + gev * u0;
        a1 += nB1 * gsv + gev * u1;
        a2 += nC1 * gsv + gev * u2;
      } else {
        a0 += gev * u0;
        a1 += gev * u1;
        a2 += gev * u2;
      }
    }
  }
  if (j < jhi) {
    int src = srcs[j];
    const float* g = geo + (size_t)j * 24;
    float gg[24];
    #pragma unroll
    for (int q = 0; q < 6; q++) *(float4*)&gg[4 * q] = *(const float4*)&g[4 * q];
    float fc = gg[23];
    float f0 = bb0 * fc, f1 = bb1 * fc, f2 = bb2 * fc;
    #pragma unroll
    for (int k = 0; k < E_RBF; k++) {
      float rk = gg[k];
      f0 += rk * wf0[k];
      f1 += rk * wf1[k];
      f2 += rk * wf2[k];
    }
    float u0 = gg[20], u1 = gg[21], u2 = gg[22];
    const bf16* sop = so + (size_t)src * F3H;
    float gsv = f0 * b2f(sop[h]);
    float gev = f1 * b2f(sop[H + h]);
    accs += f2 * b2f(sop[2 * H + h]);
    if (HASNV) {
      const bf16* nvp = nvb16 + (size_t)src * F3H;
      a0 += b2f(nvp[h])         * gsv + gev * u0;
      a1 += b2f(nvp[H + h])     * gsv + gev * u1;
      a2 += b2f(nvp[2 * H + h]) * gsv + gev * u2;
    } else {
      a0 += gev * u0;
      a1 += gev * u1;
      a2 += gev * u2;
    }
  }

  float ns_new = ns[(size_t)i * H + h] + accs;
  ns[(size_t)i * H + h] = ns_new;
  nsmsg[(size_t)i * H + h] = __float2bfloat16(ns_new);
  float o0, o1, o2;
  if (HASNV) {
    const float* nvi = nvA + (size_t)i * F3H;
    o0 = nvi[h] + a0;
    o1 = nvi[H + h] + a1;
    o2 = nvi[2 * H + h] + a2;
  } else {
    o0 = a0; o1 = a1; o2 = a2;
  }
  nvB[(size_t)i * F3H + h]         = o0;
  nvB[(size_t)i * F3H + H + h]     = o1;
  nvB[(size_t)i * F3H + 2 * H + h] = o2;
  nvmsg16[(size_t)i * F3H + h]         = __float2bfloat16(o0);
  nvmsg16[(size_t)i * F3H + H + h]     = __float2bfloat16(o1);
  nvmsg16[(size_t)i * F3H + 2 * H + h] = __float2bfloat16(o2);
}

extern "C" void kernel_launch(void* const* d_in, const int* in_sizes, int n_in,
                              void* d_out, int out_size, void* d_ws, size_t ws_size,
                              hipStream_t stream) {
  const int*   z     = (const int*)d_in[0];
  const int*   edge  = (const int*)d_in[1];
  const float* ediff = (const float*)d_in[2];
  const float* edist = (const float*)d_in[3];
  const float* embed = (const float*)d_in[4];
  const float* mfw   = (const float*)d_in[5];
  const float* mfb   = (const float*)d_in[6];
  const float* mw1   = (const float*)d_in[7];
  const float* mb1   = (const float*)d_in[8];
  const float* mw2   = (const float*)d_in[9];
  const float* mb2   = (const float*)d_in[10];
  const float* uUw   = (const float*)d_in[11];
  const float* uUb   = (const float*)d_in[12];
  const float* uVw   = (const float*)d_in[13];
  const float* uVb   = (const float*)d_in[14];
  const float* uw1   = (const float*)d_in[15];
  const float* ub1   = (const float*)d_in[16];
  const float* uw2   = (const float*)d_in[17];
  const float* ub2   = (const float*)d_in[18];
  const float* rw1   = (const float*)d_in[19];
  const float* rb1   = (const float*)d_in[20];
  const float* rw2   = (const float*)d_in[21];
  const float* rb2   = (const float*)d_in[22];

  const int N  = in_sizes[0];   // 10000
  const int nE = in_sizes[3];   // 160000

  float* ws = (float*)d_ws;
  size_t off = 0;
  float* ns      = ws + off; off += (size_t)N * H;
  float* nvA     = ws + off; off += (size_t)N * F3H;
  float* nvB     = ws + off; off += (size_t)N * F3H;
  float* geo     = ws + off; off += (size_t)nE * 24;
  bf16* so       = (bf16*)(ws + off); off += (size_t)N * F3H / 2;
  bf16* nvb16    = (bf16*)(ws + off); off += (size_t)N * F3H / 2;
  bf16* nvmsg16  = (bf16*)(ws + off); off += (size_t)N * F3H / 2;
  bf16* nsmsg    = (bf16*)(ws + off); off += (size_t)N * 64;        // N*128 bf16
  bf16* ns16     = (bf16*)(ws + off); off += (size_t)N * 64;        // N*128 bf16
  bf16* wpack    = (bf16*)(ws + off); off += 3 * 2 * 16384 / 2;     // UV
  bf16* wp_m1    = (bf16*)(ws + off); off += 3 * 256 * 128 / 2;
  bf16* wp_m2    = (bf16*)(ws + off); off += 3 * 128 * 384 / 2;
  bf16* wp_sm1   = (bf16*)(ws + off); off += 3 * 128 * 128 / 2;
  bf16* wp_sm2   = (bf16*)(ws + off); off += 3 * 128 * 384 / 2;
  bf16* wp_ro1   = (bf16*)(ws + off); off += 128 * 128 / 2;
  bf16* wp_ro2   = (bf16*)(ws + off); off += 128 * 128 / 2;
  int* srcs     = (int*)(ws + off); off += nE;
  int* cnt      = (int*)(ws + off); off += N;
  int* rowstart = (int*)(ws + off); off += N;
  int* cur      = (int*)(ws + off); off += N;

  const int tilesN = (N + 31) / 32;            // 313
  const int tilesUV = (N + 15) / 16;           // 625

  pack_all<<<1024, 256, 0, stream>>>(
      uUw, uVw, wpack, uw1, wp_m1, uw2, wp_m2, mw1, wp_sm1, mw2, wp_sm2,
      rw1, wp_ro1, rw2, wp_ro2, z, embed, ns, ns16, cnt, N);
  csr_hist<<<(nE + 255) / 256, 256, 0, stream>>>(edge, cnt, nE);
  csr_scan<<<1, 1024, 0, stream>>>(cnt, rowstart, cur, N);
  csr_fill_pack<<<(nE + 255) / 256, 256, 0, stream>>>(edge, cur, edist, ediff, srcs, geo, nE);

  float* nv_cur = nvA;
  float* nv_nxt = nvB;
  for (int l = 0; l < NLAYER; l++) {
    mlp_msg<<<tilesN, 256, 0, stream>>>(
        ns16, wp_sm1 + (size_t)l * 128 * 128, mb1 + (size_t)l * H,
        wp_sm2 + (size_t)l * 128 * 384, mb2 + (size_t)l * F3H, so, N);

    if (l == 0)
      message3<false><<<N, H, 0, stream>>>(srcs, rowstart, cnt, geo,
                                           mfw + (size_t)l * E_RBF * F3H, mfb + (size_t)l * F3H,
                                           so, nvb16, nv_cur, ns, nv_nxt, nvmsg16, nsmsg, N);
    else
      message3<true><<<N, H, 0, stream>>>(srcs, rowstart, cnt, geo,
                                          mfw + (size_t)l * E_RBF * F3H, mfb + (size_t)l * F3H,
                                          so, nvb16, nv_cur, ns, nv_nxt, nvmsg16, nsmsg, N);

    uv_upd<<<tilesUV, 384, 0, stream>>>(
        nvmsg16, wpack + (size_t)l * 2 * 16384,
        uUb + (size_t)l * H, uVb + (size_t)l * H,
        nsmsg,
        wp_m1 + (size_t)l * 256 * 128, ub1 + (size_t)l * H,
        wp_m2 + (size_t)l * 128 * 384, ub2 + (size_t)l * F3H,
        ns, ns16, nv_nxt, nvb16, N);

    float* t = nv_cur; nv_cur = nv_nxt; nv_nxt = t;
  }

  mlp_ro<<<tilesN, 256, 0, stream>>>(
      ns16, wp_ro1, rb1, wp_ro2, rb2, (float*)d_out, N);
}